// Round 1
// baseline (3498.600 us; speedup 1.0000x reference)
//
#include <hip/hip_runtime.h>
#include <hip/hip_bf16.h>
#include <math.h>

// ---- problem constants ----
#define S_LEN   2048
#define HIDDIM  2048
#define NKH     16
#define NVH     32
#define DKD     128
#define DVD     128
#define CCH     64          // chunk
#define NCHK    32          // S/chunk
#define KEY_DIM 2048
#define VAL_DIM 4096
#define CONV_DIM 8192

#define PA_LDS_FLOATS (3*64*132 + 64*68 + 128)
#define PB_LDS_FLOATS (3*64*132 + 64*68 + 64*20 + 64*20 + 128*20 + 64)

__device__ __forceinline__ float sigmoid_f(float x) { return 1.f / (1.f + __expf(-x)); }
__device__ __forceinline__ float silu_f(float x) { return x * sigmoid_f(x); }

// ================= GEMM: C[M,N] = A[M,K] @ B[N,K]^T (fp32) =================
// 128x128 tile, BK=16, 256 threads, 8x8 per thread.
__global__ __launch_bounds__(256) void gemm_nt_kernel(
    const float* __restrict__ A, const float* __restrict__ B, float* __restrict__ C,
    int M, int N, int K)
{
    __shared__ float As[16][132];
    __shared__ float Bs[16][132];
    const int bm = blockIdx.y * 128, bn = blockIdx.x * 128;
    const int tid = threadIdx.x;
    const int tx = tid & 15, ty = tid >> 4;
    const int lr = tid >> 2, lk = (tid & 3) << 2;
    float acc[8][8];
#pragma unroll
    for (int i = 0; i < 8; ++i)
#pragma unroll
        for (int j = 0; j < 8; ++j) acc[i][j] = 0.f;

    for (int k0 = 0; k0 < K; k0 += 16) {
#pragma unroll
        for (int rr = 0; rr < 128; rr += 64) {
            int row = bm + lr + rr;
            float4 v = make_float4(0.f, 0.f, 0.f, 0.f);
            if (row < M) v = *(const float4*)(A + (size_t)row * K + k0 + lk);
            As[lk + 0][lr + rr] = v.x; As[lk + 1][lr + rr] = v.y;
            As[lk + 2][lr + rr] = v.z; As[lk + 3][lr + rr] = v.w;
        }
#pragma unroll
        for (int rr = 0; rr < 128; rr += 64) {
            int row = bn + lr + rr;
            float4 v = make_float4(0.f, 0.f, 0.f, 0.f);
            if (row < N) v = *(const float4*)(B + (size_t)row * K + k0 + lk);
            Bs[lk + 0][lr + rr] = v.x; Bs[lk + 1][lr + rr] = v.y;
            Bs[lk + 2][lr + rr] = v.z; Bs[lk + 3][lr + rr] = v.w;
        }
        __syncthreads();
#pragma unroll
        for (int kk = 0; kk < 16; ++kk) {
            float a[8], b[8];
            *(float4*)&a[0] = *(const float4*)&As[kk][ty * 8];
            *(float4*)&a[4] = *(const float4*)&As[kk][ty * 8 + 4];
            *(float4*)&b[0] = *(const float4*)&Bs[kk][tx * 8];
            *(float4*)&b[4] = *(const float4*)&Bs[kk][tx * 8 + 4];
#pragma unroll
            for (int i = 0; i < 8; ++i)
#pragma unroll
                for (int j = 0; j < 8; ++j) acc[i][j] = fmaf(a[i], b[j], acc[i][j]);
        }
        __syncthreads();
    }
#pragma unroll
    for (int i = 0; i < 8; ++i) {
        int row = bm + ty * 8 + i;
        if (row >= M) continue;
#pragma unroll
        for (int j = 0; j < 8; j += 4) {
            int col = bn + tx * 8 + j;
            if (col < N) {
                float4 v = make_float4(acc[i][j], acc[i][j + 1], acc[i][j + 2], acc[i][j + 3]);
                *(float4*)(C + (size_t)row * N + col) = v;
            }
        }
    }
}

// ================= causal depthwise conv1d (K=4) + SiLU =================
__global__ __launch_bounds__(256) void conv_silu_kernel(
    const float* __restrict__ pre, const float* __restrict__ cw, float* __restrict__ out)
{
    int idx = blockIdx.x * 256 + threadIdx.x;       // S*CONV_DIM/4 threads
    const int NC4 = CONV_DIM / 4;
    int s = idx / NC4;
    int c = (idx % NC4) * 4;
    float w[4][4];
#pragma unroll
    for (int j = 0; j < 4; ++j) {
        float4 wj = *(const float4*)(cw + (size_t)(c + j) * 4);
        w[j][0] = wj.x; w[j][1] = wj.y; w[j][2] = wj.z; w[j][3] = wj.w;
    }
    float acc[4] = {0.f, 0.f, 0.f, 0.f};
#pragma unroll
    for (int t = 0; t < 4; ++t) {
        int ss = s - 3 + t;
        if (ss >= 0) {
            float4 x = *(const float4*)(pre + (size_t)ss * CONV_DIM + c);
            acc[0] = fmaf(x.x, w[0][t], acc[0]);
            acc[1] = fmaf(x.y, w[1][t], acc[1]);
            acc[2] = fmaf(x.z, w[2][t], acc[2]);
            acc[3] = fmaf(x.w, w[3][t], acc[3]);
        }
    }
    float4 o = make_float4(silu_f(acc[0]), silu_f(acc[1]), silu_f(acc[2]), silu_f(acc[3]));
    *(float4*)(out + (size_t)s * CONV_DIM + c) = o;
}

// ================= g = -exp(A_log)*softplus(a+dt_bias), beta = sigmoid(b) ====
__global__ __launch_bounds__(256) void gb_kernel(
    const float* __restrict__ a, const float* __restrict__ b,
    const float* __restrict__ dt_bias, const float* __restrict__ A_log,
    float* __restrict__ g, float* __restrict__ beta)
{
    int idx = blockIdx.x * 256 + threadIdx.x;       // S*NV threads
    int h = idx & (NVH - 1);
    float av = a[idx] + dt_bias[h];
    float sp = (av > 20.f) ? av : log1pf(__expf(av));
    g[idx] = -__expf(A_log[h]) * sp;
    beta[idx] = sigmoid_f(b[idx]);
}

// ================= l2norm of q,k rows (per original 16 heads) ===============
__global__ __launch_bounds__(256) void l2norm_kernel(
    const float* __restrict__ mixed, float* __restrict__ qn, float* __restrict__ kn)
{
    int gw = (blockIdx.x * 256 + threadIdx.x) >> 6;  // 0..2*S*NK-1
    int lane = threadIdx.x & 63;
    int isk = gw >= S_LEN * NKH;
    int r = gw - isk * S_LEN * NKH;
    int s = r / NKH, kh = r % NKH;
    const float* src = mixed + (size_t)s * CONV_DIM + isk * KEY_DIM + kh * DKD;
    float2 x = *(const float2*)(src + lane * 2);
    float ss = x.x * x.x + x.y * x.y;
#pragma unroll
    for (int m = 1; m < 64; m <<= 1) ss += __shfl_xor(ss, m, 64);
    float scale = rsqrtf(ss + 1e-6f);
    if (!isk) scale *= 0.08838834764831843f;   // DK^-0.5
    float* dst = (isk ? kn : qn) + ((size_t)(s * NKH + kh)) * DKD + lane * 2;
    *(float2*)dst = make_float2(x.x * scale, x.y * scale);
}

// ================= Phase A: per (head, chunk) intra-chunk work ==============
// Builds A (strict-lower), solves (I-A)X = RHS for u and kcd via forward
// substitution, computes scores = (q k^T)*decay (incl. diagonal).
__global__ __launch_bounds__(256) void phaseA_kernel(
    const float* __restrict__ qn, const float* __restrict__ kn,
    const float* __restrict__ mixed, const float* __restrict__ gbuf,
    const float* __restrict__ betabuf,
    float* __restrict__ u, float* __restrict__ kcd,
    float* __restrict__ scores, float* __restrict__ gcs_out)
{
    extern __shared__ float sm[];
    float (*ks)[132]  = (float(*)[132])(sm);
    float (*XU)[132]  = (float(*)[132])(sm + 64 * 132);
    float (*XK)[132]  = (float(*)[132])(sm + 2 * 64 * 132);
    float (*Asm)[68]  = (float(*)[68])(sm + 3 * 64 * 132);
    float* gcs_s = sm + 3 * 64 * 132 + 64 * 68;
    float* bet_s = gcs_s + 64;

    const int n = blockIdx.x, h = blockIdx.y, kh = h >> 1;
    const int tid = threadIdx.x;
    const int s0 = n * CCH;

    if (tid < 64) {
        float gv = gbuf[(size_t)(s0 + tid) * NVH + h];
#pragma unroll
        for (int off = 1; off < 64; off <<= 1) {
            float pv = __shfl_up(gv, off, 64);
            if (tid >= off) gv += pv;
        }
        gcs_s[tid] = gv;                              // inclusive cumsum in chunk
        bet_s[tid] = betabuf[(size_t)(s0 + tid) * NVH + h];
        gcs_out[(size_t)h * S_LEN + s0 + tid] = gv;
    }
    {
        const int r = tid >> 2, c0 = (tid & 3) * 32;
        const float* src = kn + ((size_t)(s0 + r) * NKH + kh) * DKD + c0;
#pragma unroll
        for (int j = 0; j < 32; j += 4)
            *(float4*)&ks[r][c0 + j] = *(const float4*)(src + j);
    }
    __syncthreads();

    // A[i][j] = -beta_i (k_i . k_j) exp(gcs_i - gcs_j), i>j (else 0)
    {
        const int i0 = (tid >> 4) * 4, jx = tid & 15;
        float acc[4][4];
#pragma unroll
        for (int ii = 0; ii < 4; ++ii)
#pragma unroll
            for (int jj = 0; jj < 4; ++jj) acc[ii][jj] = 0.f;
        for (int d = 0; d < DKD; d += 4) {
            float4 av[4], bv[4];
#pragma unroll
            for (int ii = 0; ii < 4; ++ii) av[ii] = *(const float4*)&ks[i0 + ii][d];
#pragma unroll
            for (int jj = 0; jj < 4; ++jj) bv[jj] = *(const float4*)&ks[jx + 16 * jj][d];
#pragma unroll
            for (int ii = 0; ii < 4; ++ii)
#pragma unroll
                for (int jj = 0; jj < 4; ++jj)
                    acc[ii][jj] += av[ii].x * bv[jj].x + av[ii].y * bv[jj].y
                                 + av[ii].z * bv[jj].z + av[ii].w * bv[jj].w;
        }
#pragma unroll
        for (int ii = 0; ii < 4; ++ii)
#pragma unroll
            for (int jj = 0; jj < 4; ++jj) {
                int i = i0 + ii, j = jx + 16 * jj;
                Asm[i][j] = (i > j) ? (-bet_s[i] * acc[ii][jj] * __expf(gcs_s[i] - gcs_s[j])) : 0.f;
            }
    }
    // RHS: XU = v*beta ; XK = k*beta*exp(gcs)
    {
        const int r = tid >> 2, c0 = (tid & 3) * 32;
        const float bv = bet_s[r];
        const float f = bv * __expf(gcs_s[r]);
        const float* vsrc = mixed + (size_t)(s0 + r) * CONV_DIM + 2 * KEY_DIM + h * DVD + c0;
#pragma unroll
        for (int j = 0; j < 32; j += 4) {
            float4 v4 = *(const float4*)(vsrc + j);
            float4 k4 = *(const float4*)&ks[r][c0 + j];
            XU[r][c0 + j + 0] = v4.x * bv; XU[r][c0 + j + 1] = v4.y * bv;
            XU[r][c0 + j + 2] = v4.z * bv; XU[r][c0 + j + 3] = v4.w * bv;
            XK[r][c0 + j + 0] = k4.x * f;  XK[r][c0 + j + 1] = k4.y * f;
            XK[r][c0 + j + 2] = k4.z * f;  XK[r][c0 + j + 3] = k4.w * f;
        }
    }
    __syncthreads();

    // forward substitution: X_i = RHS_i + sum_{k<i} A[i][k] X_k  (column-parallel)
    {
        const int d = tid & 127;
        float (*X)[132] = (tid >> 7) ? XK : XU;
        for (int i = 1; i < CCH; ++i) {
            const float* Ai = Asm[i];
            float r = 0.f;
            int k = 0;
            for (; k + 4 <= i; k += 4)
                r += Ai[k] * X[k][d] + Ai[k + 1] * X[k + 1][d]
                   + Ai[k + 2] * X[k + 2][d] + Ai[k + 3] * X[k + 3][d];
            for (; k < i; ++k) r += Ai[k] * X[k][d];
            X[i][d] += r;
            __syncthreads();
        }
    }
    // store u, kcd; then load q into XU (thread-local element ownership)
    {
        const int r = tid >> 2, c0 = (tid & 3) * 32;
        const size_t base = ((size_t)(h * NCHK + n) * CCH + r) * DVD + c0;
#pragma unroll
        for (int j = 0; j < 32; j += 4) {
            *(float4*)(u + base + j)   = *(const float4*)&XU[r][c0 + j];
            *(float4*)(kcd + base + j) = *(const float4*)&XK[r][c0 + j];
        }
        const float* qsrc = qn + ((size_t)(s0 + r) * NKH + kh) * DKD + c0;
#pragma unroll
        for (int j = 0; j < 32; j += 4)
            *(float4*)&XU[r][c0 + j] = *(const float4*)(qsrc + j);
    }
    __syncthreads();

    // scores[i][j] = (q_i . k_j) * exp(gcs_i - gcs_j) for i>=j else 0
    {
        const int i0 = (tid >> 4) * 4, jx = tid & 15;
        float acc[4][4];
#pragma unroll
        for (int ii = 0; ii < 4; ++ii)
#pragma unroll
            for (int jj = 0; jj < 4; ++jj) acc[ii][jj] = 0.f;
        for (int d = 0; d < DKD; d += 4) {
            float4 av[4], bv[4];
#pragma unroll
            for (int ii = 0; ii < 4; ++ii) av[ii] = *(const float4*)&XU[i0 + ii][d];
#pragma unroll
            for (int jj = 0; jj < 4; ++jj) bv[jj] = *(const float4*)&ks[jx + 16 * jj][d];
#pragma unroll
            for (int ii = 0; ii < 4; ++ii)
#pragma unroll
                for (int jj = 0; jj < 4; ++jj)
                    acc[ii][jj] += av[ii].x * bv[jj].x + av[ii].y * bv[jj].y
                                 + av[ii].z * bv[jj].z + av[ii].w * bv[jj].w;
        }
#pragma unroll
        for (int ii = 0; ii < 4; ++ii)
#pragma unroll
            for (int jj = 0; jj < 4; ++jj) {
                int i = i0 + ii, j = jx + 16 * jj;
                float v = (i >= j) ? acc[ii][jj] * __expf(gcs_s[i] - gcs_s[j]) : 0.f;
                scores[((size_t)(h * NCHK + n) * CCH + i) * CCH + j] = v;
            }
    }
}

// ================= Phase B: inter-chunk state scan (per head x 16-col slice) =
__global__ __launch_bounds__(256) void phaseB_kernel(
    const float* __restrict__ qn, const float* __restrict__ kn,
    const float* __restrict__ u, const float* __restrict__ kcd,
    const float* __restrict__ scores, const float* __restrict__ gcs,
    float* __restrict__ obuf)
{
    extern __shared__ float sm[];
    float (*qs)[132]   = (float(*)[132])(sm);
    float (*ks2)[132]  = (float(*)[132])(sm + 64 * 132);
    float (*kcds)[132] = (float(*)[132])(sm + 2 * 64 * 132);
    float (*sc)[68]    = (float(*)[68])(sm + 3 * 64 * 132);
    float (*us)[20]    = (float(*)[20])(sm + 3 * 64 * 132 + 64 * 68);
    float (*vn)[20]    = (float(*)[20])(sm + 3 * 64 * 132 + 64 * 68 + 64 * 20);
    float (*st)[20]    = (float(*)[20])(sm + 3 * 64 * 132 + 64 * 68 + 2 * 64 * 20);
    float* gcs_s = sm + 3 * 64 * 132 + 64 * 68 + 2 * 64 * 20 + 128 * 20;

    const int dvb = blockIdx.x;          // 0..7
    const int h = blockIdx.y;            // 0..31
    const int kh = h >> 1;
    const int d0 = dvb * 16;
    const int tid = threadIdx.x;

    for (int i = tid; i < 128 * 20; i += 256) ((float*)st)[i] = 0.f;

    const int r  = tid >> 2;             // 0..63
    const int c0 = (tid & 3) * 32;
    const int dq = tid & 3;

    for (int n = 0; n < NCHK; ++n) {
        const int s0 = n * CCH;
        __syncthreads();   // prev-iter LDS readers done before overwrite
        {
            const float* qsrc = qn + ((size_t)(s0 + r) * NKH + kh) * DKD + c0;
            const float* ksrc = kn + ((size_t)(s0 + r) * NKH + kh) * DKD + c0;
            const size_t ukb = ((size_t)(h * NCHK + n) * CCH + r) * DVD + c0;
#pragma unroll
            for (int j = 0; j < 32; j += 4) {
                *(float4*)&qs[r][c0 + j]   = *(const float4*)(qsrc + j);
                *(float4*)&ks2[r][c0 + j]  = *(const float4*)(ksrc + j);
                *(float4*)&kcds[r][c0 + j] = *(const float4*)(kcd + ukb + j);
            }
            const size_t sb = ((size_t)(h * NCHK + n) * CCH + r) * CCH + (tid & 3) * 16;
#pragma unroll
            for (int j = 0; j < 16; j += 4)
                *(float4*)&sc[r][(tid & 3) * 16 + j] = *(const float4*)(scores + sb + j);
            const size_t ub = ((size_t)(h * NCHK + n) * CCH + r) * DVD + d0 + dq * 4;
            *(float4*)&us[r][dq * 4] = *(const float4*)(u + ub);
            if (tid < 64) gcs_s[tid] = gcs[(size_t)h * S_LEN + s0 + tid];
        }
        __syncthreads();
        const float gl = gcs_s[63];

        // v_new = u - kcd @ state          (thread: row r, cols d0+4dq..+3)
        {
            float4 acc = *(const float4*)&us[r][dq * 4];
            for (int dk = 0; dk < DKD; ++dk) {
                float kv = kcds[r][dk];
                float4 s4 = *(const float4*)&st[dk][dq * 4];
                acc.x -= kv * s4.x; acc.y -= kv * s4.y;
                acc.z -= kv * s4.z; acc.w -= kv * s4.w;
            }
            *(float4*)&vn[r][dq * 4] = acc;
        }
        __syncthreads();

        // o = exp(gcs_r) * q_r @ state + scores_r @ v_new
        {
            float4 o4 = make_float4(0.f, 0.f, 0.f, 0.f);
            for (int dk = 0; dk < DKD; ++dk) {
                float qv = qs[r][dk];
                float4 s4 = *(const float4*)&st[dk][dq * 4];
                o4.x = fmaf(qv, s4.x, o4.x); o4.y = fmaf(qv, s4.y, o4.y);
                o4.z = fmaf(qv, s4.z, o4.z); o4.w = fmaf(qv, s4.w, o4.w);
            }
            float eg = __expf(gcs_s[r]);
            o4.x *= eg; o4.y *= eg; o4.z *= eg; o4.w *= eg;
            for (int c2 = 0; c2 < CCH; ++c2) {
                float sv = sc[r][c2];
                float4 v4 = *(const float4*)&vn[c2][dq * 4];
                o4.x = fmaf(sv, v4.x, o4.x); o4.y = fmaf(sv, v4.y, o4.y);
                o4.z = fmaf(sv, v4.z, o4.z); o4.w = fmaf(sv, v4.w, o4.w);
            }
            *(float4*)(obuf + (size_t)(s0 + r) * VAL_DIM + h * DVD + d0 + dq * 4) = o4;
        }
        __syncthreads();   // state readers (old) done before update

        // state = exp(gl)*state + sum_c exp(gl-gcs_c) k_c (x) v_new_c
        {
            const int dk = tid & 127, hf = tid >> 7;
            const float egl = __expf(gl);
            float stv[8];
#pragma unroll
            for (int j = 0; j < 8; ++j) stv[j] = st[dk][hf * 8 + j] * egl;
            for (int c = 0; c < CCH; ++c) {
                float kf = ks2[c][dk] * __expf(gl - gcs_s[c]);
#pragma unroll
                for (int j = 0; j < 8; ++j) stv[j] = fmaf(kf, vn[c][hf * 8 + j], stv[j]);
            }
#pragma unroll
            for (int j = 0; j < 8; ++j) st[dk][hf * 8 + j] = stv[j];
        }
    }
}

// ================= RMSNorm * norm_w * silu(z) ===============================
__global__ __launch_bounds__(256) void norm_kernel(
    const float* __restrict__ obuf, const float* __restrict__ z,
    const float* __restrict__ nw, float* __restrict__ hbuf)
{
    int row = (blockIdx.x * 256 + threadIdx.x) >> 6;   // S*NV rows
    int lane = threadIdx.x & 63;
    float2 x = *(const float2*)(obuf + (size_t)row * DVD + lane * 2);
    float ss = x.x * x.x + x.y * x.y;
#pragma unroll
    for (int m = 1; m < 64; m <<= 1) ss += __shfl_xor(ss, m, 64);
    float scale = rsqrtf(ss * (1.f / DVD) + 1e-6f);
    float2 zz = *(const float2*)(z + (size_t)row * DVD + lane * 2);
    float2 w2 = *(const float2*)(nw + lane * 2);
    float h0 = x.x * scale * w2.x * silu_f(zz.x);
    float h1 = x.y * scale * w2.y * silu_f(zz.y);
    *(float2*)(hbuf + (size_t)row * DVD + lane * 2) = make_float2(h0, h1);
}

// ============================================================================
extern "C" void kernel_launch(void* const* d_in, const int* in_sizes, int n_in,
                              void* d_out, int out_size, void* d_ws, size_t ws_size,
                              hipStream_t stream)
{
    (void)in_sizes; (void)n_in; (void)out_size; (void)ws_size;
    const float* x      = (const float*)d_in[0];
    const float* W_qkv  = (const float*)d_in[1];
    const float* W_z    = (const float*)d_in[2];
    const float* W_a    = (const float*)d_in[3];
    const float* W_b    = (const float*)d_in[4];
    const float* conv_w = (const float*)d_in[5];
    const float* dt_b   = (const float*)d_in[6];
    const float* A_log  = (const float*)d_in[7];
    const float* norm_w = (const float*)d_in[8];
    const float* W_out  = (const float*)d_in[9];
    float* out = (float*)d_out;

    // workspace layout (floats); peak ~219.4 MB
    float* ws = (float*)d_ws;
    float* mixed_pre = ws;                           // 16.78M (dead after conv)
    float* u_buf     = ws;                           // reuse: 8.39M
    float* kcd_buf   = ws + (size_t)8388608;         // 8.39M
    float* mixed     = ws + (size_t)16777216;        // 16.78M (dead after phaseA)
    float* obuf      = ws + (size_t)16777216;        // reuse: 8.39M
    float* hbuf      = ws + (size_t)25165824;        // reuse: 8.39M
    float* z_buf     = ws + (size_t)33554432;        // 8.39M
    float* sc_buf    = ws + (size_t)41943040;        // 4.19M
    float* qn        = ws + (size_t)46137344;        // 4.19M
    float* kn        = ws + (size_t)50331648;        // 4.19M
    float* gcs_buf   = ws + (size_t)54525952;        // 65K
    float* g_buf     = ws + (size_t)54591488;        // 65K
    float* bet_buf   = ws + (size_t)54657024;        // 65K
    float* a_buf     = ws + (size_t)54722560;        // 65K
    float* b_buf     = ws + (size_t)54788096;        // 65K

    hipFuncSetAttribute((const void*)phaseA_kernel,
                        hipFuncAttributeMaxDynamicSharedMemorySize, PA_LDS_FLOATS * 4);
    hipFuncSetAttribute((const void*)phaseB_kernel,
                        hipFuncAttributeMaxDynamicSharedMemorySize, PB_LDS_FLOATS * 4);

    dim3 blk(256);
    // 1) projections
    gemm_nt_kernel<<<dim3(CONV_DIM / 128, S_LEN / 128), blk, 0, stream>>>(x, W_qkv, mixed_pre, S_LEN, CONV_DIM, HIDDIM);
    gemm_nt_kernel<<<dim3(VAL_DIM / 128, S_LEN / 128), blk, 0, stream>>>(x, W_z, z_buf, S_LEN, VAL_DIM, HIDDIM);
    gemm_nt_kernel<<<dim3(1, S_LEN / 128), blk, 0, stream>>>(x, W_a, a_buf, S_LEN, NVH, HIDDIM);
    gemm_nt_kernel<<<dim3(1, S_LEN / 128), blk, 0, stream>>>(x, W_b, b_buf, S_LEN, NVH, HIDDIM);
    // 2) conv + silu
    conv_silu_kernel<<<(S_LEN * CONV_DIM / 4) / 256, blk, 0, stream>>>(mixed_pre, conv_w, mixed);
    // 3) gates
    gb_kernel<<<(S_LEN * NVH) / 256, blk, 0, stream>>>(a_buf, b_buf, dt_b, A_log, g_buf, bet_buf);
    // 4) l2norm q,k
    l2norm_kernel<<<(2 * S_LEN * NKH * 64) / 256, blk, 0, stream>>>(mixed, qn, kn);
    // 5) phase A (intra-chunk)
    phaseA_kernel<<<dim3(NCHK, NVH), blk, PA_LDS_FLOATS * 4, stream>>>(
        qn, kn, mixed, g_buf, bet_buf, u_buf, kcd_buf, sc_buf, gcs_buf);
    // 6) phase B (inter-chunk scan)
    phaseB_kernel<<<dim3(8, NVH), blk, PB_LDS_FLOATS * 4, stream>>>(
        qn, kn, u_buf, kcd_buf, sc_buf, gcs_buf, obuf);
    // 7) gated RMSNorm
    norm_kernel<<<(S_LEN * NVH * 64) / 256, blk, 0, stream>>>(obuf, z_buf, norm_w, hbuf);
    // 8) output projection
    gemm_nt_kernel<<<dim3(HIDDIM / 128, S_LEN / 128), blk, 0, stream>>>(hbuf, W_out, out, S_LEN, HIDDIM, VAL_DIM);
}

// Round 2
// 1333.816 us; speedup vs baseline: 2.6230x; 2.6230x over previous
//
#include <hip/hip_runtime.h>
#include <hip/hip_bf16.h>
#include <math.h>

// ---- problem constants ----
#define S_LEN   2048
#define HIDDIM  2048
#define NKH     16
#define NVH     32
#define DKD     128
#define DVD     128
#define CCH     64          // chunk
#define NCHK    32          // S/chunk
#define KEY_DIM 2048
#define VAL_DIM 4096
#define CONV_DIM 8192

#define PA_LDS_FLOATS (3*64*132 + 64*68 + 128)
#define PB_LDS_FLOATS (3*64*132 + 64*68 + 64*20 + 64*20 + 128*20 + 64)

typedef __bf16 bf16x8 __attribute__((ext_vector_type(8)));
typedef float f32x4 __attribute__((ext_vector_type(4)));

__device__ __forceinline__ float sigmoid_f(float x) { return 1.f / (1.f + __expf(-x)); }
__device__ __forceinline__ float silu_f(float x) { return x * sigmoid_f(x); }
__device__ __forceinline__ ushort f2bf(float f) {
    unsigned u = __float_as_uint(f);
    u += 0x7fffu + ((u >> 16) & 1u);          // RNE (inputs finite)
    return (ushort)(u >> 16);
}

// ================= fp32 -> bf16 cast (8 elems/thread) =======================
__global__ __launch_bounds__(256) void cast_kernel(
    const float* __restrict__ in, ushort* __restrict__ out, int n8)
{
    int t = blockIdx.x * 256 + threadIdx.x;
    if (t >= n8) return;
    float4 v0 = *(const float4*)(in + (size_t)t * 8);
    float4 v1 = *(const float4*)(in + (size_t)t * 8 + 4);
    union { ushort u[8]; uint4 v; } r;
    r.u[0] = f2bf(v0.x); r.u[1] = f2bf(v0.y); r.u[2] = f2bf(v0.z); r.u[3] = f2bf(v0.w);
    r.u[4] = f2bf(v1.x); r.u[5] = f2bf(v1.y); r.u[6] = f2bf(v1.z); r.u[7] = f2bf(v1.w);
    *(uint4*)(out + (size_t)t * 8) = r.v;
}

// ====== W_a,W_b -> one padded bf16 weight [128,2048] (rows 64..127 zero) ====
__global__ __launch_bounds__(256) void cast_ab_kernel(
    const float* __restrict__ Wa, const float* __restrict__ Wb, ushort* __restrict__ out)
{
    int t = blockIdx.x * 256 + threadIdx.x;          // 128*2048/8 = 32768 threads
    int row = t >> 8;
    int c8 = (t & 255) * 8;
    union { ushort u[8]; uint4 v; } r;
    if (row < 64) {
        const float* src = (row < 32) ? (Wa + (size_t)row * HIDDIM + c8)
                                      : (Wb + (size_t)(row - 32) * HIDDIM + c8);
        float4 v0 = *(const float4*)(src);
        float4 v1 = *(const float4*)(src + 4);
        r.u[0] = f2bf(v0.x); r.u[1] = f2bf(v0.y); r.u[2] = f2bf(v0.z); r.u[3] = f2bf(v0.w);
        r.u[4] = f2bf(v1.x); r.u[5] = f2bf(v1.y); r.u[6] = f2bf(v1.z); r.u[7] = f2bf(v1.w);
    } else {
        r.u[0] = r.u[1] = r.u[2] = r.u[3] = r.u[4] = r.u[5] = r.u[6] = r.u[7] = 0;
    }
    *(uint4*)(out + (size_t)t * 8) = r.v;
}

// ================= bf16 MFMA GEMM: C[M,N] = A[M,K] @ B[N,K]^T (f32 out) =====
// m97 structure: 128x128 tile, BK=32, 256 thr = 4 waves (2x2), 4x4 16x16x32
// fragments per wave, global_load_lds width-16 staging, linear LDS.
__global__ __launch_bounds__(256) void gemm_bf16_kernel(
    const ushort* __restrict__ A, const ushort* __restrict__ B, float* __restrict__ C,
    int M, int N, int K)
{
    __shared__ ushort Alds[128 * 32];
    __shared__ ushort Blds[128 * 32];
    const int tid = threadIdx.x;
    const int wv = tid >> 6, ln = tid & 63;
    const int bm = blockIdx.y * 128, bn = blockIdx.x * 128;
    const int wr = (wv >> 1) * 64, wc = (wv & 1) * 64;   // wave origin in tile
    const int lrow = ln & 15, lkg = ln >> 4;             // fragment lane decomp

    f32x4 acc[4][4];
#pragma unroll
    for (int m = 0; m < 4; ++m)
#pragma unroll
        for (int n = 0; n < 4; ++n) {
            f32x4 z = {0.f, 0.f, 0.f, 0.f};
            acc[m][n] = z;
        }

    // staging granules: g = round*256 + tid ; row = g>>2, k8 = (g&3)*8
    const int arow = tid >> 2, ak8 = (tid & 3) * 8;
    const ushort* srcA0 = A + (size_t)(bm + arow) * K + ak8;
    const ushort* srcA1 = A + (size_t)(bm + 64 + arow) * K + ak8;
    const ushort* srcB0 = B + (size_t)(bn + arow) * K + ak8;
    const ushort* srcB1 = B + (size_t)(bn + 64 + arow) * K + ak8;
    // wave-uniform LDS dests (granule base of this wave's 64 lanes)
    ushort* dstA0 = &Alds[(size_t)(wv * 64) * 8];
    ushort* dstA1 = &Alds[(size_t)(256 + wv * 64) * 8];
    ushort* dstB0 = &Blds[(size_t)(wv * 64) * 8];
    ushort* dstB1 = &Blds[(size_t)(256 + wv * 64) * 8];

    for (int k0 = 0; k0 < K; k0 += 32) {
        __builtin_amdgcn_global_load_lds(
            (const __attribute__((address_space(1))) void*)(srcA0 + k0),
            (__attribute__((address_space(3))) void*)dstA0, 16, 0, 0);
        __builtin_amdgcn_global_load_lds(
            (const __attribute__((address_space(1))) void*)(srcA1 + k0),
            (__attribute__((address_space(3))) void*)dstA1, 16, 0, 0);
        __builtin_amdgcn_global_load_lds(
            (const __attribute__((address_space(1))) void*)(srcB0 + k0),
            (__attribute__((address_space(3))) void*)dstB0, 16, 0, 0);
        __builtin_amdgcn_global_load_lds(
            (const __attribute__((address_space(1))) void*)(srcB1 + k0),
            (__attribute__((address_space(3))) void*)dstB1, 16, 0, 0);
        __syncthreads();   // drains vmcnt -> LDS tile ready

        bf16x8 af[4], bfr[4];
#pragma unroll
        for (int m = 0; m < 4; ++m)
            af[m] = *(const bf16x8*)&Alds[(size_t)(wr + m * 16 + lrow) * 32 + lkg * 8];
#pragma unroll
        for (int n = 0; n < 4; ++n)
            bfr[n] = *(const bf16x8*)&Blds[(size_t)(wc + n * 16 + lrow) * 32 + lkg * 8];
#pragma unroll
        for (int m = 0; m < 4; ++m)
#pragma unroll
            for (int n = 0; n < 4; ++n)
                acc[m][n] = __builtin_amdgcn_mfma_f32_16x16x32_bf16(
                    af[m], bfr[n], acc[m][n], 0, 0, 0);
        __syncthreads();   // frag reads done before next-stage overwrite
    }

    // epilogue: C/D layout col=lane&15, row=(lane>>4)*4+j  [m89/m91]
#pragma unroll
    for (int m = 0; m < 4; ++m) {
        int row0 = bm + wr + m * 16 + lkg * 4;
#pragma unroll
        for (int n = 0; n < 4; ++n) {
            int col = bn + wc + n * 16 + lrow;
            float* cp = C + (size_t)row0 * N + col;
#pragma unroll
            for (int j = 0; j < 4; ++j) cp[(size_t)j * N] = acc[m][n][j];
        }
    }
}

// ================= causal depthwise conv1d (K=4) + SiLU =====================
__global__ __launch_bounds__(256) void conv_silu_kernel(
    const float* __restrict__ pre, const float* __restrict__ cw, float* __restrict__ out)
{
    int idx = blockIdx.x * 256 + threadIdx.x;       // S*CONV_DIM/4 threads
    const int NC4 = CONV_DIM / 4;
    int s = idx / NC4;
    int c = (idx % NC4) * 4;
    float w[4][4];
#pragma unroll
    for (int j = 0; j < 4; ++j) {
        float4 wj = *(const float4*)(cw + (size_t)(c + j) * 4);
        w[j][0] = wj.x; w[j][1] = wj.y; w[j][2] = wj.z; w[j][3] = wj.w;
    }
    float acc[4] = {0.f, 0.f, 0.f, 0.f};
#pragma unroll
    for (int t = 0; t < 4; ++t) {
        int ss = s - 3 + t;
        if (ss >= 0) {
            float4 x = *(const float4*)(pre + (size_t)ss * CONV_DIM + c);
            acc[0] = fmaf(x.x, w[0][t], acc[0]);
            acc[1] = fmaf(x.y, w[1][t], acc[1]);
            acc[2] = fmaf(x.z, w[2][t], acc[2]);
            acc[3] = fmaf(x.w, w[3][t], acc[3]);
        }
    }
    float4 o = make_float4(silu_f(acc[0]), silu_f(acc[1]), silu_f(acc[2]), silu_f(acc[3]));
    *(float4*)(out + (size_t)s * CONV_DIM + c) = o;
}

// ====== g = -exp(A_log)*softplus(a+dt_bias), beta = sigmoid(b) ==============
// ab buffer layout: [S][128], a at cols 0..31, b at cols 32..63
__global__ __launch_bounds__(256) void gb_kernel(
    const float* __restrict__ ab, const float* __restrict__ dt_bias,
    const float* __restrict__ A_log, float* __restrict__ g, float* __restrict__ beta)
{
    int idx = blockIdx.x * 256 + threadIdx.x;       // S*NV threads
    int s = idx >> 5, h = idx & 31;
    float av = ab[(size_t)s * 128 + h] + dt_bias[h];
    float sp = (av > 20.f) ? av : log1pf(__expf(av));
    g[idx] = -__expf(A_log[h]) * sp;
    beta[idx] = sigmoid_f(ab[(size_t)s * 128 + 32 + h]);
}

// ================= l2norm of q,k rows (per original 16 heads) ===============
__global__ __launch_bounds__(256) void l2norm_kernel(
    const float* __restrict__ mixed, float* __restrict__ qn, float* __restrict__ kn)
{
    int gw = (blockIdx.x * 256 + threadIdx.x) >> 6;  // 0..2*S*NK-1
    int lane = threadIdx.x & 63;
    int isk = gw >= S_LEN * NKH;
    int r = gw - isk * S_LEN * NKH;
    int s = r / NKH, kh = r % NKH;
    const float* src = mixed + (size_t)s * CONV_DIM + isk * KEY_DIM + kh * DKD;
    float2 x = *(const float2*)(src + lane * 2);
    float ss = x.x * x.x + x.y * x.y;
#pragma unroll
    for (int m = 1; m < 64; m <<= 1) ss += __shfl_xor(ss, m, 64);
    float scale = rsqrtf(ss + 1e-6f);
    if (!isk) scale *= 0.08838834764831843f;   // DK^-0.5
    float* dst = (isk ? kn : qn) + ((size_t)(s * NKH + kh)) * DKD + lane * 2;
    *(float2*)dst = make_float2(x.x * scale, x.y * scale);
}

// ================= Phase A: per (head, chunk) intra-chunk work ==============
__global__ __launch_bounds__(256) void phaseA_kernel(
    const float* __restrict__ qn, const float* __restrict__ kn,
    const float* __restrict__ mixed, const float* __restrict__ gbuf,
    const float* __restrict__ betabuf,
    float* __restrict__ u, float* __restrict__ kcd,
    float* __restrict__ scores, float* __restrict__ gcs_out)
{
    extern __shared__ float sm[];
    float (*ks)[132]  = (float(*)[132])(sm);
    float (*XU)[132]  = (float(*)[132])(sm + 64 * 132);
    float (*XK)[132]  = (float(*)[132])(sm + 2 * 64 * 132);
    float (*Asm)[68]  = (float(*)[68])(sm + 3 * 64 * 132);
    float* gcs_s = sm + 3 * 64 * 132 + 64 * 68;
    float* bet_s = gcs_s + 64;

    const int n = blockIdx.x, h = blockIdx.y, kh = h >> 1;
    const int tid = threadIdx.x;
    const int s0 = n * CCH;

    if (tid < 64) {
        float gv = gbuf[(size_t)(s0 + tid) * NVH + h];
#pragma unroll
        for (int off = 1; off < 64; off <<= 1) {
            float pv = __shfl_up(gv, off, 64);
            if (tid >= off) gv += pv;
        }
        gcs_s[tid] = gv;
        bet_s[tid] = betabuf[(size_t)(s0 + tid) * NVH + h];
        gcs_out[(size_t)h * S_LEN + s0 + tid] = gv;
    }
    {
        const int r = tid >> 2, c0 = (tid & 3) * 32;
        const float* src = kn + ((size_t)(s0 + r) * NKH + kh) * DKD + c0;
#pragma unroll
        for (int j = 0; j < 32; j += 4)
            *(float4*)&ks[r][c0 + j] = *(const float4*)(src + j);
    }
    __syncthreads();

    {
        const int i0 = (tid >> 4) * 4, jx = tid & 15;
        float acc[4][4];
#pragma unroll
        for (int ii = 0; ii < 4; ++ii)
#pragma unroll
            for (int jj = 0; jj < 4; ++jj) acc[ii][jj] = 0.f;
        for (int d = 0; d < DKD; d += 4) {
            float4 av[4], bv[4];
#pragma unroll
            for (int ii = 0; ii < 4; ++ii) av[ii] = *(const float4*)&ks[i0 + ii][d];
#pragma unroll
            for (int jj = 0; jj < 4; ++jj) bv[jj] = *(const float4*)&ks[jx + 16 * jj][d];
#pragma unroll
            for (int ii = 0; ii < 4; ++ii)
#pragma unroll
                for (int jj = 0; jj < 4; ++jj)
                    acc[ii][jj] += av[ii].x * bv[jj].x + av[ii].y * bv[jj].y
                                 + av[ii].z * bv[jj].z + av[ii].w * bv[jj].w;
        }
#pragma unroll
        for (int ii = 0; ii < 4; ++ii)
#pragma unroll
            for (int jj = 0; jj < 4; ++jj) {
                int i = i0 + ii, j = jx + 16 * jj;
                Asm[i][j] = (i > j) ? (-bet_s[i] * acc[ii][jj] * __expf(gcs_s[i] - gcs_s[j])) : 0.f;
            }
    }
    {
        const int r = tid >> 2, c0 = (tid & 3) * 32;
        const float bv = bet_s[r];
        const float f = bv * __expf(gcs_s[r]);
        const float* vsrc = mixed + (size_t)(s0 + r) * CONV_DIM + 2 * KEY_DIM + h * DVD + c0;
#pragma unroll
        for (int j = 0; j < 32; j += 4) {
            float4 v4 = *(const float4*)(vsrc + j);
            float4 k4 = *(const float4*)&ks[r][c0 + j];
            XU[r][c0 + j + 0] = v4.x * bv; XU[r][c0 + j + 1] = v4.y * bv;
            XU[r][c0 + j + 2] = v4.z * bv; XU[r][c0 + j + 3] = v4.w * bv;
            XK[r][c0 + j + 0] = k4.x * f;  XK[r][c0 + j + 1] = k4.y * f;
            XK[r][c0 + j + 2] = k4.z * f;  XK[r][c0 + j + 3] = k4.w * f;
        }
    }
    __syncthreads();

    {
        const int d = tid & 127;
        float (*X)[132] = (tid >> 7) ? XK : XU;
        for (int i = 1; i < CCH; ++i) {
            const float* Ai = Asm[i];
            float r = 0.f;
            int k = 0;
            for (; k + 4 <= i; k += 4)
                r += Ai[k] * X[k][d] + Ai[k + 1] * X[k + 1][d]
                   + Ai[k + 2] * X[k + 2][d] + Ai[k + 3] * X[k + 3][d];
            for (; k < i; ++k) r += Ai[k] * X[k][d];
            X[i][d] += r;
            __syncthreads();
        }
    }
    {
        const int r = tid >> 2, c0 = (tid & 3) * 32;
        const size_t base = ((size_t)(h * NCHK + n) * CCH + r) * DVD + c0;
#pragma unroll
        for (int j = 0; j < 32; j += 4) {
            *(float4*)(u + base + j)   = *(const float4*)&XU[r][c0 + j];
            *(float4*)(kcd + base + j) = *(const float4*)&XK[r][c0 + j];
        }
        const float* qsrc = qn + ((size_t)(s0 + r) * NKH + kh) * DKD + c0;
#pragma unroll
        for (int j = 0; j < 32; j += 4)
            *(float4*)&XU[r][c0 + j] = *(const float4*)(qsrc + j);
    }
    __syncthreads();

    {
        const int i0 = (tid >> 4) * 4, jx = tid & 15;
        float acc[4][4];
#pragma unroll
        for (int ii = 0; ii < 4; ++ii)
#pragma unroll
            for (int jj = 0; jj < 4; ++jj) acc[ii][jj] = 0.f;
        for (int d = 0; d < DKD; d += 4) {
            float4 av[4], bv[4];
#pragma unroll
            for (int ii = 0; ii < 4; ++ii) av[ii] = *(const float4*)&XU[i0 + ii][d];
#pragma unroll
            for (int jj = 0; jj < 4; ++jj) bv[jj] = *(const float4*)&ks[jx + 16 * jj][d];
#pragma unroll
            for (int ii = 0; ii < 4; ++ii)
#pragma unroll
                for (int jj = 0; jj < 4; ++jj)
                    acc[ii][jj] += av[ii].x * bv[jj].x + av[ii].y * bv[jj].y
                                 + av[ii].z * bv[jj].z + av[ii].w * bv[jj].w;
        }
#pragma unroll
        for (int ii = 0; ii < 4; ++ii)
#pragma unroll
            for (int jj = 0; jj < 4; ++jj) {
                int i = i0 + ii, j = jx + 16 * jj;
                float v = (i >= j) ? acc[ii][jj] * __expf(gcs_s[i] - gcs_s[j]) : 0.f;
                scores[((size_t)(h * NCHK + n) * CCH + i) * CCH + j] = v;
            }
    }
}

// ================= Phase B: inter-chunk state scan ==========================
__global__ __launch_bounds__(256) void phaseB_kernel(
    const float* __restrict__ qn, const float* __restrict__ kn,
    const float* __restrict__ u, const float* __restrict__ kcd,
    const float* __restrict__ scores, const float* __restrict__ gcs,
    float* __restrict__ obuf)
{
    extern __shared__ float sm[];
    float (*qs)[132]   = (float(*)[132])(sm);
    float (*ks2)[132]  = (float(*)[132])(sm + 64 * 132);
    float (*kcds)[132] = (float(*)[132])(sm + 2 * 64 * 132);
    float (*sc)[68]    = (float(*)[68])(sm + 3 * 64 * 132);
    float (*us)[20]    = (float(*)[20])(sm + 3 * 64 * 132 + 64 * 68);
    float (*vn)[20]    = (float(*)[20])(sm + 3 * 64 * 132 + 64 * 68 + 64 * 20);
    float (*st)[20]    = (float(*)[20])(sm + 3 * 64 * 132 + 64 * 68 + 2 * 64 * 20);
    float* gcs_s = sm + 3 * 64 * 132 + 64 * 68 + 2 * 64 * 20 + 128 * 20;

    const int dvb = blockIdx.x;          // 0..7
    const int h = blockIdx.y;            // 0..31
    const int kh = h >> 1;
    const int d0 = dvb * 16;
    const int tid = threadIdx.x;

    for (int i = tid; i < 128 * 20; i += 256) ((float*)st)[i] = 0.f;

    const int r  = tid >> 2;             // 0..63
    const int c0 = (tid & 3) * 32;
    const int dq = tid & 3;

    for (int n = 0; n < NCHK; ++n) {
        const int s0 = n * CCH;
        __syncthreads();
        {
            const float* qsrc = qn + ((size_t)(s0 + r) * NKH + kh) * DKD + c0;
            const float* ksrc = kn + ((size_t)(s0 + r) * NKH + kh) * DKD + c0;
            const size_t ukb = ((size_t)(h * NCHK + n) * CCH + r) * DVD + c0;
#pragma unroll
            for (int j = 0; j < 32; j += 4) {
                *(float4*)&qs[r][c0 + j]   = *(const float4*)(qsrc + j);
                *(float4*)&ks2[r][c0 + j]  = *(const float4*)(ksrc + j);
                *(float4*)&kcds[r][c0 + j] = *(const float4*)(kcd + ukb + j);
            }
            const size_t sb = ((size_t)(h * NCHK + n) * CCH + r) * CCH + (tid & 3) * 16;
#pragma unroll
            for (int j = 0; j < 16; j += 4)
                *(float4*)&sc[r][(tid & 3) * 16 + j] = *(const float4*)(scores + sb + j);
            const size_t ub = ((size_t)(h * NCHK + n) * CCH + r) * DVD + d0 + dq * 4;
            *(float4*)&us[r][dq * 4] = *(const float4*)(u + ub);
            if (tid < 64) gcs_s[tid] = gcs[(size_t)h * S_LEN + s0 + tid];
        }
        __syncthreads();
        const float gl = gcs_s[63];

        {
            float4 acc = *(const float4*)&us[r][dq * 4];
            for (int dk = 0; dk < DKD; ++dk) {
                float kv = kcds[r][dk];
                float4 s4 = *(const float4*)&st[dk][dq * 4];
                acc.x -= kv * s4.x; acc.y -= kv * s4.y;
                acc.z -= kv * s4.z; acc.w -= kv * s4.w;
            }
            *(float4*)&vn[r][dq * 4] = acc;
        }
        __syncthreads();

        {
            float4 o4 = make_float4(0.f, 0.f, 0.f, 0.f);
            for (int dk = 0; dk < DKD; ++dk) {
                float qv = qs[r][dk];
                float4 s4 = *(const float4*)&st[dk][dq * 4];
                o4.x = fmaf(qv, s4.x, o4.x); o4.y = fmaf(qv, s4.y, o4.y);
                o4.z = fmaf(qv, s4.z, o4.z); o4.w = fmaf(qv, s4.w, o4.w);
            }
            float eg = __expf(gcs_s[r]);
            o4.x *= eg; o4.y *= eg; o4.z *= eg; o4.w *= eg;
            for (int c2 = 0; c2 < CCH; ++c2) {
                float sv = sc[r][c2];
                float4 v4 = *(const float4*)&vn[c2][dq * 4];
                o4.x = fmaf(sv, v4.x, o4.x); o4.y = fmaf(sv, v4.y, o4.y);
                o4.z = fmaf(sv, v4.z, o4.z); o4.w = fmaf(sv, v4.w, o4.w);
            }
            *(float4*)(obuf + (size_t)(s0 + r) * VAL_DIM + h * DVD + d0 + dq * 4) = o4;
        }
        __syncthreads();

        {
            const int dk = tid & 127, hf = tid >> 7;
            const float egl = __expf(gl);
            float stv[8];
#pragma unroll
            for (int j = 0; j < 8; ++j) stv[j] = st[dk][hf * 8 + j] * egl;
            for (int c = 0; c < CCH; ++c) {
                float kf = ks2[c][dk] * __expf(gl - gcs_s[c]);
#pragma unroll
                for (int j = 0; j < 8; ++j) stv[j] = fmaf(kf, vn[c][hf * 8 + j], stv[j]);
            }
#pragma unroll
            for (int j = 0; j < 8; ++j) st[dk][hf * 8 + j] = stv[j];
        }
    }
}

// ================= RMSNorm * norm_w * silu(z) -> bf16 =======================
__global__ __launch_bounds__(256) void norm_kernel(
    const float* __restrict__ obuf, const float* __restrict__ z,
    const float* __restrict__ nw, ushort* __restrict__ hbuf)
{
    int row = (blockIdx.x * 256 + threadIdx.x) >> 6;   // S*NV rows
    int lane = threadIdx.x & 63;
    float2 x = *(const float2*)(obuf + (size_t)row * DVD + lane * 2);
    float ss = x.x * x.x + x.y * x.y;
#pragma unroll
    for (int m = 1; m < 64; m <<= 1) ss += __shfl_xor(ss, m, 64);
    float scale = rsqrtf(ss * (1.f / DVD) + 1e-6f);
    float2 zz = *(const float2*)(z + (size_t)row * DVD + lane * 2);
    float2 w2 = *(const float2*)(nw + lane * 2);
    float h0 = x.x * scale * w2.x * silu_f(zz.x);
    float h1 = x.y * scale * w2.y * silu_f(zz.y);
    union { ushort u[2]; uint v; } r;
    r.u[0] = f2bf(h0); r.u[1] = f2bf(h1);
    *(uint*)(hbuf + (size_t)row * DVD + lane * 2) = r.v;
}

// ============================================================================
extern "C" void kernel_launch(void* const* d_in, const int* in_sizes, int n_in,
                              void* d_out, int out_size, void* d_ws, size_t ws_size,
                              hipStream_t stream)
{
    (void)in_sizes; (void)n_in; (void)out_size; (void)ws_size;
    const float* x      = (const float*)d_in[0];
    const float* W_qkv  = (const float*)d_in[1];
    const float* W_z    = (const float*)d_in[2];
    const float* W_a    = (const float*)d_in[3];
    const float* W_b    = (const float*)d_in[4];
    const float* conv_w = (const float*)d_in[5];
    const float* dt_b   = (const float*)d_in[6];
    const float* A_log  = (const float*)d_in[7];
    const float* norm_w = (const float*)d_in[8];
    const float* W_out  = (const float*)d_in[9];
    float* out = (float*)d_out;

    // ---- workspace layout (bytes), overlaid by liveness; total 218.9 MB ----
    char* ws = (char*)d_ws;
    // region A @0 (67,108,864 B): mixed_pre -> {u, kcd}
    float*  mixed_pre = (float*)(ws);
    float*  u_buf     = (float*)(ws);
    float*  kcd_buf   = (float*)(ws + 33554432);
    // region B @67,108,864 (67,108,864 B):
    //   steps 1-2: xb, wzb, wqkvb ; steps 3-6: mixed ; steps 7-9: obuf, hbuf, wob
    ushort* xb        = (ushort*)(ws + 67108864);
    ushort* wzb       = (ushort*)(ws + 75497472);
    ushort* wqkvb     = (ushort*)(ws + 92274688);
    float*  mixed     = (float*)(ws + 67108864);
    float*  obuf      = (float*)(ws + 67108864);
    ushort* hbuf      = (ushort*)(ws + 100663296);
    ushort* wob       = (ushort*)(ws + 117440512);
    // fixed regions
    float*  z_buf     = (float*)(ws + 134217728);      // 33,554,432
    float*  sc_buf    = (float*)(ws + 167772160);      // 16,777,216 (steps 6-7)
    ushort* wabb      = (ushort*)(ws + 167772160);     // 524,288 (steps 1-2, pre-sc)
    float*  ab_buf    = (float*)(ws + 168296448);      // 1,048,576 (steps 2-4, pre-sc)
    float*  qn        = (float*)(ws + 184549376);      // 16,777,216
    float*  kn        = (float*)(ws + 201326592);      // 16,777,216
    float*  g_buf     = (float*)(ws + 218103808);      // 262,144
    float*  bet_buf   = (float*)(ws + 218365952);      // 262,144
    float*  gcs_buf   = (float*)(ws + 218628096);      // 262,144 -> end 218,890,240

    hipFuncSetAttribute((const void*)phaseA_kernel,
                        hipFuncAttributeMaxDynamicSharedMemorySize, PA_LDS_FLOATS * 4);
    hipFuncSetAttribute((const void*)phaseB_kernel,
                        hipFuncAttributeMaxDynamicSharedMemorySize, PB_LDS_FLOATS * 4);

    dim3 blk(256);
    // 1) casts to bf16
    cast_kernel<<<(S_LEN * HIDDIM / 8) / 256, blk, 0, stream>>>(x, xb, S_LEN * HIDDIM / 8);
    cast_kernel<<<(CONV_DIM * HIDDIM / 8) / 256, blk, 0, stream>>>(W_qkv, wqkvb, CONV_DIM * HIDDIM / 8);
    cast_kernel<<<(VAL_DIM * HIDDIM / 8) / 256, blk, 0, stream>>>(W_z, wzb, VAL_DIM * HIDDIM / 8);
    cast_ab_kernel<<<(128 * HIDDIM / 8) / 256, blk, 0, stream>>>(W_a, W_b, wabb);
    // 2) projections (bf16 MFMA)
    gemm_bf16_kernel<<<dim3(CONV_DIM / 128, S_LEN / 128), blk, 0, stream>>>(xb, wqkvb, mixed_pre, S_LEN, CONV_DIM, HIDDIM);
    gemm_bf16_kernel<<<dim3(VAL_DIM / 128, S_LEN / 128), blk, 0, stream>>>(xb, wzb, z_buf, S_LEN, VAL_DIM, HIDDIM);
    gemm_bf16_kernel<<<dim3(1, S_LEN / 128), blk, 0, stream>>>(xb, wabb, ab_buf, S_LEN, 128, HIDDIM);
    // 3) conv + silu (fp32)
    conv_silu_kernel<<<(S_LEN * CONV_DIM / 4) / 256, blk, 0, stream>>>(mixed_pre, conv_w, mixed);
    // 4) gates
    gb_kernel<<<(S_LEN * NVH) / 256, blk, 0, stream>>>(ab_buf, dt_b, A_log, g_buf, bet_buf);
    // 5) l2norm q,k
    l2norm_kernel<<<(2 * S_LEN * NKH * 64) / 256, blk, 0, stream>>>(mixed, qn, kn);
    // 6) phase A (intra-chunk)
    phaseA_kernel<<<dim3(NCHK, NVH), blk, PA_LDS_FLOATS * 4, stream>>>(
        qn, kn, mixed, g_buf, bet_buf, u_buf, kcd_buf, sc_buf, gcs_buf);
    // 7) phase B (inter-chunk scan)
    phaseB_kernel<<<dim3(8, NVH), blk, PB_LDS_FLOATS * 4, stream>>>(
        qn, kn, u_buf, kcd_buf, sc_buf, gcs_buf, obuf);
    // 8) W_out cast (mixed region now dead) + gated RMSNorm -> bf16
    cast_kernel<<<(HIDDIM * VAL_DIM / 8) / 256, blk, 0, stream>>>(W_out, wob, HIDDIM * VAL_DIM / 8);
    norm_kernel<<<(S_LEN * NVH * 64) / 256, blk, 0, stream>>>(obuf, z_buf, norm_w, hbuf);
    // 9) output projection (bf16 MFMA)
    gemm_bf16_kernel<<<dim3(HIDDIM / 128, S_LEN / 128), blk, 0, stream>>>(hbuf, wob, out, S_LEN, HIDDIM, VAL_DIM);
}

// Round 3
// 748.017 us; speedup vs baseline: 4.6772x; 1.7831x over previous
//
#include <hip/hip_runtime.h>
#include <hip/hip_bf16.h>
#include <math.h>

// ---- problem constants ----
#define S_LEN   2048
#define HIDDIM  2048
#define NKH     16
#define NVH     32
#define DKD     128
#define DVD     128
#define CCH     64          // chunk
#define NCHK    32          // S/chunk
#define KEY_DIM 2048
#define VAL_DIM 4096
#define CONV_DIM 8192

#define PA_LDS_FLOATS (3*64*132 + 64*68 + 128)
// phaseB LDS (ushorts): qorg 8192, kcorg 8192, scorg 4096, kTorg 8192,
// storg 2048, vnorg 1024, vnsorg 1024  + 64 floats gcs
#define PB_LDS_BYTES ((8192+8192+4096+8192+2048+1024+1024)*2 + 64*4)

typedef __bf16 bf16x8 __attribute__((ext_vector_type(8)));
typedef float f32x4 __attribute__((ext_vector_type(4)));

__device__ __forceinline__ float sigmoid_f(float x) { return 1.f / (1.f + __expf(-x)); }
__device__ __forceinline__ float silu_f(float x) { return x * sigmoid_f(x); }
__device__ __forceinline__ ushort f2bf(float f) {
    unsigned u = __float_as_uint(f);
    u += 0x7fffu + ((u >> 16) & 1u);          // RNE (inputs finite)
    return (ushort)(u >> 16);
}
__device__ __forceinline__ float bf2f(ushort u) {
    return __uint_as_float((unsigned)u << 16);
}

#define GLL(srcp, dstp) __builtin_amdgcn_global_load_lds( \
    (const __attribute__((address_space(1))) void*)(srcp), \
    (__attribute__((address_space(3))) void*)(dstp), 16, 0, 0)

// ================= fp32 -> bf16 cast (8 elems/thread) =======================
__global__ __launch_bounds__(256) void cast_kernel(
    const float* __restrict__ in, ushort* __restrict__ out, int n8)
{
    int t = blockIdx.x * 256 + threadIdx.x;
    if (t >= n8) return;
    float4 v0 = *(const float4*)(in + (size_t)t * 8);
    float4 v1 = *(const float4*)(in + (size_t)t * 8 + 4);
    union { ushort u[8]; uint4 v; } r;
    r.u[0] = f2bf(v0.x); r.u[1] = f2bf(v0.y); r.u[2] = f2bf(v0.z); r.u[3] = f2bf(v0.w);
    r.u[4] = f2bf(v1.x); r.u[5] = f2bf(v1.y); r.u[6] = f2bf(v1.z); r.u[7] = f2bf(v1.w);
    *(uint4*)(out + (size_t)t * 8) = r.v;
}

// ====== W_a,W_b -> one padded bf16 weight [128,2048] (rows 64..127 zero) ====
__global__ __launch_bounds__(256) void cast_ab_kernel(
    const float* __restrict__ Wa, const float* __restrict__ Wb, ushort* __restrict__ out)
{
    int t = blockIdx.x * 256 + threadIdx.x;          // 128*2048/8 = 32768 threads
    int row = t >> 8;
    int c8 = (t & 255) * 8;
    union { ushort u[8]; uint4 v; } r;
    if (row < 64) {
        const float* src = (row < 32) ? (Wa + (size_t)row * HIDDIM + c8)
                                      : (Wb + (size_t)(row - 32) * HIDDIM + c8);
        float4 v0 = *(const float4*)(src);
        float4 v1 = *(const float4*)(src + 4);
        r.u[0] = f2bf(v0.x); r.u[1] = f2bf(v0.y); r.u[2] = f2bf(v0.z); r.u[3] = f2bf(v0.w);
        r.u[4] = f2bf(v1.x); r.u[5] = f2bf(v1.y); r.u[6] = f2bf(v1.z); r.u[7] = f2bf(v1.w);
    } else {
        r.u[0] = r.u[1] = r.u[2] = r.u[3] = r.u[4] = r.u[5] = r.u[6] = r.u[7] = 0;
    }
    *(uint4*)(out + (size_t)t * 8) = r.v;
}

// ================= bf16 MFMA GEMM: C[M,N] = A[M,K] @ B[N,K]^T (f32 out) =====
__global__ __launch_bounds__(256) void gemm_bf16_kernel(
    const ushort* __restrict__ A, const ushort* __restrict__ B, float* __restrict__ C,
    int M, int N, int K)
{
    __shared__ ushort Alds[128 * 32];
    __shared__ ushort Blds[128 * 32];
    const int tid = threadIdx.x;
    const int wv = tid >> 6, ln = tid & 63;
    const int bm = blockIdx.y * 128, bn = blockIdx.x * 128;
    const int wr = (wv >> 1) * 64, wc = (wv & 1) * 64;
    const int lrow = ln & 15, lkg = ln >> 4;

    f32x4 acc[4][4];
#pragma unroll
    for (int m = 0; m < 4; ++m)
#pragma unroll
        for (int n = 0; n < 4; ++n) {
            f32x4 z = {0.f, 0.f, 0.f, 0.f};
            acc[m][n] = z;
        }

    const int arow = tid >> 2, ak8 = (tid & 3) * 8;
    const ushort* srcA0 = A + (size_t)(bm + arow) * K + ak8;
    const ushort* srcA1 = A + (size_t)(bm + 64 + arow) * K + ak8;
    const ushort* srcB0 = B + (size_t)(bn + arow) * K + ak8;
    const ushort* srcB1 = B + (size_t)(bn + 64 + arow) * K + ak8;
    ushort* dstA0 = &Alds[(size_t)(wv * 64) * 8];
    ushort* dstA1 = &Alds[(size_t)(256 + wv * 64) * 8];
    ushort* dstB0 = &Blds[(size_t)(wv * 64) * 8];
    ushort* dstB1 = &Blds[(size_t)(256 + wv * 64) * 8];

    for (int k0 = 0; k0 < K; k0 += 32) {
        GLL(srcA0 + k0, dstA0);
        GLL(srcA1 + k0, dstA1);
        GLL(srcB0 + k0, dstB0);
        GLL(srcB1 + k0, dstB1);
        __syncthreads();

        bf16x8 af[4], bfr[4];
#pragma unroll
        for (int m = 0; m < 4; ++m)
            af[m] = *(const bf16x8*)&Alds[(size_t)(wr + m * 16 + lrow) * 32 + lkg * 8];
#pragma unroll
        for (int n = 0; n < 4; ++n)
            bfr[n] = *(const bf16x8*)&Blds[(size_t)(wc + n * 16 + lrow) * 32 + lkg * 8];
#pragma unroll
        for (int m = 0; m < 4; ++m)
#pragma unroll
            for (int n = 0; n < 4; ++n)
                acc[m][n] = __builtin_amdgcn_mfma_f32_16x16x32_bf16(
                    af[m], bfr[n], acc[m][n], 0, 0, 0);
        __syncthreads();
    }

#pragma unroll
    for (int m = 0; m < 4; ++m) {
        int row0 = bm + wr + m * 16 + lkg * 4;
#pragma unroll
        for (int n = 0; n < 4; ++n) {
            int col = bn + wc + n * 16 + lrow;
            float* cp = C + (size_t)row0 * N + col;
#pragma unroll
            for (int j = 0; j < 4; ++j) cp[(size_t)j * N] = acc[m][n][j];
        }
    }
}

// ================= causal depthwise conv1d (K=4) + SiLU =====================
__global__ __launch_bounds__(256) void conv_silu_kernel(
    const float* __restrict__ pre, const float* __restrict__ cw, float* __restrict__ out)
{
    int idx = blockIdx.x * 256 + threadIdx.x;
    const int NC4 = CONV_DIM / 4;
    int s = idx / NC4;
    int c = (idx % NC4) * 4;
    float w[4][4];
#pragma unroll
    for (int j = 0; j < 4; ++j) {
        float4 wj = *(const float4*)(cw + (size_t)(c + j) * 4);
        w[j][0] = wj.x; w[j][1] = wj.y; w[j][2] = wj.z; w[j][3] = wj.w;
    }
    float acc[4] = {0.f, 0.f, 0.f, 0.f};
#pragma unroll
    for (int t = 0; t < 4; ++t) {
        int ss = s - 3 + t;
        if (ss >= 0) {
            float4 x = *(const float4*)(pre + (size_t)ss * CONV_DIM + c);
            acc[0] = fmaf(x.x, w[0][t], acc[0]);
            acc[1] = fmaf(x.y, w[1][t], acc[1]);
            acc[2] = fmaf(x.z, w[2][t], acc[2]);
            acc[3] = fmaf(x.w, w[3][t], acc[3]);
        }
    }
    float4 o = make_float4(silu_f(acc[0]), silu_f(acc[1]), silu_f(acc[2]), silu_f(acc[3]));
    *(float4*)(out + (size_t)s * CONV_DIM + c) = o;
}

// ====== g = -exp(A_log)*softplus(a+dt_bias), beta = sigmoid(b) ==============
__global__ __launch_bounds__(256) void gb_kernel(
    const float* __restrict__ ab, const float* __restrict__ dt_bias,
    const float* __restrict__ A_log, float* __restrict__ g, float* __restrict__ beta)
{
    int idx = blockIdx.x * 256 + threadIdx.x;
    int s = idx >> 5, h = idx & 31;
    float av = ab[(size_t)s * 128 + h] + dt_bias[h];
    float sp = (av > 20.f) ? av : log1pf(__expf(av));
    g[idx] = -__expf(A_log[h]) * sp;
    beta[idx] = sigmoid_f(ab[(size_t)s * 128 + 32 + h]);
}

// ===== l2norm q,k: q -> bf16 (qnb), k -> f32 (kn) ===========================
__global__ __launch_bounds__(256) void l2norm_kernel(
    const float* __restrict__ mixed, ushort* __restrict__ qnb, float* __restrict__ kn)
{
    int gw = (blockIdx.x * 256 + threadIdx.x) >> 6;
    int lane = threadIdx.x & 63;
    int isk = gw >= S_LEN * NKH;
    int r = gw - isk * S_LEN * NKH;
    int s = r / NKH, kh = r % NKH;
    const float* src = mixed + (size_t)s * CONV_DIM + isk * KEY_DIM + kh * DKD;
    float2 x = *(const float2*)(src + lane * 2);
    float ss = x.x * x.x + x.y * x.y;
#pragma unroll
    for (int m = 1; m < 64; m <<= 1) ss += __shfl_xor(ss, m, 64);
    float scale = rsqrtf(ss + 1e-6f);
    if (!isk) {
        scale *= 0.08838834764831843f;   // DK^-0.5
        union { ushort u[2]; uint v; } p;
        p.u[0] = f2bf(x.x * scale); p.u[1] = f2bf(x.y * scale);
        *(uint*)(qnb + ((size_t)(s * NKH + kh)) * DKD + lane * 2) = p.v;
    } else {
        float* dst = kn + ((size_t)(s * NKH + kh)) * DKD + lane * 2;
        *(float2*)dst = make_float2(x.x * scale, x.y * scale);
    }
}

// ================= Phase A: per (head, chunk) intra-chunk work ==============
// outputs: u f32, kcd bf16, scores bf16, gcs f32, knT bf16 (even h only)
__global__ __launch_bounds__(256) void phaseA_kernel(
    const ushort* __restrict__ qnb, const float* __restrict__ kn,
    const float* __restrict__ mixed, const float* __restrict__ gbuf,
    const float* __restrict__ betabuf,
    float* __restrict__ u, ushort* __restrict__ kcd,
    ushort* __restrict__ scores, float* __restrict__ gcs_out,
    ushort* __restrict__ knT)
{
    extern __shared__ float sm[];
    float (*ks)[132]  = (float(*)[132])(sm);
    float (*XU)[132]  = (float(*)[132])(sm + 64 * 132);
    float (*XK)[132]  = (float(*)[132])(sm + 2 * 64 * 132);
    float (*Asm)[68]  = (float(*)[68])(sm + 3 * 64 * 132);
    float* gcs_s = sm + 3 * 64 * 132 + 64 * 68;
    float* bet_s = gcs_s + 64;

    const int n = blockIdx.x, h = blockIdx.y, kh = h >> 1;
    const int tid = threadIdx.x;
    const int s0 = n * CCH;

    if (tid < 64) {
        float gv = gbuf[(size_t)(s0 + tid) * NVH + h];
#pragma unroll
        for (int off = 1; off < 64; off <<= 1) {
            float pv = __shfl_up(gv, off, 64);
            if (tid >= off) gv += pv;
        }
        gcs_s[tid] = gv;
        bet_s[tid] = betabuf[(size_t)(s0 + tid) * NVH + h];
        gcs_out[(size_t)h * S_LEN + s0 + tid] = gv;
    }
    {
        const int r = tid >> 2, c0 = (tid & 3) * 32;
        const float* src = kn + ((size_t)(s0 + r) * NKH + kh) * DKD + c0;
#pragma unroll
        for (int j = 0; j < 32; j += 4)
            *(float4*)&ks[r][c0 + j] = *(const float4*)(src + j);
    }
    __syncthreads();

    {   // A[i][j] = -beta_i (k_i.k_j) exp(gcs_i-gcs_j), i>j
        const int i0 = (tid >> 4) * 4, jx = tid & 15;
        float acc[4][4];
#pragma unroll
        for (int ii = 0; ii < 4; ++ii)
#pragma unroll
            for (int jj = 0; jj < 4; ++jj) acc[ii][jj] = 0.f;
        for (int d = 0; d < DKD; d += 4) {
            float4 av[4], bv[4];
#pragma unroll
            for (int ii = 0; ii < 4; ++ii) av[ii] = *(const float4*)&ks[i0 + ii][d];
#pragma unroll
            for (int jj = 0; jj < 4; ++jj) bv[jj] = *(const float4*)&ks[jx + 16 * jj][d];
#pragma unroll
            for (int ii = 0; ii < 4; ++ii)
#pragma unroll
                for (int jj = 0; jj < 4; ++jj)
                    acc[ii][jj] += av[ii].x * bv[jj].x + av[ii].y * bv[jj].y
                                 + av[ii].z * bv[jj].z + av[ii].w * bv[jj].w;
        }
#pragma unroll
        for (int ii = 0; ii < 4; ++ii)
#pragma unroll
            for (int jj = 0; jj < 4; ++jj) {
                int i = i0 + ii, j = jx + 16 * jj;
                Asm[i][j] = (i > j) ? (-bet_s[i] * acc[ii][jj] * __expf(gcs_s[i] - gcs_s[j])) : 0.f;
            }
    }
    {   // RHS: XU = v*beta ; XK = k*beta*exp(gcs)
        const int r = tid >> 2, c0 = (tid & 3) * 32;
        const float bv = bet_s[r];
        const float f = bv * __expf(gcs_s[r]);
        const float* vsrc = mixed + (size_t)(s0 + r) * CONV_DIM + 2 * KEY_DIM + h * DVD + c0;
#pragma unroll
        for (int j = 0; j < 32; j += 4) {
            float4 v4 = *(const float4*)(vsrc + j);
            float4 k4 = *(const float4*)&ks[r][c0 + j];
            XU[r][c0 + j + 0] = v4.x * bv; XU[r][c0 + j + 1] = v4.y * bv;
            XU[r][c0 + j + 2] = v4.z * bv; XU[r][c0 + j + 3] = v4.w * bv;
            XK[r][c0 + j + 0] = k4.x * f;  XK[r][c0 + j + 1] = k4.y * f;
            XK[r][c0 + j + 2] = k4.z * f;  XK[r][c0 + j + 3] = k4.w * f;
        }
    }
    __syncthreads();

    {   // forward substitution (I-A)X = RHS, column-parallel
        const int d = tid & 127;
        float (*X)[132] = (tid >> 7) ? XK : XU;
        for (int i = 1; i < CCH; ++i) {
            const float* Ai = Asm[i];
            float r = 0.f;
            int k = 0;
            for (; k + 4 <= i; k += 4)
                r += Ai[k] * X[k][d] + Ai[k + 1] * X[k + 1][d]
                   + Ai[k + 2] * X[k + 2][d] + Ai[k + 3] * X[k + 3][d];
            for (; k < i; ++k) r += Ai[k] * X[k][d];
            X[i][d] += r;
            __syncthreads();
        }
    }
    {   // store u (f32), kcd (bf16); load q (bf16->f32) into XU
        const int r = tid >> 2, c0 = (tid & 3) * 32;
        const size_t base = ((size_t)(h * NCHK + n) * CCH + r) * DVD + c0;
#pragma unroll
        for (int j = 0; j < 32; j += 4) {
            *(float4*)(u + base + j) = *(const float4*)&XU[r][c0 + j];
            union { ushort u2[4]; uint2 v; } p;
            p.u2[0] = f2bf(XK[r][c0 + j + 0]); p.u2[1] = f2bf(XK[r][c0 + j + 1]);
            p.u2[2] = f2bf(XK[r][c0 + j + 2]); p.u2[3] = f2bf(XK[r][c0 + j + 3]);
            *(uint2*)(kcd + base + j) = p.v;
        }
        const ushort* qsrc = qnb + ((size_t)(s0 + r) * NKH + kh) * DKD + c0;
#pragma unroll
        for (int j = 0; j < 32; j += 8) {
            uint4 pv = *(const uint4*)(qsrc + j);
            const ushort* pu = (const ushort*)&pv;
#pragma unroll
            for (int e = 0; e < 8; ++e) XU[r][c0 + j + e] = bf2f(pu[e]);
        }
    }
    __syncthreads();

    {   // scores[i][j] = (q_i.k_j) exp(gcs_i-gcs_j), i>=j else 0  -> bf16
        const int i0 = (tid >> 4) * 4, jx = tid & 15;
        float acc[4][4];
#pragma unroll
        for (int ii = 0; ii < 4; ++ii)
#pragma unroll
            for (int jj = 0; jj < 4; ++jj) acc[ii][jj] = 0.f;
        for (int d = 0; d < DKD; d += 4) {
            float4 av[4], bv[4];
#pragma unroll
            for (int ii = 0; ii < 4; ++ii) av[ii] = *(const float4*)&XU[i0 + ii][d];
#pragma unroll
            for (int jj = 0; jj < 4; ++jj) bv[jj] = *(const float4*)&ks[jx + 16 * jj][d];
#pragma unroll
            for (int ii = 0; ii < 4; ++ii)
#pragma unroll
                for (int jj = 0; jj < 4; ++jj)
                    acc[ii][jj] += av[ii].x * bv[jj].x + av[ii].y * bv[jj].y
                                 + av[ii].z * bv[jj].z + av[ii].w * bv[jj].w;
        }
#pragma unroll
        for (int ii = 0; ii < 4; ++ii)
#pragma unroll
            for (int jj = 0; jj < 4; ++jj) {
                int i = i0 + ii, j = jx + 16 * jj;
                float v = (i >= j) ? acc[ii][jj] * __expf(gcs_s[i] - gcs_s[j]) : 0.f;
                scores[((size_t)(h * NCHK + n) * CCH + i) * CCH + j] = f2bf(v);
            }
    }

    // knT emit (once per kh): knT[kh][n][dk][c] bf16 from ks LDS (read-only)
    if (!(h & 1)) {
        const int dk = tid >> 1, ch = (tid & 1) * 32;
        ushort* dst = knT + ((size_t)(kh * NCHK + n) * DKD + dk) * CCH + ch;
#pragma unroll
        for (int j0 = 0; j0 < 32; j0 += 8) {
            union { ushort u2[8]; uint4 v; } p;
#pragma unroll
            for (int j = 0; j < 8; ++j) p.u2[j] = f2bf(ks[ch + j0 + j][dk]);
            *(uint4*)(dst + j0) = p.v;
        }
    }
}

// ================= Phase B: inter-chunk state scan (MFMA) ===================
// grid (32 heads, 8 dv-slices): blockIdx.x = h so all slices of a head share
// h%8 -> same XCD -> L2-shared q/kcd/sc/kT staging.
// LDS buffers are fragment-ordered [tile][kstep][lane][8] -> conflict-free
// ds_read_b128 AND linear global_load_lds destinations (shuffle on src addr).
__global__ __launch_bounds__(256) void phaseB_kernel(
    const ushort* __restrict__ qnb, const ushort* __restrict__ knT,
    const float* __restrict__ u, const ushort* __restrict__ kcd,
    const ushort* __restrict__ sc, const float* __restrict__ gcs,
    float* __restrict__ obuf)
{
    extern __shared__ ushort smu[];
    ushort* qorg  = smu;             // 8192  [m4][ks4][64][8]
    ushort* kcorg = smu + 8192;      // 8192  [m4][ks4][64][8]
    ushort* scorg = smu + 16384;     // 4096  [m4][ks2][64][8]
    ushort* kTorg = smu + 20480;     // 8192  [nt8][ks2][64][8]
    ushort* storg = smu + 28672;     // 2048  [ks4][64][8]   S^T bf16
    ushort* vnorg = smu + 30720;     // 1024  [ks2][64][8]   v_new^T
    ushort* vnsorg= smu + 31744;     // 1024  [ks2][64][8]   v_new^T * exp(gl-gcs)
    float* gcs_s  = (float*)(smu + 32768);   // 64

    const int h = blockIdx.x;            // 0..31
    const int dvb = blockIdx.y;          // 0..7
    const int d0 = dvb * 16;
    const int kh = h >> 1;
    const int tid = threadIdx.x;
    const int wv = tid >> 6, ln = tid & 63;
    const int lrow = ln & 15, lkg = ln >> 4;

    // zero S^T
    for (int i = tid; i < 2048 / 8; i += 256) {
        uint4 z = {0, 0, 0, 0};
        *(uint4*)&storg[i * 8] = z;
    }

    // staging source lane-offsets (element units), round-invariant parts
    const int q_lane  = lrow * (NKH * DKD) + kh * DKD + wv * 32 + lkg * 8;  // +r*16*2048
    const int kc_lane = lrow * DKD + wv * 32 + lkg * 8;                     // +r*16*128
    const int st_lane = ((tid >> 7) * 16 + lrow) * 64 + ((tid >> 6) & 1) * 32 + lkg * 8; // +r*2048
    const int dst_e   = wv * 512;                                            // +r*2048

    // per-wave accumulators: S^T slice [16 dv rows][32 dk cols] as 2 n-tiles
    f32x4 accS0 = {0.f, 0.f, 0.f, 0.f}, accS1 = {0.f, 0.f, 0.f, 0.f};

    for (int n = 0; n < NCHK; ++n) {
        const int s0 = n * CCH;
        // ---- stage chunk operands (linear LDS dest, shuffled global src) ----
        const ushort* qsrc  = qnb + (size_t)s0 * (NKH * DKD);
        const ushort* kcsrc = kcd + (size_t)(h * NCHK + n) * (CCH * DKD);
        const ushort* scsrc = sc  + (size_t)(h * NCHK + n) * (CCH * CCH);
        const ushort* kTsrc = knT + (size_t)(kh * NCHK + n) * (DKD * CCH);
#pragma unroll
        for (int r = 0; r < 4; ++r) {
            GLL(qsrc + q_lane + r * 32768, &qorg[r * 2048 + dst_e]);
            GLL(kcsrc + kc_lane + r * 2048, &kcorg[r * 2048 + dst_e]);
            GLL(kTsrc + st_lane + r * 2048, &kTorg[r * 2048 + dst_e]);
        }
#pragma unroll
        for (int r = 0; r < 2; ++r)
            GLL(scsrc + st_lane + r * 2048, &scorg[r * 2048 + dst_e]);
        if (tid < 64) gcs_s[tid] = gcs[(size_t)h * S_LEN + s0 + tid];
        __syncthreads();                 // B1: staged data + gcs + S^T ready

        // ---- phase 1: accv = kcd@S, acco = q@S (old state) ----
        f32x4 accv = {0.f, 0.f, 0.f, 0.f};
        f32x4 acco = {0.f, 0.f, 0.f, 0.f};
#pragma unroll
        for (int ks = 0; ks < 4; ++ks) {
            bf16x8 b_st = *(const bf16x8*)&storg[(ks * 64 + ln) * 8];
            bf16x8 a_kc = *(const bf16x8*)&kcorg[((wv * 4 + ks) * 64 + ln) * 8];
            bf16x8 a_q  = *(const bf16x8*)&qorg[((wv * 4 + ks) * 64 + ln) * 8];
            accv = __builtin_amdgcn_mfma_f32_16x16x32_bf16(a_kc, b_st, accv, 0, 0, 0);
            acco = __builtin_amdgcn_mfma_f32_16x16x32_bf16(a_q, b_st, acco, 0, 0, 0);
        }
        const float* up = u + (size_t)(h * NCHK + n) * (CCH * DVD)
                            + (wv * 16 + lkg * 4) * DVD + d0 + lrow;
        float u0 = up[0], u1 = up[DVD], u2 = up[2 * DVD], u3 = up[3 * DVD];
        const float gl = gcs_s[63];
        float vn0 = u0 - accv[0], vn1 = u1 - accv[1];
        float vn2 = u2 - accv[2], vn3 = u3 - accv[3];
        {
            const int row = wv * 16 + lkg * 4;
            float g0 = gcs_s[row], g1 = gcs_s[row + 1], g2 = gcs_s[row + 2], g3 = gcs_s[row + 3];
            acco[0] *= __expf(g0); acco[1] *= __expf(g1);
            acco[2] *= __expf(g2); acco[3] *= __expf(g3);
            // vnT / vnTs stores (8B each)
            const int eb = ((wv >> 1) * 64 + ((wv & 1) * 2 + (lkg >> 1)) * 16 + lrow) * 8
                         + (lkg & 1) * 4;
            union { ushort u2a[4]; uint2 v; } pa, pb;
            pa.u2a[0] = f2bf(vn0); pa.u2a[1] = f2bf(vn1);
            pa.u2a[2] = f2bf(vn2); pa.u2a[3] = f2bf(vn3);
            pb.u2a[0] = f2bf(vn0 * __expf(gl - g0)); pb.u2a[1] = f2bf(vn1 * __expf(gl - g1));
            pb.u2a[2] = f2bf(vn2 * __expf(gl - g2)); pb.u2a[3] = f2bf(vn3 * __expf(gl - g3));
            *(uint2*)&vnorg[eb] = pa.v;
            *(uint2*)&vnsorg[eb] = pb.v;
        }
        __syncthreads();                 // B2: v_new^T ready

        // ---- phase 2: o += scores@v_new ; state update ----
#pragma unroll
        for (int ks = 0; ks < 2; ++ks) {
            bf16x8 a_sc = *(const bf16x8*)&scorg[((wv * 2 + ks) * 64 + ln) * 8];
            bf16x8 b_vn = *(const bf16x8*)&vnorg[(ks * 64 + ln) * 8];
            acco = __builtin_amdgcn_mfma_f32_16x16x32_bf16(a_sc, b_vn, acco, 0, 0, 0);
        }
        float* op = obuf + (size_t)(s0 + wv * 16 + lkg * 4) * VAL_DIM + h * DVD + d0 + lrow;
        op[0] = acco[0]; op[VAL_DIM] = acco[1];
        op[2 * VAL_DIM] = acco[2]; op[3 * VAL_DIM] = acco[3];

        const float egl = __expf(gl);
        accS0 *= egl; accS1 *= egl;
#pragma unroll
        for (int ks = 0; ks < 2; ++ks) {
            bf16x8 a_vs = *(const bf16x8*)&vnsorg[(ks * 64 + ln) * 8];
            bf16x8 b_k0 = *(const bf16x8*)&kTorg[(((wv * 2 + 0) * 2 + ks) * 64 + ln) * 8];
            bf16x8 b_k1 = *(const bf16x8*)&kTorg[(((wv * 2 + 1) * 2 + ks) * 64 + ln) * 8];
            accS0 = __builtin_amdgcn_mfma_f32_16x16x32_bf16(a_vs, b_k0, accS0, 0, 0, 0);
            accS1 = __builtin_amdgcn_mfma_f32_16x16x32_bf16(a_vs, b_k1, accS1, 0, 0, 0);
        }
        // write S^T bf16 back to storg (fragment-ordered scatter, 2B x8)
#pragma unroll
        for (int j = 0; j < 4; ++j) {
            storg[(wv * 64 + ((lrow >> 3)) * 16 + lkg * 4 + j) * 8 + (lrow & 7)] = f2bf(accS0[j]);
            storg[(wv * 64 + (2 + (lrow >> 3)) * 16 + lkg * 4 + j) * 8 + (lrow & 7)] = f2bf(accS1[j]);
        }
        __syncthreads();                 // B3: all reads of staged bufs + S^T write done
    }
}

// ================= RMSNorm * norm_w * silu(z) -> bf16 =======================
__global__ __launch_bounds__(256) void norm_kernel(
    const float* __restrict__ obuf, const float* __restrict__ z,
    const float* __restrict__ nw, ushort* __restrict__ hbuf)
{
    int row = (blockIdx.x * 256 + threadIdx.x) >> 6;
    int lane = threadIdx.x & 63;
    float2 x = *(const float2*)(obuf + (size_t)row * DVD + lane * 2);
    float ss = x.x * x.x + x.y * x.y;
#pragma unroll
    for (int m = 1; m < 64; m <<= 1) ss += __shfl_xor(ss, m, 64);
    float scale = rsqrtf(ss * (1.f / DVD) + 1e-6f);
    float2 zz = *(const float2*)(z + (size_t)row * DVD + lane * 2);
    float2 w2 = *(const float2*)(nw + lane * 2);
    float h0 = x.x * scale * w2.x * silu_f(zz.x);
    float h1 = x.y * scale * w2.y * silu_f(zz.y);
    union { ushort u[2]; uint v; } r;
    r.u[0] = f2bf(h0); r.u[1] = f2bf(h1);
    *(uint*)(hbuf + (size_t)row * DVD + lane * 2) = r.v;
}

// ============================================================================
extern "C" void kernel_launch(void* const* d_in, const int* in_sizes, int n_in,
                              void* d_out, int out_size, void* d_ws, size_t ws_size,
                              hipStream_t stream)
{
    (void)in_sizes; (void)n_in; (void)out_size; (void)ws_size;
    const float* x      = (const float*)d_in[0];
    const float* W_qkv  = (const float*)d_in[1];
    const float* W_z    = (const float*)d_in[2];
    const float* W_a    = (const float*)d_in[3];
    const float* W_b    = (const float*)d_in[4];
    const float* conv_w = (const float*)d_in[5];
    const float* dt_b   = (const float*)d_in[6];
    const float* A_log  = (const float*)d_in[7];
    const float* norm_w = (const float*)d_in[8];
    const float* W_out  = (const float*)d_in[9];
    float* out = (float*)d_out;

    // ---- workspace layout (bytes), overlaid by liveness; total ~202.1 MB ---
    char* ws = (char*)d_ws;
    // region A @0 (67,108,864): mixed_pre -> {u f32, kcd bf16, knT bf16}
    float*  mixed_pre = (float*)(ws);
    float*  u_buf     = (float*)(ws);                   // 33,554,432
    ushort* kcd_buf   = (ushort*)(ws + 33554432);       // 16,777,216
    ushort* knT_buf   = (ushort*)(ws + 50331648);       //  8,388,608
    // region B @67,108,864 (67,108,864): casts -> mixed -> {obuf,hbuf,wob}
    ushort* xb        = (ushort*)(ws + 67108864);
    ushort* wzb       = (ushort*)(ws + 75497472);
    ushort* wqkvb     = (ushort*)(ws + 92274688);
    float*  mixed     = (float*)(ws + 67108864);
    float*  obuf      = (float*)(ws + 67108864);
    ushort* hbuf      = (ushort*)(ws + 100663296);
    ushort* wob       = (ushort*)(ws + 117440512);
    // fixed regions
    float*  z_buf     = (float*)(ws + 134217728);       // 33,554,432
    ushort* sc_buf    = (ushort*)(ws + 167772160);      //  8,388,608 (step>=6)
    ushort* wabb      = (ushort*)(ws + 167772160);      //    524,288 (steps 1-2)
    float*  ab_buf    = (float*)(ws + 168296448);       //  1,048,576 (steps 2-4)
    ushort* qnb       = (ushort*)(ws + 176160768);      //  8,388,608
    float*  kn        = (float*)(ws + 184549376);       // 16,777,216
    float*  g_buf     = (float*)(ws + 201326592);       //    262,144
    float*  bet_buf   = (float*)(ws + 201588736);       //    262,144
    float*  gcs_buf   = (float*)(ws + 201850880);       //    262,144

    hipFuncSetAttribute((const void*)phaseA_kernel,
                        hipFuncAttributeMaxDynamicSharedMemorySize, PA_LDS_FLOATS * 4);
    hipFuncSetAttribute((const void*)phaseB_kernel,
                        hipFuncAttributeMaxDynamicSharedMemorySize, PB_LDS_BYTES);

    dim3 blk(256);
    // 1) casts to bf16
    cast_kernel<<<(S_LEN * HIDDIM / 8) / 256, blk, 0, stream>>>(x, xb, S_LEN * HIDDIM / 8);
    cast_kernel<<<(CONV_DIM * HIDDIM / 8) / 256, blk, 0, stream>>>(W_qkv, wqkvb, CONV_DIM * HIDDIM / 8);
    cast_kernel<<<(VAL_DIM * HIDDIM / 8) / 256, blk, 0, stream>>>(W_z, wzb, VAL_DIM * HIDDIM / 8);
    cast_ab_kernel<<<(128 * HIDDIM / 8) / 256, blk, 0, stream>>>(W_a, W_b, wabb);
    // 2) projections (bf16 MFMA)
    gemm_bf16_kernel<<<dim3(CONV_DIM / 128, S_LEN / 128), blk, 0, stream>>>(xb, wqkvb, mixed_pre, S_LEN, CONV_DIM, HIDDIM);
    gemm_bf16_kernel<<<dim3(VAL_DIM / 128, S_LEN / 128), blk, 0, stream>>>(xb, wzb, z_buf, S_LEN, VAL_DIM, HIDDIM);
    gemm_bf16_kernel<<<dim3(1, S_LEN / 128), blk, 0, stream>>>(xb, wabb, ab_buf, S_LEN, 128, HIDDIM);
    // 3) conv + silu (fp32)
    conv_silu_kernel<<<(S_LEN * CONV_DIM / 4) / 256, blk, 0, stream>>>(mixed_pre, conv_w, mixed);
    // 4) gates
    gb_kernel<<<(S_LEN * NVH) / 256, blk, 0, stream>>>(ab_buf, dt_b, A_log, g_buf, bet_buf);
    // 5) l2norm q,k
    l2norm_kernel<<<(2 * S_LEN * NKH * 64) / 256, blk, 0, stream>>>(mixed, qnb, kn);
    // 6) phase A (intra-chunk)
    phaseA_kernel<<<dim3(NCHK, NVH), blk, PA_LDS_FLOATS * 4, stream>>>(
        qnb, kn, mixed, g_buf, bet_buf, u_buf, kcd_buf, sc_buf, gcs_buf, knT_buf);
    // 7) phase B (inter-chunk scan, MFMA)
    phaseB_kernel<<<dim3(NVH, 8), blk, PB_LDS_BYTES, stream>>>(
        qnb, knT_buf, u_buf, kcd_buf, sc_buf, gcs_buf, obuf);
    // 8) W_out cast (mixed region now dead) + gated RMSNorm -> bf16
    cast_kernel<<<(HIDDIM * VAL_DIM / 8) / 256, blk, 0, stream>>>(W_out, wob, HIDDIM * VAL_DIM / 8);
    norm_kernel<<<(S_LEN * NVH * 64) / 256, blk, 0, stream>>>(obuf, z_buf, norm_w, hbuf);
    // 9) output projection (bf16 MFMA)
    gemm_bf16_kernel<<<dim3(HIDDIM / 128, S_LEN / 128), blk, 0, stream>>>(hbuf, wob, out, S_LEN, HIDDIM, VAL_DIM);
}

// Round 4
// 704.200 us; speedup vs baseline: 4.9682x; 1.0622x over previous
//
#include <hip/hip_runtime.h>
#include <hip/hip_bf16.h>
#include <math.h>

// ---- problem constants ----
#define S_LEN   2048
#define HIDDIM  2048
#define NKH     16
#define NVH     32
#define DKD     128
#define DVD     128
#define CCH     64          // chunk
#define NCHK    32          // S/chunk
#define KEY_DIM 2048
#define VAL_DIM 4096
#define CONV_DIM 8192

// phaseB LDS (ushorts): qorg 8192, kcorg 8192, scorg 4096, kTorg 8192,
// storg 2048, vnorg 1024, vnsorg 1024  + 64 floats gcs
#define PB_LDS_BYTES ((8192+8192+4096+8192+2048+1024+1024)*2 + 64*4)

typedef __bf16 bf16x8 __attribute__((ext_vector_type(8)));
typedef float f32x4 __attribute__((ext_vector_type(4)));

__device__ __forceinline__ float sigmoid_f(float x) { return 1.f / (1.f + __expf(-x)); }
__device__ __forceinline__ float silu_f(float x) { return x * sigmoid_f(x); }
__device__ __forceinline__ ushort f2bf(float f) {
    unsigned u = __float_as_uint(f);
    u += 0x7fffu + ((u >> 16) & 1u);          // RNE (inputs finite)
    return (ushort)(u >> 16);
}
__device__ __forceinline__ float bf2f(ushort u) {
    return __uint_as_float((unsigned)u << 16);
}

#define GLL(srcp, dstp) __builtin_amdgcn_global_load_lds( \
    (const __attribute__((address_space(1))) void*)(srcp), \
    (__attribute__((address_space(3))) void*)(dstp), 16, 0, 0)

// ================= fp32 -> bf16 cast (8 elems/thread) =======================
__global__ __launch_bounds__(256) void cast_kernel(
    const float* __restrict__ in, ushort* __restrict__ out, int n8)
{
    int t = blockIdx.x * 256 + threadIdx.x;
    if (t >= n8) return;
    float4 v0 = *(const float4*)(in + (size_t)t * 8);
    float4 v1 = *(const float4*)(in + (size_t)t * 8 + 4);
    union { ushort u[8]; uint4 v; } r;
    r.u[0] = f2bf(v0.x); r.u[1] = f2bf(v0.y); r.u[2] = f2bf(v0.z); r.u[3] = f2bf(v0.w);
    r.u[4] = f2bf(v1.x); r.u[5] = f2bf(v1.y); r.u[6] = f2bf(v1.z); r.u[7] = f2bf(v1.w);
    *(uint4*)(out + (size_t)t * 8) = r.v;
}

// ====== W_a,W_b -> one padded bf16 weight [128,2048] (rows 64..127 zero) ====
__global__ __launch_bounds__(256) void cast_ab_kernel(
    const float* __restrict__ Wa, const float* __restrict__ Wb, ushort* __restrict__ out)
{
    int t = blockIdx.x * 256 + threadIdx.x;          // 128*2048/8 = 32768 threads
    int row = t >> 8;
    int c8 = (t & 255) * 8;
    union { ushort u[8]; uint4 v; } r;
    if (row < 64) {
        const float* src = (row < 32) ? (Wa + (size_t)row * HIDDIM + c8)
                                      : (Wb + (size_t)(row - 32) * HIDDIM + c8);
        float4 v0 = *(const float4*)(src);
        float4 v1 = *(const float4*)(src + 4);
        r.u[0] = f2bf(v0.x); r.u[1] = f2bf(v0.y); r.u[2] = f2bf(v0.z); r.u[3] = f2bf(v0.w);
        r.u[4] = f2bf(v1.x); r.u[5] = f2bf(v1.y); r.u[6] = f2bf(v1.z); r.u[7] = f2bf(v1.w);
    } else {
        r.u[0] = r.u[1] = r.u[2] = r.u[3] = r.u[4] = r.u[5] = r.u[6] = r.u[7] = 0;
    }
    *(uint4*)(out + (size_t)t * 8) = r.v;
}

// ================= bf16 MFMA GEMM: C[M,N] = A[M,K] @ B[N,K]^T (f32 out) =====
__global__ __launch_bounds__(256) void gemm_bf16_kernel(
    const ushort* __restrict__ A, const ushort* __restrict__ B, float* __restrict__ C,
    int M, int N, int K)
{
    __shared__ ushort Alds[128 * 32];
    __shared__ ushort Blds[128 * 32];
    const int tid = threadIdx.x;
    const int wv = tid >> 6, ln = tid & 63;
    const int bm = blockIdx.y * 128, bn = blockIdx.x * 128;
    const int wr = (wv >> 1) * 64, wc = (wv & 1) * 64;
    const int lrow = ln & 15, lkg = ln >> 4;

    f32x4 acc[4][4];
#pragma unroll
    for (int m = 0; m < 4; ++m)
#pragma unroll
        for (int n = 0; n < 4; ++n) {
            f32x4 z = {0.f, 0.f, 0.f, 0.f};
            acc[m][n] = z;
        }

    const int arow = tid >> 2, ak8 = (tid & 3) * 8;
    const ushort* srcA0 = A + (size_t)(bm + arow) * K + ak8;
    const ushort* srcA1 = A + (size_t)(bm + 64 + arow) * K + ak8;
    const ushort* srcB0 = B + (size_t)(bn + arow) * K + ak8;
    const ushort* srcB1 = B + (size_t)(bn + 64 + arow) * K + ak8;
    ushort* dstA0 = &Alds[(size_t)(wv * 64) * 8];
    ushort* dstA1 = &Alds[(size_t)(256 + wv * 64) * 8];
    ushort* dstB0 = &Blds[(size_t)(wv * 64) * 8];
    ushort* dstB1 = &Blds[(size_t)(256 + wv * 64) * 8];

    for (int k0 = 0; k0 < K; k0 += 32) {
        GLL(srcA0 + k0, dstA0);
        GLL(srcA1 + k0, dstA1);
        GLL(srcB0 + k0, dstB0);
        GLL(srcB1 + k0, dstB1);
        __syncthreads();

        bf16x8 af[4], bfr[4];
#pragma unroll
        for (int m = 0; m < 4; ++m)
            af[m] = *(const bf16x8*)&Alds[(size_t)(wr + m * 16 + lrow) * 32 + lkg * 8];
#pragma unroll
        for (int n = 0; n < 4; ++n)
            bfr[n] = *(const bf16x8*)&Blds[(size_t)(wc + n * 16 + lrow) * 32 + lkg * 8];
#pragma unroll
        for (int m = 0; m < 4; ++m)
#pragma unroll
            for (int n = 0; n < 4; ++n)
                acc[m][n] = __builtin_amdgcn_mfma_f32_16x16x32_bf16(
                    af[m], bfr[n], acc[m][n], 0, 0, 0);
        __syncthreads();
    }

#pragma unroll
    for (int m = 0; m < 4; ++m) {
        int row0 = bm + wr + m * 16 + lkg * 4;
#pragma unroll
        for (int n = 0; n < 4; ++n) {
            int col = bn + wc + n * 16 + lrow;
            float* cp = C + (size_t)row0 * N + col;
#pragma unroll
            for (int j = 0; j < 4; ++j) cp[(size_t)j * N] = acc[m][n][j];
        }
    }
}

// ================= causal depthwise conv1d (K=4) + SiLU =====================
__global__ __launch_bounds__(256) void conv_silu_kernel(
    const float* __restrict__ pre, const float* __restrict__ cw, float* __restrict__ out)
{
    int idx = blockIdx.x * 256 + threadIdx.x;
    const int NC4 = CONV_DIM / 4;
    int s = idx / NC4;
    int c = (idx % NC4) * 4;
    float w[4][4];
#pragma unroll
    for (int j = 0; j < 4; ++j) {
        float4 wj = *(const float4*)(cw + (size_t)(c + j) * 4);
        w[j][0] = wj.x; w[j][1] = wj.y; w[j][2] = wj.z; w[j][3] = wj.w;
    }
    float acc[4] = {0.f, 0.f, 0.f, 0.f};
#pragma unroll
    for (int t = 0; t < 4; ++t) {
        int ss = s - 3 + t;
        if (ss >= 0) {
            float4 x = *(const float4*)(pre + (size_t)ss * CONV_DIM + c);
            acc[0] = fmaf(x.x, w[0][t], acc[0]);
            acc[1] = fmaf(x.y, w[1][t], acc[1]);
            acc[2] = fmaf(x.z, w[2][t], acc[2]);
            acc[3] = fmaf(x.w, w[3][t], acc[3]);
        }
    }
    float4 o = make_float4(silu_f(acc[0]), silu_f(acc[1]), silu_f(acc[2]), silu_f(acc[3]));
    *(float4*)(out + (size_t)s * CONV_DIM + c) = o;
}

// ====== g = -exp(A_log)*softplus(a+dt_bias), beta = sigmoid(b) ==============
__global__ __launch_bounds__(256) void gb_kernel(
    const float* __restrict__ ab, const float* __restrict__ dt_bias,
    const float* __restrict__ A_log, float* __restrict__ g, float* __restrict__ beta)
{
    int idx = blockIdx.x * 256 + threadIdx.x;
    int s = idx >> 5, h = idx & 31;
    float av = ab[(size_t)s * 128 + h] + dt_bias[h];
    float sp = (av > 20.f) ? av : log1pf(__expf(av));
    g[idx] = -__expf(A_log[h]) * sp;
    beta[idx] = sigmoid_f(ab[(size_t)s * 128 + 32 + h]);
}

// ===== l2norm q,k: q -> bf16 (qnb), k -> f32 (kn) ===========================
__global__ __launch_bounds__(256) void l2norm_kernel(
    const float* __restrict__ mixed, ushort* __restrict__ qnb, float* __restrict__ kn)
{
    int gw = (blockIdx.x * 256 + threadIdx.x) >> 6;
    int lane = threadIdx.x & 63;
    int isk = gw >= S_LEN * NKH;
    int r = gw - isk * S_LEN * NKH;
    int s = r / NKH, kh = r % NKH;
    const float* src = mixed + (size_t)s * CONV_DIM + isk * KEY_DIM + kh * DKD;
    float2 x = *(const float2*)(src + lane * 2);
    float ss = x.x * x.x + x.y * x.y;
#pragma unroll
    for (int m = 1; m < 64; m <<= 1) ss += __shfl_xor(ss, m, 64);
    float scale = rsqrtf(ss + 1e-6f);
    if (!isk) {
        scale *= 0.08838834764831843f;   // DK^-0.5
        union { ushort u[2]; uint v; } p;
        p.u[0] = f2bf(x.x * scale); p.u[1] = f2bf(x.y * scale);
        *(uint*)(qnb + ((size_t)(s * NKH + kh)) * DKD + lane * 2) = p.v;
    } else {
        float* dst = kn + ((size_t)(s * NKH + kh)) * DKD + lane * 2;
        *(float2*)dst = make_float2(x.x * scale, x.y * scale);
    }
}

// ================= Phase A: per (head, chunk) intra-chunk work ==============
// Restructured: X columns in registers (barrier-free substitution), KK^T and
// QK^T via MFMA on fragment-ordered bf16 LDS. 2 barriers total (was 65).
// outputs: u f32, kcd bf16, scores bf16, gcs f32, knT bf16 (even h only)
__global__ __launch_bounds__(256) void phaseA_kernel(
    const ushort* __restrict__ qnb, const float* __restrict__ kn,
    const float* __restrict__ mixed, const float* __restrict__ gbuf,
    const float* __restrict__ betabuf,
    float* __restrict__ u, ushort* __restrict__ kcd,
    ushort* __restrict__ scores, float* __restrict__ gcs_out,
    ushort* __restrict__ knT)
{
    __shared__ ushort kb[4 * 4 * 64 * 8];     // k bf16, frag order [m][ks][lane][8]
    __shared__ ushort qb[4 * 4 * 64 * 8];     // q bf16, frag order
    __shared__ float Asm[64][68];
    __shared__ float gcs_s[64];
    __shared__ float bet_s[64];

    const int n = blockIdx.x, h = blockIdx.y, kh = h >> 1;
    const int tid = threadIdx.x;
    const int s0 = n * CCH;
    const int wv = tid >> 6, ln = tid & 63;
    const int lrow = ln & 15, lkg = ln >> 4;

    // ---- issue X-column raw loads early (latency hides under MFMA phase) ---
    // thread d<128 owns value-column d; d>=128 owns key-column d-128.
    float xr[64];
    if (tid < 128) {
        const float* vp = mixed + (size_t)s0 * CONV_DIM + 2 * KEY_DIM + h * DVD + tid;
#pragma unroll
        for (int i = 0; i < 64; ++i) xr[i] = vp[(size_t)i * CONV_DIM];
    } else {
        const float* kp = kn + ((size_t)s0 * NKH + kh) * DKD + (tid - 128);
#pragma unroll
        for (int i = 0; i < 64; ++i) xr[i] = kp[(size_t)i * (NKH * DKD)];
    }

    // ---- gcs cumsum + beta (wave 0) ----
    if (tid < 64) {
        float gv = gbuf[(size_t)(s0 + tid) * NVH + h];
#pragma unroll
        for (int off = 1; off < 64; off <<= 1) {
            float pv = __shfl_up(gv, off, 64);
            if (tid >= off) gv += pv;
        }
        gcs_s[tid] = gv;
        bet_s[tid] = betabuf[(size_t)(s0 + tid) * NVH + h];
        gcs_out[(size_t)h * S_LEN + s0 + tid] = gv;
    }

    // ---- stage k (f32->bf16) and q (bf16) into fragment-ordered LDS ----
    {
        const int r = tid >> 2, c0 = (tid & 3) * 32;
        // element (row r, col c): m=r>>4, ks=c>>5(=tid&3), lane=(r&15)|(((c>>3)&3)<<4), slot=c&7
        const int mbase = (((r >> 4) * 4 + (tid & 3)) * 64 + (r & 15)) * 8;
        const float* ksrc = kn + ((size_t)(s0 + r) * NKH + kh) * DKD + c0;
#pragma unroll
        for (int j0 = 0; j0 < 4; ++j0) {
            float4 v0 = *(const float4*)(ksrc + j0 * 8);
            float4 v1 = *(const float4*)(ksrc + j0 * 8 + 4);
            union { ushort us[8]; uint4 v; } p;
            p.us[0] = f2bf(v0.x); p.us[1] = f2bf(v0.y); p.us[2] = f2bf(v0.z); p.us[3] = f2bf(v0.w);
            p.us[4] = f2bf(v1.x); p.us[5] = f2bf(v1.y); p.us[6] = f2bf(v1.z); p.us[7] = f2bf(v1.w);
            *(uint4*)&kb[mbase + (j0 << 7)] = p.v;    // lane += j0*16 -> +j0*128 ushorts
        }
        const ushort* qsrc = qnb + ((size_t)(s0 + r) * NKH + kh) * DKD + c0;
#pragma unroll
        for (int j0 = 0; j0 < 4; ++j0) {
            uint4 v = *(const uint4*)(qsrc + j0 * 8);
            *(uint4*)&qb[mbase + (j0 << 7)] = v;
        }
    }
    __syncthreads();    // B1: kb, qb, gcs, beta ready

    // ---- MFMA: KK^T and QK^T (wave wv owns row-tile wv) ----
    f32x4 accA[4], accQ[4];
#pragma unroll
    for (int j = 0; j < 4; ++j) {
        f32x4 z = {0.f, 0.f, 0.f, 0.f};
        accA[j] = z; accQ[j] = z;
    }
#pragma unroll
    for (int ks = 0; ks < 4; ++ks) {
        bf16x8 a_k = *(const bf16x8*)&kb[((wv * 4 + ks) * 64 + ln) * 8];
        bf16x8 a_q = *(const bf16x8*)&qb[((wv * 4 + ks) * 64 + ln) * 8];
#pragma unroll
        for (int j = 0; j < 4; ++j) {
            bf16x8 b_k = *(const bf16x8*)&kb[((j * 4 + ks) * 64 + ln) * 8];
            accA[j] = __builtin_amdgcn_mfma_f32_16x16x32_bf16(a_k, b_k, accA[j], 0, 0, 0);
            accQ[j] = __builtin_amdgcn_mfma_f32_16x16x32_bf16(a_q, b_k, accQ[j], 0, 0, 0);
        }
    }
    // ---- masks: A (strict lower, f32 LDS) and scores (lower+diag, bf16 out) -
    {
        ushort* scp = scores + (size_t)(h * NCHK + n) * (CCH * CCH);
#pragma unroll
        for (int j = 0; j < 4; ++j) {
            const int c = j * 16 + lrow;
            const float gc = gcs_s[c];
#pragma unroll
            for (int jj = 0; jj < 4; ++jj) {
                const int i = wv * 16 + lkg * 4 + jj;
                const float e = __expf(gcs_s[i] - gc);
                Asm[i][c] = (i > c) ? (-bet_s[i] * accA[j][jj] * e) : 0.f;
                float sv = (i >= c) ? (accQ[j][jj] * e) : 0.f;
                scp[i * CCH + c] = f2bf(sv);
            }
        }
    }
    __syncthreads();    // B2: Asm ready

    // ---- scale RHS in registers ----
    if (tid < 128) {
#pragma unroll
        for (int i = 0; i < 64; ++i) xr[i] *= bet_s[i];
    } else {
#pragma unroll
        for (int i = 0; i < 64; ++i) xr[i] *= bet_s[i] * __expf(gcs_s[i]);
    }
    // ---- forward substitution, thread-local (no barriers) ----
#pragma unroll
    for (int i = 1; i < 64; ++i) {
        float acc = 0.f;
        int k = 0;
#pragma unroll
        for (; k + 4 <= i; k += 4) {
            float4 a4 = *(const float4*)&Asm[i][k];
            acc += a4.x * xr[k] + a4.y * xr[k + 1] + a4.z * xr[k + 2] + a4.w * xr[k + 3];
        }
#pragma unroll
        for (; k < i; ++k) acc += Asm[i][k] * xr[k];
        xr[i] += acc;
    }
    // ---- stores: u f32 (cols 0..127), kcd bf16 (cols 128..255) ----
    if (tid < 128) {
        float* up = u + (size_t)(h * NCHK + n) * (CCH * DVD) + tid;
#pragma unroll
        for (int i = 0; i < 64; ++i) up[(size_t)i * DVD] = xr[i];
    } else {
        ushort* kp = kcd + (size_t)(h * NCHK + n) * (CCH * DKD) + (tid - 128);
#pragma unroll
        for (int i = 0; i < 64; ++i) kp[(size_t)i * DKD] = f2bf(xr[i]);
    }

    // ---- knT emit (once per kh) from kb frag-ordered LDS ----
    if (!(h & 1)) {
        const int dk = tid >> 1, ch = (tid & 1) * 32;
        ushort* dst = knT + ((size_t)(kh * NCHK + n) * DKD + dk) * CCH + ch;
        const int kpart = ((dk >> 5) * 64) * 8 + (((dk >> 3) & 3) << 4) * 8 + (dk & 7);
#pragma unroll
        for (int j0 = 0; j0 < 32; j0 += 8) {
            union { ushort us[8]; uint4 v; } p;
#pragma unroll
            for (int j = 0; j < 8; ++j) {
                const int row = ch + j0 + j;
                p.us[j] = kb[((row >> 4) * 4 * 64 + (row & 15)) * 8 + kpart];
            }
            *(uint4*)(dst + j0) = p.v;
        }
    }
}

// ================= Phase B: inter-chunk state scan (MFMA) ===================
__global__ __launch_bounds__(256) void phaseB_kernel(
    const ushort* __restrict__ qnb, const ushort* __restrict__ knT,
    const float* __restrict__ u, const ushort* __restrict__ kcd,
    const ushort* __restrict__ sc, const float* __restrict__ gcs,
    float* __restrict__ obuf)
{
    extern __shared__ ushort smu[];
    ushort* qorg  = smu;             // 8192  [m4][ks4][64][8]
    ushort* kcorg = smu + 8192;      // 8192  [m4][ks4][64][8]
    ushort* scorg = smu + 16384;     // 4096  [m4][ks2][64][8]
    ushort* kTorg = smu + 20480;     // 8192  [nt8][ks2][64][8]
    ushort* storg = smu + 28672;     // 2048  [ks4][64][8]   S^T bf16
    ushort* vnorg = smu + 30720;     // 1024  [ks2][64][8]   v_new^T
    ushort* vnsorg= smu + 31744;     // 1024  [ks2][64][8]   v_new^T * exp(gl-gcs)
    float* gcs_s  = (float*)(smu + 32768);   // 64

    const int h = blockIdx.x;            // 0..31
    const int dvb = blockIdx.y;          // 0..7
    const int d0 = dvb * 16;
    const int kh = h >> 1;
    const int tid = threadIdx.x;
    const int wv = tid >> 6, ln = tid & 63;
    const int lrow = ln & 15, lkg = ln >> 4;

    for (int i = tid; i < 2048 / 8; i += 256) {
        uint4 z = {0, 0, 0, 0};
        *(uint4*)&storg[i * 8] = z;
    }

    const int q_lane  = lrow * (NKH * DKD) + kh * DKD + wv * 32 + lkg * 8;
    const int kc_lane = lrow * DKD + wv * 32 + lkg * 8;
    const int st_lane = ((tid >> 7) * 16 + lrow) * 64 + ((tid >> 6) & 1) * 32 + lkg * 8;
    const int dst_e   = wv * 512;

    f32x4 accS0 = {0.f, 0.f, 0.f, 0.f}, accS1 = {0.f, 0.f, 0.f, 0.f};

    for (int n = 0; n < NCHK; ++n) {
        const int s0 = n * CCH;
        const ushort* qsrc  = qnb + (size_t)s0 * (NKH * DKD);
        const ushort* kcsrc = kcd + (size_t)(h * NCHK + n) * (CCH * DKD);
        const ushort* scsrc = sc  + (size_t)(h * NCHK + n) * (CCH * CCH);
        const ushort* kTsrc = knT + (size_t)(kh * NCHK + n) * (DKD * CCH);
#pragma unroll
        for (int r = 0; r < 4; ++r) {
            GLL(qsrc + q_lane + r * 32768, &qorg[r * 2048 + dst_e]);
            GLL(kcsrc + kc_lane + r * 2048, &kcorg[r * 2048 + dst_e]);
            GLL(kTsrc + st_lane + r * 2048, &kTorg[r * 2048 + dst_e]);
        }
#pragma unroll
        for (int r = 0; r < 2; ++r)
            GLL(scsrc + st_lane + r * 2048, &scorg[r * 2048 + dst_e]);
        if (tid < 64) gcs_s[tid] = gcs[(size_t)h * S_LEN + s0 + tid];
        __syncthreads();                 // B1: staged data + gcs + S^T ready

        f32x4 accv = {0.f, 0.f, 0.f, 0.f};
        f32x4 acco = {0.f, 0.f, 0.f, 0.f};
#pragma unroll
        for (int ks = 0; ks < 4; ++ks) {
            bf16x8 b_st = *(const bf16x8*)&storg[(ks * 64 + ln) * 8];
            bf16x8 a_kc = *(const bf16x8*)&kcorg[((wv * 4 + ks) * 64 + ln) * 8];
            bf16x8 a_q  = *(const bf16x8*)&qorg[((wv * 4 + ks) * 64 + ln) * 8];
            accv = __builtin_amdgcn_mfma_f32_16x16x32_bf16(a_kc, b_st, accv, 0, 0, 0);
            acco = __builtin_amdgcn_mfma_f32_16x16x32_bf16(a_q, b_st, acco, 0, 0, 0);
        }
        const float* up = u + (size_t)(h * NCHK + n) * (CCH * DVD)
                            + (wv * 16 + lkg * 4) * DVD + d0 + lrow;
        float u0 = up[0], u1 = up[DVD], u2 = up[2 * DVD], u3 = up[3 * DVD];
        const float gl = gcs_s[63];
        float vn0 = u0 - accv[0], vn1 = u1 - accv[1];
        float vn2 = u2 - accv[2], vn3 = u3 - accv[3];
        {
            const int row = wv * 16 + lkg * 4;
            float g0 = gcs_s[row], g1 = gcs_s[row + 1], g2 = gcs_s[row + 2], g3 = gcs_s[row + 3];
            acco[0] *= __expf(g0); acco[1] *= __expf(g1);
            acco[2] *= __expf(g2); acco[3] *= __expf(g3);
            const int eb = ((wv >> 1) * 64 + ((wv & 1) * 2 + (lkg >> 1)) * 16 + lrow) * 8
                         + (lkg & 1) * 4;
            union { ushort u2a[4]; uint2 v; } pa, pb;
            pa.u2a[0] = f2bf(vn0); pa.u2a[1] = f2bf(vn1);
            pa.u2a[2] = f2bf(vn2); pa.u2a[3] = f2bf(vn3);
            pb.u2a[0] = f2bf(vn0 * __expf(gl - g0)); pb.u2a[1] = f2bf(vn1 * __expf(gl - g1));
            pb.u2a[2] = f2bf(vn2 * __expf(gl - g2)); pb.u2a[3] = f2bf(vn3 * __expf(gl - g3));
            *(uint2*)&vnorg[eb] = pa.v;
            *(uint2*)&vnsorg[eb] = pb.v;
        }
        __syncthreads();                 // B2: v_new^T ready

#pragma unroll
        for (int ks = 0; ks < 2; ++ks) {
            bf16x8 a_sc = *(const bf16x8*)&scorg[((wv * 2 + ks) * 64 + ln) * 8];
            bf16x8 b_vn = *(const bf16x8*)&vnorg[(ks * 64 + ln) * 8];
            acco = __builtin_amdgcn_mfma_f32_16x16x32_bf16(a_sc, b_vn, acco, 0, 0, 0);
        }
        float* op = obuf + (size_t)(s0 + wv * 16 + lkg * 4) * VAL_DIM + h * DVD + d0 + lrow;
        op[0] = acco[0]; op[VAL_DIM] = acco[1];
        op[2 * VAL_DIM] = acco[2]; op[3 * VAL_DIM] = acco[3];

        const float egl = __expf(gl);
        accS0 *= egl; accS1 *= egl;
#pragma unroll
        for (int ks = 0; ks < 2; ++ks) {
            bf16x8 a_vs = *(const bf16x8*)&vnsorg[(ks * 64 + ln) * 8];
            bf16x8 b_k0 = *(const bf16x8*)&kTorg[(((wv * 2 + 0) * 2 + ks) * 64 + ln) * 8];
            bf16x8 b_k1 = *(const bf16x8*)&kTorg[(((wv * 2 + 1) * 2 + ks) * 64 + ln) * 8];
            accS0 = __builtin_amdgcn_mfma_f32_16x16x32_bf16(a_vs, b_k0, accS0, 0, 0, 0);
            accS1 = __builtin_amdgcn_mfma_f32_16x16x32_bf16(a_vs, b_k1, accS1, 0, 0, 0);
        }
#pragma unroll
        for (int j = 0; j < 4; ++j) {
            storg[(wv * 64 + ((lrow >> 3)) * 16 + lkg * 4 + j) * 8 + (lrow & 7)] = f2bf(accS0[j]);
            storg[(wv * 64 + (2 + (lrow >> 3)) * 16 + lkg * 4 + j) * 8 + (lrow & 7)] = f2bf(accS1[j]);
        }
        __syncthreads();                 // B3
    }
}

// ================= RMSNorm * norm_w * silu(z) -> bf16 =======================
__global__ __launch_bounds__(256) void norm_kernel(
    const float* __restrict__ obuf, const float* __restrict__ z,
    const float* __restrict__ nw, ushort* __restrict__ hbuf)
{
    int row = (blockIdx.x * 256 + threadIdx.x) >> 6;
    int lane = threadIdx.x & 63;
    float2 x = *(const float2*)(obuf + (size_t)row * DVD + lane * 2);
    float ss = x.x * x.x + x.y * x.y;
#pragma unroll
    for (int m = 1; m < 64; m <<= 1) ss += __shfl_xor(ss, m, 64);
    float scale = rsqrtf(ss * (1.f / DVD) + 1e-6f);
    float2 zz = *(const float2*)(z + (size_t)row * DVD + lane * 2);
    float2 w2 = *(const float2*)(nw + lane * 2);
    float h0 = x.x * scale * w2.x * silu_f(zz.x);
    float h1 = x.y * scale * w2.y * silu_f(zz.y);
    union { ushort u[2]; uint v; } r;
    r.u[0] = f2bf(h0); r.u[1] = f2bf(h1);
    *(uint*)(hbuf + (size_t)row * DVD + lane * 2) = r.v;
}

// ============================================================================
extern "C" void kernel_launch(void* const* d_in, const int* in_sizes, int n_in,
                              void* d_out, int out_size, void* d_ws, size_t ws_size,
                              hipStream_t stream)
{
    (void)in_sizes; (void)n_in; (void)out_size; (void)ws_size;
    const float* x      = (const float*)d_in[0];
    const float* W_qkv  = (const float*)d_in[1];
    const float* W_z    = (const float*)d_in[2];
    const float* W_a    = (const float*)d_in[3];
    const float* W_b    = (const float*)d_in[4];
    const float* conv_w = (const float*)d_in[5];
    const float* dt_b   = (const float*)d_in[6];
    const float* A_log  = (const float*)d_in[7];
    const float* norm_w = (const float*)d_in[8];
    const float* W_out  = (const float*)d_in[9];
    float* out = (float*)d_out;

    // ---- workspace layout (bytes), overlaid by liveness; total ~202.1 MB ---
    char* ws = (char*)d_ws;
    // region A @0 (67,108,864): mixed_pre -> {u f32, kcd bf16, knT bf16}
    float*  mixed_pre = (float*)(ws);
    float*  u_buf     = (float*)(ws);                   // 33,554,432
    ushort* kcd_buf   = (ushort*)(ws + 33554432);       // 16,777,216
    ushort* knT_buf   = (ushort*)(ws + 50331648);       //  8,388,608
    // region B @67,108,864 (67,108,864): casts -> mixed -> {obuf,hbuf,wob}
    ushort* xb        = (ushort*)(ws + 67108864);
    ushort* wzb       = (ushort*)(ws + 75497472);
    ushort* wqkvb     = (ushort*)(ws + 92274688);
    float*  mixed     = (float*)(ws + 67108864);
    float*  obuf      = (float*)(ws + 67108864);
    ushort* hbuf      = (ushort*)(ws + 100663296);
    ushort* wob       = (ushort*)(ws + 117440512);
    // fixed regions
    float*  z_buf     = (float*)(ws + 134217728);       // 33,554,432
    ushort* sc_buf    = (ushort*)(ws + 167772160);      //  8,388,608 (step>=6)
    ushort* wabb      = (ushort*)(ws + 167772160);      //    524,288 (steps 1-2)
    float*  ab_buf    = (float*)(ws + 168296448);       //  1,048,576 (steps 2-4)
    ushort* qnb       = (ushort*)(ws + 176160768);      //  8,388,608
    float*  kn        = (float*)(ws + 184549376);       // 16,777,216
    float*  g_buf     = (float*)(ws + 201326592);       //    262,144
    float*  bet_buf   = (float*)(ws + 201588736);       //    262,144
    float*  gcs_buf   = (float*)(ws + 201850880);       //    262,144

    hipFuncSetAttribute((const void*)phaseB_kernel,
                        hipFuncAttributeMaxDynamicSharedMemorySize, PB_LDS_BYTES);

    dim3 blk(256);
    // 1) casts to bf16
    cast_kernel<<<(S_LEN * HIDDIM / 8) / 256, blk, 0, stream>>>(x, xb, S_LEN * HIDDIM / 8);
    cast_kernel<<<(CONV_DIM * HIDDIM / 8) / 256, blk, 0, stream>>>(W_qkv, wqkvb, CONV_DIM * HIDDIM / 8);
    cast_kernel<<<(VAL_DIM * HIDDIM / 8) / 256, blk, 0, stream>>>(W_z, wzb, VAL_DIM * HIDDIM / 8);
    cast_ab_kernel<<<(128 * HIDDIM / 8) / 256, blk, 0, stream>>>(W_a, W_b, wabb);
    // 2) projections (bf16 MFMA)
    gemm_bf16_kernel<<<dim3(CONV_DIM / 128, S_LEN / 128), blk, 0, stream>>>(xb, wqkvb, mixed_pre, S_LEN, CONV_DIM, HIDDIM);
    gemm_bf16_kernel<<<dim3(VAL_DIM / 128, S_LEN / 128), blk, 0, stream>>>(xb, wzb, z_buf, S_LEN, VAL_DIM, HIDDIM);
    gemm_bf16_kernel<<<dim3(1, S_LEN / 128), blk, 0, stream>>>(xb, wabb, ab_buf, S_LEN, 128, HIDDIM);
    // 3) conv + silu (fp32)
    conv_silu_kernel<<<(S_LEN * CONV_DIM / 4) / 256, blk, 0, stream>>>(mixed_pre, conv_w, mixed);
    // 4) gates
    gb_kernel<<<(S_LEN * NVH) / 256, blk, 0, stream>>>(ab_buf, dt_b, A_log, g_buf, bet_buf);
    // 5) l2norm q,k
    l2norm_kernel<<<(2 * S_LEN * NKH * 64) / 256, blk, 0, stream>>>(mixed, qnb, kn);
    // 6) phase A (intra-chunk, MFMA + register-column substitution)
    phaseA_kernel<<<dim3(NCHK, NVH), blk, 0, stream>>>(
        qnb, kn, mixed, g_buf, bet_buf, u_buf, kcd_buf, sc_buf, gcs_buf, knT_buf);
    // 7) phase B (inter-chunk scan, MFMA)
    phaseB_kernel<<<dim3(NVH, 8), blk, PB_LDS_BYTES, stream>>>(
        qnb, knT_buf, u_buf, kcd_buf, sc_buf, gcs_buf, obuf);
    // 8) W_out cast (mixed region now dead) + gated RMSNorm -> bf16
    cast_kernel<<<(HIDDIM * VAL_DIM / 8) / 256, blk, 0, stream>>>(W_out, wob, HIDDIM * VAL_DIM / 8);
    norm_kernel<<<(S_LEN * NVH * 64) / 256, blk, 0, stream>>>(obuf, z_buf, norm_w, hbuf);
    // 9) output projection (bf16 MFMA)
    gemm_bf16_kernel<<<dim3(HIDDIM / 128, S_LEN / 128), blk, 0, stream>>>(hbuf, wob, out, S_LEN, HIDDIM, VAL_DIM);
}

// Round 5
// 546.237 us; speedup vs baseline: 6.4049x; 1.2892x over previous
//
#include <hip/hip_runtime.h>
#include <hip/hip_bf16.h>
#include <math.h>

// ---- problem constants ----
#define S_LEN   2048
#define HIDDIM  2048
#define NKH     16
#define NVH     32
#define DKD     128
#define DVD     128
#define CCH     64          // chunk
#define NCHK    32          // S/chunk
#define KEY_DIM 2048
#define VAL_DIM 4096
#define CONV_DIM 8192

// phaseA LDS: kb 16K, qb 16K (aliased as P f32[16][256]), Xb 32K,
// Adiag 4K, Ab 4K, gcs 256, bet 256, scK 256
#define PA_LDS_BYTES (16384 + 16384 + 32768 + 4096 + 4096 + 256 + 256 + 256)
// phaseB LDS (ushorts): qorg 8192, kcorg 8192, scorg 4096, kTorg 8192,
// storg 2048, vnorg 1024, vnsorg 1024  + 64 floats gcs
#define PB_LDS_BYTES ((8192+8192+4096+8192+2048+1024+1024)*2 + 64*4)

typedef __bf16 bf16x8 __attribute__((ext_vector_type(8)));
typedef float f32x4 __attribute__((ext_vector_type(4)));

__device__ __forceinline__ float sigmoid_f(float x) { return 1.f / (1.f + __expf(-x)); }
__device__ __forceinline__ float silu_f(float x) { return x * sigmoid_f(x); }
__device__ __forceinline__ ushort f2bf(float f) {
    unsigned u = __float_as_uint(f);
    u += 0x7fffu + ((u >> 16) & 1u);          // RNE (inputs finite)
    return (ushort)(u >> 16);
}
__device__ __forceinline__ float bf2f(ushort u) {
    return __uint_as_float((unsigned)u << 16);
}

#define GLL(srcp, dstp) __builtin_amdgcn_global_load_lds( \
    (const __attribute__((address_space(1))) void*)(srcp), \
    (__attribute__((address_space(3))) void*)(dstp), 16, 0, 0)

// ================= fp32 -> bf16 cast (8 elems/thread) =======================
__global__ __launch_bounds__(256) void cast_kernel(
    const float* __restrict__ in, ushort* __restrict__ out, int n8)
{
    int t = blockIdx.x * 256 + threadIdx.x;
    if (t >= n8) return;
    float4 v0 = *(const float4*)(in + (size_t)t * 8);
    float4 v1 = *(const float4*)(in + (size_t)t * 8 + 4);
    union { ushort u[8]; uint4 v; } r;
    r.u[0] = f2bf(v0.x); r.u[1] = f2bf(v0.y); r.u[2] = f2bf(v0.z); r.u[3] = f2bf(v0.w);
    r.u[4] = f2bf(v1.x); r.u[5] = f2bf(v1.y); r.u[6] = f2bf(v1.z); r.u[7] = f2bf(v1.w);
    *(uint4*)(out + (size_t)t * 8) = r.v;
}

// ====== W_a,W_b -> one padded bf16 weight [128,2048] (rows 64..127 zero) ====
__global__ __launch_bounds__(256) void cast_ab_kernel(
    const float* __restrict__ Wa, const float* __restrict__ Wb, ushort* __restrict__ out)
{
    int t = blockIdx.x * 256 + threadIdx.x;          // 128*2048/8 = 32768 threads
    int row = t >> 8;
    int c8 = (t & 255) * 8;
    union { ushort u[8]; uint4 v; } r;
    if (row < 64) {
        const float* src = (row < 32) ? (Wa + (size_t)row * HIDDIM + c8)
                                      : (Wb + (size_t)(row - 32) * HIDDIM + c8);
        float4 v0 = *(const float4*)(src);
        float4 v1 = *(const float4*)(src + 4);
        r.u[0] = f2bf(v0.x); r.u[1] = f2bf(v0.y); r.u[2] = f2bf(v0.z); r.u[3] = f2bf(v0.w);
        r.u[4] = f2bf(v1.x); r.u[5] = f2bf(v1.y); r.u[6] = f2bf(v1.z); r.u[7] = f2bf(v1.w);
    } else {
        r.u[0] = r.u[1] = r.u[2] = r.u[3] = r.u[4] = r.u[5] = r.u[6] = r.u[7] = 0;
    }
    *(uint4*)(out + (size_t)t * 8) = r.v;
}

// ================= bf16 MFMA GEMM: C[M,N] = A[M,K] @ B[N,K]^T (f32 out) =====
__global__ __launch_bounds__(256) void gemm_bf16_kernel(
    const ushort* __restrict__ A, const ushort* __restrict__ B, float* __restrict__ C,
    int M, int N, int K)
{
    __shared__ ushort Alds[128 * 32];
    __shared__ ushort Blds[128 * 32];
    const int tid = threadIdx.x;
    const int wv = tid >> 6, ln = tid & 63;
    const int bm = blockIdx.y * 128, bn = blockIdx.x * 128;
    const int wr = (wv >> 1) * 64, wc = (wv & 1) * 64;
    const int lrow = ln & 15, lkg = ln >> 4;

    f32x4 acc[4][4];
#pragma unroll
    for (int m = 0; m < 4; ++m)
#pragma unroll
        for (int n = 0; n < 4; ++n) {
            f32x4 z = {0.f, 0.f, 0.f, 0.f};
            acc[m][n] = z;
        }

    const int arow = tid >> 2, ak8 = (tid & 3) * 8;
    const ushort* srcA0 = A + (size_t)(bm + arow) * K + ak8;
    const ushort* srcA1 = A + (size_t)(bm + 64 + arow) * K + ak8;
    const ushort* srcB0 = B + (size_t)(bn + arow) * K + ak8;
    const ushort* srcB1 = B + (size_t)(bn + 64 + arow) * K + ak8;
    ushort* dstA0 = &Alds[(size_t)(wv * 64) * 8];
    ushort* dstA1 = &Alds[(size_t)(256 + wv * 64) * 8];
    ushort* dstB0 = &Blds[(size_t)(wv * 64) * 8];
    ushort* dstB1 = &Blds[(size_t)(256 + wv * 64) * 8];

    for (int k0 = 0; k0 < K; k0 += 32) {
        GLL(srcA0 + k0, dstA0);
        GLL(srcA1 + k0, dstA1);
        GLL(srcB0 + k0, dstB0);
        GLL(srcB1 + k0, dstB1);
        __syncthreads();

        bf16x8 af[4], bfr[4];
#pragma unroll
        for (int m = 0; m < 4; ++m)
            af[m] = *(const bf16x8*)&Alds[(size_t)(wr + m * 16 + lrow) * 32 + lkg * 8];
#pragma unroll
        for (int n = 0; n < 4; ++n)
            bfr[n] = *(const bf16x8*)&Blds[(size_t)(wc + n * 16 + lrow) * 32 + lkg * 8];
#pragma unroll
        for (int m = 0; m < 4; ++m)
#pragma unroll
            for (int n = 0; n < 4; ++n)
                acc[m][n] = __builtin_amdgcn_mfma_f32_16x16x32_bf16(
                    af[m], bfr[n], acc[m][n], 0, 0, 0);
        __syncthreads();
    }

#pragma unroll
    for (int m = 0; m < 4; ++m) {
        int row0 = bm + wr + m * 16 + lkg * 4;
#pragma unroll
        for (int n = 0; n < 4; ++n) {
            int col = bn + wc + n * 16 + lrow;
            float* cp = C + (size_t)row0 * N + col;
#pragma unroll
            for (int j = 0; j < 4; ++j) cp[(size_t)j * N] = acc[m][n][j];
        }
    }
}

// ================= causal depthwise conv1d (K=4) + SiLU =====================
__global__ __launch_bounds__(256) void conv_silu_kernel(
    const float* __restrict__ pre, const float* __restrict__ cw, float* __restrict__ out)
{
    int idx = blockIdx.x * 256 + threadIdx.x;
    const int NC4 = CONV_DIM / 4;
    int s = idx / NC4;
    int c = (idx % NC4) * 4;
    float w[4][4];
#pragma unroll
    for (int j = 0; j < 4; ++j) {
        float4 wj = *(const float4*)(cw + (size_t)(c + j) * 4);
        w[j][0] = wj.x; w[j][1] = wj.y; w[j][2] = wj.z; w[j][3] = wj.w;
    }
    float acc[4] = {0.f, 0.f, 0.f, 0.f};
#pragma unroll
    for (int t = 0; t < 4; ++t) {
        int ss = s - 3 + t;
        if (ss >= 0) {
            float4 x = *(const float4*)(pre + (size_t)ss * CONV_DIM + c);
            acc[0] = fmaf(x.x, w[0][t], acc[0]);
            acc[1] = fmaf(x.y, w[1][t], acc[1]);
            acc[2] = fmaf(x.z, w[2][t], acc[2]);
            acc[3] = fmaf(x.w, w[3][t], acc[3]);
        }
    }
    float4 o = make_float4(silu_f(acc[0]), silu_f(acc[1]), silu_f(acc[2]), silu_f(acc[3]));
    *(float4*)(out + (size_t)s * CONV_DIM + c) = o;
}

// ====== g = -exp(A_log)*softplus(a+dt_bias), beta = sigmoid(b) ==============
__global__ __launch_bounds__(256) void gb_kernel(
    const float* __restrict__ ab, const float* __restrict__ dt_bias,
    const float* __restrict__ A_log, float* __restrict__ g, float* __restrict__ beta)
{
    int idx = blockIdx.x * 256 + threadIdx.x;
    int s = idx >> 5, h = idx & 31;
    float av = ab[(size_t)s * 128 + h] + dt_bias[h];
    float sp = (av > 20.f) ? av : log1pf(__expf(av));
    g[idx] = -__expf(A_log[h]) * sp;
    beta[idx] = sigmoid_f(ab[(size_t)s * 128 + 32 + h]);
}

// ===== l2norm q,k: q -> bf16 (qnb), k -> f32 (kn) ===========================
__global__ __launch_bounds__(256) void l2norm_kernel(
    const float* __restrict__ mixed, ushort* __restrict__ qnb, float* __restrict__ kn)
{
    int gw = (blockIdx.x * 256 + threadIdx.x) >> 6;
    int lane = threadIdx.x & 63;
    int isk = gw >= S_LEN * NKH;
    int r = gw - isk * S_LEN * NKH;
    int s = r / NKH, kh = r % NKH;
    const float* src = mixed + (size_t)s * CONV_DIM + isk * KEY_DIM + kh * DKD;
    float2 x = *(const float2*)(src + lane * 2);
    float ss = x.x * x.x + x.y * x.y;
#pragma unroll
    for (int m = 1; m < 64; m <<= 1) ss += __shfl_xor(ss, m, 64);
    float scale = rsqrtf(ss + 1e-6f);
    if (!isk) {
        scale *= 0.08838834764831843f;   // DK^-0.5
        union { ushort u[2]; uint v; } p;
        p.u[0] = f2bf(x.x * scale); p.u[1] = f2bf(x.y * scale);
        *(uint*)(qnb + ((size_t)(s * NKH + kh)) * DKD + lane * 2) = p.v;
    } else {
        float* dst = kn + ((size_t)(s * NKH + kh)) * DKD + lane * 2;
        *(float2*)dst = make_float2(x.x * scale, x.y * scale);
    }
}

// ================= Phase A: per (head, chunk) intra-chunk work ==============
// v3: blocked WY solve. Off-diagonal A-block contributions via MFMA
// (bf16, zero-padded K=32 frags), only 16x16 diagonal solves stay scalar
// (fp32, 120 FMA each). 8 barriers total.
// outputs: u f32, kcd bf16, scores bf16, gcs f32, knT bf16 (even h only)
__global__ __launch_bounds__(256) void phaseA_kernel(
    const ushort* __restrict__ qnb, const float* __restrict__ kn,
    const float* __restrict__ mixed, const float* __restrict__ gbuf,
    const float* __restrict__ betabuf,
    float* __restrict__ u, ushort* __restrict__ kcd,
    ushort* __restrict__ scores, float* __restrict__ gcs_out,
    ushort* __restrict__ knT)
{
    extern __shared__ char pasm[];
    ushort* kb    = (ushort*)(pasm);            // 16KB frag [m4][ks4][64][8]
    ushort* qb    = (ushort*)(pasm + 16384);    // 16KB frag; later P f32[16][256]
    ushort* Xb    = (ushort*)(pasm + 32768);    // 32KB [t2(2)][ct(16)][64][8]
    float*  Adiag = (float*)(pasm + 65536);     // 4KB [4][16][16] fp32 diag blocks
    ushort* Ab    = (ushort*)(pasm + 69632);    // 4KB: 4 frags 16x32 bf16 (K=32 padded)
    float*  gcs_s = (float*)(pasm + 73728);     // 64 f
    float*  bet_s = (float*)(pasm + 73984);     // 64 f
    float*  scK_s = (float*)(pasm + 74240);     // 64 f : beta*exp(gcs)
    float*  Pf    = (float*)qb;                 // alias (qb dead after QK^T MFMA)

    const int n = blockIdx.x, h = blockIdx.y, kh = h >> 1;
    const int tid = threadIdx.x;
    const int s0 = n * CCH;
    const int wv = tid >> 6, ln = tid & 63;
    const int lrow = ln & 15, lkg = ln >> 4;

    // ---- issue RHS column raw loads early (latency hides under MFMA phase) -
    // thread d<128 owns value-column d; d>=128 owns key-column d-128.
    float xr[64];
    if (tid < 128) {
        const float* vp = mixed + (size_t)s0 * CONV_DIM + 2 * KEY_DIM + h * DVD + tid;
#pragma unroll
        for (int i = 0; i < 64; ++i) xr[i] = vp[(size_t)i * CONV_DIM];
    } else {
        const float* kp = kn + ((size_t)s0 * NKH + kh) * DKD + (tid - 128);
#pragma unroll
        for (int i = 0; i < 64; ++i) xr[i] = kp[(size_t)i * (NKH * DKD)];
    }

    // ---- zero-init Xb (32KB) and Ab (4KB): padded-K regions must be 0 ----
    {
        uint4 z = {0, 0, 0, 0};
#pragma unroll
        for (int i = 0; i < 8; ++i)
            *(uint4*)&Xb[(i * 256 + tid) * 8] = z;
        *(uint4*)&Ab[tid * 8] = z;
    }

    // ---- gcs cumsum + beta + scK (wave 0) ----
    if (tid < 64) {
        float gv = gbuf[(size_t)(s0 + tid) * NVH + h];
#pragma unroll
        for (int off = 1; off < 64; off <<= 1) {
            float pv = __shfl_up(gv, off, 64);
            if (tid >= off) gv += pv;
        }
        float bv = betabuf[(size_t)(s0 + tid) * NVH + h];
        gcs_s[tid] = gv;
        bet_s[tid] = bv;
        scK_s[tid] = bv * __expf(gv);
        gcs_out[(size_t)h * S_LEN + s0 + tid] = gv;
    }

    // ---- stage k (f32->bf16) and q (bf16) into fragment-ordered LDS ----
    {
        const int r = tid >> 2, c0 = (tid & 3) * 32;
        const int mbase = (((r >> 4) * 4 + (tid & 3)) * 64 + (r & 15)) * 8;
        const float* ksrc = kn + ((size_t)(s0 + r) * NKH + kh) * DKD + c0;
#pragma unroll
        for (int j0 = 0; j0 < 4; ++j0) {
            float4 v0 = *(const float4*)(ksrc + j0 * 8);
            float4 v1 = *(const float4*)(ksrc + j0 * 8 + 4);
            union { ushort us[8]; uint4 v; } p;
            p.us[0] = f2bf(v0.x); p.us[1] = f2bf(v0.y); p.us[2] = f2bf(v0.z); p.us[3] = f2bf(v0.w);
            p.us[4] = f2bf(v1.x); p.us[5] = f2bf(v1.y); p.us[6] = f2bf(v1.z); p.us[7] = f2bf(v1.w);
            *(uint4*)&kb[mbase + (j0 << 7)] = p.v;
        }
        const ushort* qsrc = qnb + ((size_t)(s0 + r) * NKH + kh) * DKD + c0;
#pragma unroll
        for (int j0 = 0; j0 < 4; ++j0) {
            uint4 v = *(const uint4*)(qsrc + j0 * 8);
            *(uint4*)&qb[mbase + (j0 << 7)] = v;
        }
    }
    __syncthreads();    // B1: kb, qb, gcs, beta, zeros ready

    // ---- MFMA: KK^T and QK^T (wave wv owns row-tile wv) ----
    f32x4 accA[4], accQ[4];
#pragma unroll
    for (int j = 0; j < 4; ++j) {
        f32x4 z = {0.f, 0.f, 0.f, 0.f};
        accA[j] = z; accQ[j] = z;
    }
#pragma unroll
    for (int ks = 0; ks < 4; ++ks) {
        bf16x8 a_k = *(const bf16x8*)&kb[((wv * 4 + ks) * 64 + ln) * 8];
        bf16x8 a_q = *(const bf16x8*)&qb[((wv * 4 + ks) * 64 + ln) * 8];
#pragma unroll
        for (int j = 0; j < 4; ++j) {
            bf16x8 b_k = *(const bf16x8*)&kb[((j * 4 + ks) * 64 + ln) * 8];
            accA[j] = __builtin_amdgcn_mfma_f32_16x16x32_bf16(a_k, b_k, accA[j], 0, 0, 0);
            accQ[j] = __builtin_amdgcn_mfma_f32_16x16x32_bf16(a_q, b_k, accQ[j], 0, 0, 0);
        }
    }
    // ---- masks: scores -> global bf16; A -> Adiag f32 + Ab bf16 frags ----
    {
        ushort* scp = scores + (size_t)(h * NCHK + n) * (CCH * CCH);
#pragma unroll
        for (int j = 0; j < 4; ++j) {
            const int c = j * 16 + lrow;
            const float gc = gcs_s[c];
#pragma unroll
            for (int jj = 0; jj < 4; ++jj) {
                const int i = wv * 16 + lkg * 4 + jj;
                const float e = __expf(gcs_s[i] - gc);
                float sv = (i >= c) ? (accQ[j][jj] * e) : 0.f;
                scp[i * CCH + c] = f2bf(sv);
                float aval = (i > c) ? (-bet_s[i] * accA[j][jj] * e) : 0.f;
                if (j == wv) {
                    Adiag[wv * 256 + (i & 15) * 16 + lrow] = aval;
                } else if (j < wv) {
                    const int f = (wv == 1) ? 0 : ((wv == 2) ? 1 : (2 + (j >> 1)));
                    const int lk = ((j & 1) << 4) | lrow;           // k within 32-frag
                    const int lane2 = (i & 15) | ((lk >> 3) << 4);
                    Ab[(f * 64 + lane2) * 8 + (lk & 7)] = f2bf(aval);
                }
            }
        }
    }
    // ---- scale RHS in registers (chunked LDS broadcasts) ----
    if (tid < 128) {
#pragma unroll
        for (int i4 = 0; i4 < 16; ++i4) {
            float4 b4 = *(const float4*)&bet_s[i4 * 4];
            xr[i4 * 4 + 0] *= b4.x; xr[i4 * 4 + 1] *= b4.y;
            xr[i4 * 4 + 2] *= b4.z; xr[i4 * 4 + 3] *= b4.w;
        }
    } else {
#pragma unroll
        for (int i4 = 0; i4 < 16; ++i4) {
            float4 b4 = *(const float4*)&scK_s[i4 * 4];
            xr[i4 * 4 + 0] *= b4.x; xr[i4 * 4 + 1] *= b4.y;
            xr[i4 * 4 + 2] *= b4.z; xr[i4 * 4 + 3] *= b4.w;
        }
    }
    __syncthreads();    // B2: Adiag, Ab ready (qb now dead -> Pf)

    // ---- blocked forward substitution: 4 stages of 16 rows ----
    const int ct = tid >> 4, lct = tid & 15;
#pragma unroll
    for (int s = 0; s < 4; ++s) {
        float y[16];
        // rhs = xr + P (P from previous stage's MFMA; none for s=0)
        float pr[16];
        if (s > 0) {
#pragma unroll
            for (int r = 0; r < 16; ++r) pr[r] = Pf[r * 256 + tid];
        } else {
#pragma unroll
            for (int r = 0; r < 16; ++r) pr[r] = 0.f;
        }
        // 16x16 fp32 triangular solve (diag block broadcast from LDS)
#pragma unroll
        for (int r = 0; r < 16; ++r) {
            float acc = xr[s * 16 + r] + pr[r];
#pragma unroll
            for (int k4 = 0; k4 < 16; k4 += 4) {
                if (k4 < r) {
                    float4 a4 = *(const float4*)&Adiag[s * 256 + r * 16 + k4];
                    if (k4 + 0 < r) acc = fmaf(a4.x, y[k4 + 0], acc);
                    if (k4 + 1 < r) acc = fmaf(a4.y, y[k4 + 1], acc);
                    if (k4 + 2 < r) acc = fmaf(a4.z, y[k4 + 2], acc);
                    if (k4 + 3 < r) acc = fmaf(a4.w, y[k4 + 3], acc);
                }
            }
            y[r] = acc;
        }
        // global stores (coalesced across lanes: thread owns a column)
        if (tid < 128) {
            float* up = u + (size_t)(h * NCHK + n) * (CCH * DVD) + (s * 16) * DVD + tid;
#pragma unroll
            for (int r = 0; r < 16; ++r) up[r * DVD] = y[r];
        } else {
            ushort* kp = kcd + (size_t)(h * NCHK + n) * (CCH * DKD) + (s * 16) * DKD + (tid - 128);
#pragma unroll
            for (int r = 0; r < 16; ++r) kp[r * DKD] = f2bf(y[r]);
        }
        if (s < 3) {
            // publish X_s as bf16 B-frag (16x16x32 layout), for future MFMAs
#pragma unroll
            for (int half = 0; half < 2; ++half) {
                union { ushort us[8]; uint4 v; } p;
#pragma unroll
                for (int e = 0; e < 8; ++e) p.us[e] = f2bf(y[half * 8 + e]);
                const int kg = (s & 1) * 2 + half;
                *(uint4*)&Xb[(((s >> 1) * 16 + ct) * 64 + (kg * 16 + lct)) * 8] = p.v;
            }
            __syncthreads();    // Xb[s] visible; also all pr reads done
            // MFMA: P(s+1) = sum_{t2} A32[s+1][t2] @ X32[t2]  (zero-padded K)
            const int snx = s + 1;
            const int nT2 = (snx + 1) >> 1;
            f32x4 accP[4];
#pragma unroll
            for (int ctl = 0; ctl < 4; ++ctl) {
                f32x4 z = {0.f, 0.f, 0.f, 0.f};
                accP[ctl] = z;
            }
#pragma unroll
            for (int t2 = 0; t2 < 2; ++t2) {
                if (t2 < nT2) {
                    const int f = (snx == 1) ? 0 : ((snx == 2) ? 1 : (2 + t2));
                    bf16x8 a = *(const bf16x8*)&Ab[(f * 64 + ln) * 8];
#pragma unroll
                    for (int ctl = 0; ctl < 4; ++ctl) {
                        bf16x8 b = *(const bf16x8*)&Xb[((t2 * 16 + wv * 4 + ctl) * 64 + ln) * 8];
                        accP[ctl] = __builtin_amdgcn_mfma_f32_16x16x32_bf16(a, b, accP[ctl], 0, 0, 0);
                    }
                }
            }
#pragma unroll
            for (int ctl = 0; ctl < 4; ++ctl)
#pragma unroll
                for (int jj = 0; jj < 4; ++jj)
                    Pf[(lkg * 4 + jj) * 256 + wv * 64 + ctl * 16 + lrow] = accP[ctl][jj];
            __syncthreads();    // P(s+1) visible
        }
    }

    // ---- knT emit (once per kh) from kb frag-ordered LDS ----
    if (!(h & 1)) {
        const int dk = tid >> 1, ch = (tid & 1) * 32;
        ushort* dst = knT + ((size_t)(kh * NCHK + n) * DKD + dk) * CCH + ch;
        const int kpart = ((dk >> 5) * 64) * 8 + (((dk >> 3) & 3) << 4) * 8 + (dk & 7);
#pragma unroll
        for (int j0 = 0; j0 < 32; j0 += 8) {
            union { ushort us[8]; uint4 v; } p;
#pragma unroll
            for (int j = 0; j < 8; ++j) {
                const int row = ch + j0 + j;
                p.us[j] = kb[((row >> 4) * 4 * 64 + (row & 15)) * 8 + kpart];
            }
            *(uint4*)(dst + j0) = p.v;
        }
    }
}

// ================= Phase B: inter-chunk state scan (MFMA) ===================
__global__ __launch_bounds__(256) void phaseB_kernel(
    const ushort* __restrict__ qnb, const ushort* __restrict__ knT,
    const float* __restrict__ u, const ushort* __restrict__ kcd,
    const ushort* __restrict__ sc, const float* __restrict__ gcs,
    float* __restrict__ obuf)
{
    extern __shared__ ushort smu[];
    ushort* qorg  = smu;             // 8192  [m4][ks4][64][8]
    ushort* kcorg = smu + 8192;      // 8192  [m4][ks4][64][8]
    ushort* scorg = smu + 16384;     // 4096  [m4][ks2][64][8]
    ushort* kTorg = smu + 20480;     // 8192  [nt8][ks2][64][8]
    ushort* storg = smu + 28672;     // 2048  [ks4][64][8]   S^T bf16
    ushort* vnorg = smu + 30720;     // 1024  [ks2][64][8]   v_new^T
    ushort* vnsorg= smu + 31744;     // 1024  [ks2][64][8]   v_new^T * exp(gl-gcs)
    float* gcs_s  = (float*)(smu + 32768);   // 64

    const int h = blockIdx.x;            // 0..31
    const int dvb = blockIdx.y;          // 0..7
    const int d0 = dvb * 16;
    const int kh = h >> 1;
    const int tid = threadIdx.x;
    const int wv = tid >> 6, ln = tid & 63;
    const int lrow = ln & 15, lkg = ln >> 4;

    for (int i = tid; i < 2048 / 8; i += 256) {
        uint4 z = {0, 0, 0, 0};
        *(uint4*)&storg[i * 8] = z;
    }

    const int q_lane  = lrow * (NKH * DKD) + kh * DKD + wv * 32 + lkg * 8;
    const int kc_lane = lrow * DKD + wv * 32 + lkg * 8;
    const int st_lane = ((tid >> 7) * 16 + lrow) * 64 + ((tid >> 6) & 1) * 32 + lkg * 8;
    const int dst_e   = wv * 512;

    f32x4 accS0 = {0.f, 0.f, 0.f, 0.f}, accS1 = {0.f, 0.f, 0.f, 0.f};

    for (int n = 0; n < NCHK; ++n) {
        const int s0 = n * CCH;
        const ushort* qsrc  = qnb + (size_t)s0 * (NKH * DKD);
        const ushort* kcsrc = kcd + (size_t)(h * NCHK + n) * (CCH * DKD);
        const ushort* scsrc = sc  + (size_t)(h * NCHK + n) * (CCH * CCH);
        const ushort* kTsrc = knT + (size_t)(kh * NCHK + n) * (DKD * CCH);
#pragma unroll
        for (int r = 0; r < 4; ++r) {
            GLL(qsrc + q_lane + r * 32768, &qorg[r * 2048 + dst_e]);
            GLL(kcsrc + kc_lane + r * 2048, &kcorg[r * 2048 + dst_e]);
            GLL(kTsrc + st_lane + r * 2048, &kTorg[r * 2048 + dst_e]);
        }
#pragma unroll
        for (int r = 0; r < 2; ++r)
            GLL(scsrc + st_lane + r * 2048, &scorg[r * 2048 + dst_e]);
        if (tid < 64) gcs_s[tid] = gcs[(size_t)h * S_LEN + s0 + tid];
        __syncthreads();                 // B1: staged data + gcs + S^T ready

        f32x4 accv = {0.f, 0.f, 0.f, 0.f};
        f32x4 acco = {0.f, 0.f, 0.f, 0.f};
#pragma unroll
        for (int ks = 0; ks < 4; ++ks) {
            bf16x8 b_st = *(const bf16x8*)&storg[(ks * 64 + ln) * 8];
            bf16x8 a_kc = *(const bf16x8*)&kcorg[((wv * 4 + ks) * 64 + ln) * 8];
            bf16x8 a_q  = *(const bf16x8*)&qorg[((wv * 4 + ks) * 64 + ln) * 8];
            accv = __builtin_amdgcn_mfma_f32_16x16x32_bf16(a_kc, b_st, accv, 0, 0, 0);
            acco = __builtin_amdgcn_mfma_f32_16x16x32_bf16(a_q, b_st, acco, 0, 0, 0);
        }
        const float* up = u + (size_t)(h * NCHK + n) * (CCH * DVD)
                            + (wv * 16 + lkg * 4) * DVD + d0 + lrow;
        float u0 = up[0], u1 = up[DVD], u2 = up[2 * DVD], u3 = up[3 * DVD];
        const float gl = gcs_s[63];
        float vn0 = u0 - accv[0], vn1 = u1 - accv[1];
        float vn2 = u2 - accv[2], vn3 = u3 - accv[3];
        {
            const int row = wv * 16 + lkg * 4;
            float g0 = gcs_s[row], g1 = gcs_s[row + 1], g2 = gcs_s[row + 2], g3 = gcs_s[row + 3];
            acco[0] *= __expf(g0); acco[1] *= __expf(g1);
            acco[2] *= __expf(g2); acco[3] *= __expf(g3);
            const int eb = ((wv >> 1) * 64 + ((wv & 1) * 2 + (lkg >> 1)) * 16 + lrow) * 8
                         + (lkg & 1) * 4;
            union { ushort u2a[4]; uint2 v; } pa, pb;
            pa.u2a[0] = f2bf(vn0); pa.u2a[1] = f2bf(vn1);
            pa.u2a[2] = f2bf(vn2); pa.u2a[3] = f2bf(vn3);
            pb.u2a[0] = f2bf(vn0 * __expf(gl - g0)); pb.u2a[1] = f2bf(vn1 * __expf(gl - g1));
            pb.u2a[2] = f2bf(vn2 * __expf(gl - g2)); pb.u2a[3] = f2bf(vn3 * __expf(gl - g3));
            *(uint2*)&vnorg[eb] = pa.v;
            *(uint2*)&vnsorg[eb] = pb.v;
        }
        __syncthreads();                 // B2: v_new^T ready

#pragma unroll
        for (int ks = 0; ks < 2; ++ks) {
            bf16x8 a_sc = *(const bf16x8*)&scorg[((wv * 2 + ks) * 64 + ln) * 8];
            bf16x8 b_vn = *(const bf16x8*)&vnorg[(ks * 64 + ln) * 8];
            acco = __builtin_amdgcn_mfma_f32_16x16x32_bf16(a_sc, b_vn, acco, 0, 0, 0);
        }
        float* op = obuf + (size_t)(s0 + wv * 16 + lkg * 4) * VAL_DIM + h * DVD + d0 + lrow;
        op[0] = acco[0]; op[VAL_DIM] = acco[1];
        op[2 * VAL_DIM] = acco[2]; op[3 * VAL_DIM] = acco[3];

        const float egl = __expf(gl);
        accS0 *= egl; accS1 *= egl;
#pragma unroll
        for (int ks = 0; ks < 2; ++ks) {
            bf16x8 a_vs = *(const bf16x8*)&vnsorg[(ks * 64 + ln) * 8];
            bf16x8 b_k0 = *(const bf16x8*)&kTorg[(((wv * 2 + 0) * 2 + ks) * 64 + ln) * 8];
            bf16x8 b_k1 = *(const bf16x8*)&kTorg[(((wv * 2 + 1) * 2 + ks) * 64 + ln) * 8];
            accS0 = __builtin_amdgcn_mfma_f32_16x16x32_bf16(a_vs, b_k0, accS0, 0, 0, 0);
            accS1 = __builtin_amdgcn_mfma_f32_16x16x32_bf16(a_vs, b_k1, accS1, 0, 0, 0);
        }
#pragma unroll
        for (int j = 0; j < 4; ++j) {
            storg[(wv * 64 + ((lrow >> 3)) * 16 + lkg * 4 + j) * 8 + (lrow & 7)] = f2bf(accS0[j]);
            storg[(wv * 64 + (2 + (lrow >> 3)) * 16 + lkg * 4 + j) * 8 + (lrow & 7)] = f2bf(accS1[j]);
        }
        __syncthreads();                 // B3
    }
}

// ================= RMSNorm * norm_w * silu(z) -> bf16 =======================
__global__ __launch_bounds__(256) void norm_kernel(
    const float* __restrict__ obuf, const float* __restrict__ z,
    const float* __restrict__ nw, ushort* __restrict__ hbuf)
{
    int row = (blockIdx.x * 256 + threadIdx.x) >> 6;
    int lane = threadIdx.x & 63;
    float2 x = *(const float2*)(obuf + (size_t)row * DVD + lane * 2);
    float ss = x.x * x.x + x.y * x.y;
#pragma unroll
    for (int m = 1; m < 64; m <<= 1) ss += __shfl_xor(ss, m, 64);
    float scale = rsqrtf(ss * (1.f / DVD) + 1e-6f);
    float2 zz = *(const float2*)(z + (size_t)row * DVD + lane * 2);
    float2 w2 = *(const float2*)(nw + lane * 2);
    float h0 = x.x * scale * w2.x * silu_f(zz.x);
    float h1 = x.y * scale * w2.y * silu_f(zz.y);
    union { ushort u[2]; uint v; } r;
    r.u[0] = f2bf(h0); r.u[1] = f2bf(h1);
    *(uint*)(hbuf + (size_t)row * DVD + lane * 2) = r.v;
}

// ============================================================================
extern "C" void kernel_launch(void* const* d_in, const int* in_sizes, int n_in,
                              void* d_out, int out_size, void* d_ws, size_t ws_size,
                              hipStream_t stream)
{
    (void)in_sizes; (void)n_in; (void)out_size; (void)ws_size;
    const float* x      = (const float*)d_in[0];
    const float* W_qkv  = (const float*)d_in[1];
    const float* W_z    = (const float*)d_in[2];
    const float* W_a    = (const float*)d_in[3];
    const float* W_b    = (const float*)d_in[4];
    const float* conv_w = (const float*)d_in[5];
    const float* dt_b   = (const float*)d_in[6];
    const float* A_log  = (const float*)d_in[7];
    const float* norm_w = (const float*)d_in[8];
    const float* W_out  = (const float*)d_in[9];
    float* out = (float*)d_out;

    // ---- workspace layout (bytes), overlaid by liveness; total ~202.1 MB ---
    char* ws = (char*)d_ws;
    // region A @0 (67,108,864): mixed_pre -> {u f32, kcd bf16, knT bf16}
    float*  mixed_pre = (float*)(ws);
    float*  u_buf     = (float*)(ws);                   // 33,554,432
    ushort* kcd_buf   = (ushort*)(ws + 33554432);       // 16,777,216
    ushort* knT_buf   = (ushort*)(ws + 50331648);       //  8,388,608
    // region B @67,108,864 (67,108,864): casts -> mixed -> {obuf,hbuf,wob}
    ushort* xb        = (ushort*)(ws + 67108864);
    ushort* wzb       = (ushort*)(ws + 75497472);
    ushort* wqkvb     = (ushort*)(ws + 92274688);
    float*  mixed     = (float*)(ws + 67108864);
    float*  obuf      = (float*)(ws + 67108864);
    ushort* hbuf      = (ushort*)(ws + 100663296);
    ushort* wob       = (ushort*)(ws + 117440512);
    // fixed regions
    float*  z_buf     = (float*)(ws + 134217728);       // 33,554,432
    ushort* sc_buf    = (ushort*)(ws + 167772160);      //  8,388,608 (step>=6)
    ushort* wabb      = (ushort*)(ws + 167772160);      //    524,288 (steps 1-2)
    float*  ab_buf    = (float*)(ws + 168296448);       //  1,048,576 (steps 2-4)
    ushort* qnb       = (ushort*)(ws + 176160768);      //  8,388,608
    float*  kn        = (float*)(ws + 184549376);       // 16,777,216
    float*  g_buf     = (float*)(ws + 201326592);       //    262,144
    float*  bet_buf   = (float*)(ws + 201588736);       //    262,144
    float*  gcs_buf   = (float*)(ws + 201850880);       //    262,144

    hipFuncSetAttribute((const void*)phaseA_kernel,
                        hipFuncAttributeMaxDynamicSharedMemorySize, PA_LDS_BYTES);
    hipFuncSetAttribute((const void*)phaseB_kernel,
                        hipFuncAttributeMaxDynamicSharedMemorySize, PB_LDS_BYTES);

    dim3 blk(256);
    // 1) casts to bf16
    cast_kernel<<<(S_LEN * HIDDIM / 8) / 256, blk, 0, stream>>>(x, xb, S_LEN * HIDDIM / 8);
    cast_kernel<<<(CONV_DIM * HIDDIM / 8) / 256, blk, 0, stream>>>(W_qkv, wqkvb, CONV_DIM * HIDDIM / 8);
    cast_kernel<<<(VAL_DIM * HIDDIM / 8) / 256, blk, 0, stream>>>(W_z, wzb, VAL_DIM * HIDDIM / 8);
    cast_ab_kernel<<<(128 * HIDDIM / 8) / 256, blk, 0, stream>>>(W_a, W_b, wabb);
    // 2) projections (bf16 MFMA)
    gemm_bf16_kernel<<<dim3(CONV_DIM / 128, S_LEN / 128), blk, 0, stream>>>(xb, wqkvb, mixed_pre, S_LEN, CONV_DIM, HIDDIM);
    gemm_bf16_kernel<<<dim3(VAL_DIM / 128, S_LEN / 128), blk, 0, stream>>>(xb, wzb, z_buf, S_LEN, VAL_DIM, HIDDIM);
    gemm_bf16_kernel<<<dim3(1, S_LEN / 128), blk, 0, stream>>>(xb, wabb, ab_buf, S_LEN, 128, HIDDIM);
    // 3) conv + silu (fp32)
    conv_silu_kernel<<<(S_LEN * CONV_DIM / 4) / 256, blk, 0, stream>>>(mixed_pre, conv_w, mixed);
    // 4) gates
    gb_kernel<<<(S_LEN * NVH) / 256, blk, 0, stream>>>(ab_buf, dt_b, A_log, g_buf, bet_buf);
    // 5) l2norm q,k
    l2norm_kernel<<<(2 * S_LEN * NKH * 64) / 256, blk, 0, stream>>>(mixed, qnb, kn);
    // 6) phase A (intra-chunk, blocked-MFMA solve)
    phaseA_kernel<<<dim3(NCHK, NVH), blk, PA_LDS_BYTES, stream>>>(
        qnb, kn, mixed, g_buf, bet_buf, u_buf, kcd_buf, sc_buf, gcs_buf, knT_buf);
    // 7) phase B (inter-chunk scan, MFMA)
    phaseB_kernel<<<dim3(NVH, 8), blk, PB_LDS_BYTES, stream>>>(
        qnb, knT_buf, u_buf, kcd_buf, sc_buf, gcs_buf, obuf);
    // 8) W_out cast (mixed region now dead) + gated RMSNorm -> bf16
    cast_kernel<<<(HIDDIM * VAL_DIM / 8) / 256, blk, 0, stream>>>(W_out, wob, HIDDIM * VAL_DIM / 8);
    norm_kernel<<<(S_LEN * NVH * 64) / 256, blk, 0, stream>>>(obuf, z_buf, norm_w, hbuf);
    // 9) output projection (bf16 MFMA)
    gemm_bf16_kernel<<<dim3(HIDDIM / 128, S_LEN / 128), blk, 0, stream>>>(hbuf, wob, out, S_LEN, HIDDIM, VAL_DIM);
}

// Round 6
// 531.765 us; speedup vs baseline: 6.5792x; 1.0272x over previous
//
#include <hip/hip_runtime.h>
#include <hip/hip_bf16.h>
#include <math.h>

// ---- problem constants ----
#define S_LEN   2048
#define HIDDIM  2048
#define NKH     16
#define NVH     32
#define DKD     128
#define DVD     128
#define CCH     64          // chunk
#define NCHK    32          // S/chunk
#define KEY_DIM 2048
#define VAL_DIM 4096
#define CONV_DIM 8192

// phaseA LDS: kb 16K, qb 16K (aliased as P f32[16][256]), Xb 32K,
// Adiag 4K, Ab 4K, gcs 256, bet 256, scK 256
#define PA_LDS_BYTES (16384 + 16384 + 32768 + 4096 + 4096 + 256 + 256 + 256)
// phaseB LDS bytes
#define PB_LDS_BYTES ((8192+8192+4096+8192+2048+1024+1024)*2 + 64*4)
// gemm LDS: 2 buf x 2 mat x (granules x 16B)
#define G256_LDS_BYTES (2 * 2 * 2048 * 16)   // 131072
#define G128_LDS_BYTES (2 * 2 * 1024 * 16)   // 65536

typedef __bf16 bf16x8 __attribute__((ext_vector_type(8)));
typedef float f32x4 __attribute__((ext_vector_type(4)));

__device__ __forceinline__ float sigmoid_f(float x) { return 1.f / (1.f + __expf(-x)); }
__device__ __forceinline__ float silu_f(float x) { return x * sigmoid_f(x); }
__device__ __forceinline__ ushort f2bf(float f) {
    unsigned u = __float_as_uint(f);
    u += 0x7fffu + ((u >> 16) & 1u);          // RNE (inputs finite)
    return (ushort)(u >> 16);
}
__device__ __forceinline__ float bf2f(ushort u) {
    return __uint_as_float((unsigned)u << 16);
}

#define GLL(srcp, dstp) __builtin_amdgcn_global_load_lds( \
    (const __attribute__((address_space(1))) void*)(srcp), \
    (__attribute__((address_space(3))) void*)(dstp), 16, 0, 0)

// ================= fp32 -> bf16 cast (8 elems/thread) =======================
__global__ __launch_bounds__(256) void cast_kernel(
    const float* __restrict__ in, ushort* __restrict__ out, int n8)
{
    int t = blockIdx.x * 256 + threadIdx.x;
    if (t >= n8) return;
    float4 v0 = *(const float4*)(in + (size_t)t * 8);
    float4 v1 = *(const float4*)(in + (size_t)t * 8 + 4);
    union { ushort u[8]; uint4 v; } r;
    r.u[0] = f2bf(v0.x); r.u[1] = f2bf(v0.y); r.u[2] = f2bf(v0.z); r.u[3] = f2bf(v0.w);
    r.u[4] = f2bf(v1.x); r.u[5] = f2bf(v1.y); r.u[6] = f2bf(v1.z); r.u[7] = f2bf(v1.w);
    *(uint4*)(out + (size_t)t * 8) = r.v;
}

// ====== W_a,W_b -> one padded bf16 weight [128,2048] (rows 64..127 zero) ====
__global__ __launch_bounds__(256) void cast_ab_kernel(
    const float* __restrict__ Wa, const float* __restrict__ Wb, ushort* __restrict__ out)
{
    int t = blockIdx.x * 256 + threadIdx.x;          // 128*2048/8 = 32768 threads
    int row = t >> 8;
    int c8 = (t & 255) * 8;
    union { ushort u[8]; uint4 v; } r;
    if (row < 64) {
        const float* src = (row < 32) ? (Wa + (size_t)row * HIDDIM + c8)
                                      : (Wb + (size_t)(row - 32) * HIDDIM + c8);
        float4 v0 = *(const float4*)(src);
        float4 v1 = *(const float4*)(src + 4);
        r.u[0] = f2bf(v0.x); r.u[1] = f2bf(v0.y); r.u[2] = f2bf(v0.z); r.u[3] = f2bf(v0.w);
        r.u[4] = f2bf(v1.x); r.u[5] = f2bf(v1.y); r.u[6] = f2bf(v1.z); r.u[7] = f2bf(v1.w);
    } else {
        r.u[0] = r.u[1] = r.u[2] = r.u[3] = r.u[4] = r.u[5] = r.u[6] = r.u[7] = 0;
    }
    *(uint4*)(out + (size_t)t * 8) = r.v;
}

// ======== 256x256 pipelined bf16 GEMM, dual f32 output (col split) ==========
// C[M,Ntot] = A[M,K] @ B[Ntot,K]^T ; cols < NSPLIT -> C0 (ldc0), else C1.
// 512 thr = 8 waves (2M x 4N). BK=64, double-buffered frag-ordered LDS.
// Staging of tile t+1 issued at top of tile t; raw s_barrier (no vmcnt drain);
// single explicit vmcnt(0) per tile where only own-tile loads are outstanding.
__global__ __launch_bounds__(512, 2) void gemm256_kernel(
    const ushort* __restrict__ A, const ushort* __restrict__ B,
    float* __restrict__ C0, float* __restrict__ C1,
    int K, int NSPLIT, int ldc0, int ldc1)
{
    extern __shared__ ushort g2s[];          // [buf2][mat2][2048 gran][8]
    const int tid = threadIdx.x;
    const int wv = tid >> 6, ln = tid & 63;
    const int wm = wv >> 2, wn = wv & 3;
    const int lrow = ln & 15, lkg = ln >> 4;
    const int bm = blockIdx.y * 256, bn = blockIdx.x * 256;

    // per-thread staging source offsets: granule g = tid + i*512
    // g -> frag=g>>7, ks=(g>>6)&1, l=g&63 ; elem (frag*16+(l&15), ks*32+(l>>4)*8)
    int soff[4];
#pragma unroll
    for (int i = 0; i < 4; ++i) {
        int g = tid + i * 512;
        int frag = g >> 7, ks = (g >> 6) & 1, l = g & 63;
        soff[i] = (frag * 16 + (l & 15)) * K + ks * 32 + (l >> 4) * 8;
    }
    const ushort* Abase = A + (size_t)bm * K;
    const ushort* Bbase = B + (size_t)bn * K;

    f32x4 acc[8][4];
#pragma unroll
    for (int m = 0; m < 8; ++m)
#pragma unroll
        for (int n = 0; n < 4; ++n) {
            f32x4 z = {0.f, 0.f, 0.f, 0.f};
            acc[m][n] = z;
        }

#define G256_STAGE(bsel, k0) do {                                          \
        ushort* dA_ = g2s + ((bsel) * 2 + 0) * 16384 + (wv * 64) * 8;      \
        ushort* dB_ = g2s + ((bsel) * 2 + 1) * 16384 + (wv * 64) * 8;      \
        _Pragma("unroll")                                                  \
        for (int i_ = 0; i_ < 4; ++i_) {                                   \
            GLL(Abase + soff[i_] + (k0), dA_ + i_ * 512 * 8);              \
            GLL(Bbase + soff[i_] + (k0), dB_ + i_ * 512 * 8);              \
        }                                                                  \
    } while (0)

    G256_STAGE(0, 0);
    const int T = K >> 6;
    for (int t = 0; t < T; ++t) {
        const int cur = t & 1;
        // only this tile's 8 loads are outstanding (issued one tile ago)
        asm volatile("s_waitcnt vmcnt(0)" ::: "memory");
        __builtin_amdgcn_s_barrier();                  // tile data visible
        if (t + 1 < T) G256_STAGE(cur ^ 1, (t + 1) * 64);
        const ushort* LA = g2s + (cur * 2 + 0) * 16384;
        const ushort* LB = g2s + (cur * 2 + 1) * 16384;
#pragma unroll
        for (int q = 0; q < 4; ++q) {
            const int mq = q >> 1, nq = q & 1;
            __builtin_amdgcn_s_setprio(1);
#pragma unroll
            for (int ks = 0; ks < 2; ++ks) {
                bf16x8 bfv[2];
#pragma unroll
                for (int nf = 0; nf < 2; ++nf) {
                    const int fragB = wn * 4 + nq * 2 + nf;
                    bfv[nf] = *(const bf16x8*)&LB[((fragB * 2 + ks) * 64 + ln) * 8];
                }
#pragma unroll
                for (int mf = 0; mf < 4; ++mf) {
                    const int fragA = wm * 8 + mq * 4 + mf;
                    bf16x8 af = *(const bf16x8*)&LA[((fragA * 2 + ks) * 64 + ln) * 8];
                    acc[mq * 4 + mf][nq * 2 + 0] = __builtin_amdgcn_mfma_f32_16x16x32_bf16(
                        af, bfv[0], acc[mq * 4 + mf][nq * 2 + 0], 0, 0, 0);
                    acc[mq * 4 + mf][nq * 2 + 1] = __builtin_amdgcn_mfma_f32_16x16x32_bf16(
                        af, bfv[1], acc[mq * 4 + mf][nq * 2 + 1], 0, 0, 0);
                }
            }
            __builtin_amdgcn_s_setprio(0);
        }
        __builtin_amdgcn_s_barrier();   // reads of buf[cur] done before t+1 writes it
    }
#undef G256_STAGE

    // epilogue: dual-output split (block entirely on one side; NSPLIT%256==0)
    const bool inC1 = (bn >= NSPLIT);
    float* Cp = inC1 ? C1 : C0;
    const int ldc = inC1 ? ldc1 : ldc0;
    const int cb = bn + wn * 64 - (inC1 ? NSPLIT : 0);
#pragma unroll
    for (int mf = 0; mf < 8; ++mf) {
        const int row0 = bm + wm * 128 + mf * 16 + lkg * 4;
#pragma unroll
        for (int nf = 0; nf < 4; ++nf) {
            float* cp = Cp + (size_t)row0 * ldc + cb + nf * 16 + lrow;
#pragma unroll
            for (int j = 0; j < 4; ++j) cp[(size_t)j * ldc] = acc[mf][nf][j];
        }
    }
}

// ======== 128x128 pipelined bf16 GEMM (same structure, 4 waves) =============
__global__ __launch_bounds__(256, 2) void gemm128_kernel(
    const ushort* __restrict__ A, const ushort* __restrict__ B,
    float* __restrict__ C, int N, int K)
{
    extern __shared__ ushort g1s[];          // [buf2][mat2][1024 gran][8]
    const int tid = threadIdx.x;
    const int wv = tid >> 6, ln = tid & 63;
    const int wm = wv >> 1, wn = wv & 1;
    const int lrow = ln & 15, lkg = ln >> 4;
    const int bm = blockIdx.y * 128, bn = blockIdx.x * 128;

    int soff[4];
#pragma unroll
    for (int i = 0; i < 4; ++i) {
        int g = tid + i * 256;
        int frag = g >> 7, ks = (g >> 6) & 1, l = g & 63;
        soff[i] = (frag * 16 + (l & 15)) * K + ks * 32 + (l >> 4) * 8;
    }
    const ushort* Abase = A + (size_t)bm * K;
    const ushort* Bbase = B + (size_t)bn * K;

    f32x4 acc[4][4];
#pragma unroll
    for (int m = 0; m < 4; ++m)
#pragma unroll
        for (int n = 0; n < 4; ++n) {
            f32x4 z = {0.f, 0.f, 0.f, 0.f};
            acc[m][n] = z;
        }

#define G128_STAGE(bsel, k0) do {                                          \
        ushort* dA_ = g1s + ((bsel) * 2 + 0) * 8192 + (wv * 64) * 8;       \
        ushort* dB_ = g1s + ((bsel) * 2 + 1) * 8192 + (wv * 64) * 8;       \
        _Pragma("unroll")                                                  \
        for (int i_ = 0; i_ < 4; ++i_) {                                   \
            GLL(Abase + soff[i_] + (k0), dA_ + i_ * 256 * 8);              \
            GLL(Bbase + soff[i_] + (k0), dB_ + i_ * 256 * 8);              \
        }                                                                  \
    } while (0)

    G128_STAGE(0, 0);
    const int T = K >> 6;
    for (int t = 0; t < T; ++t) {
        const int cur = t & 1;
        asm volatile("s_waitcnt vmcnt(0)" ::: "memory");
        __builtin_amdgcn_s_barrier();
        if (t + 1 < T) G128_STAGE(cur ^ 1, (t + 1) * 64);
        const ushort* LA = g1s + (cur * 2 + 0) * 8192;
        const ushort* LB = g1s + (cur * 2 + 1) * 8192;
        __builtin_amdgcn_s_setprio(1);
#pragma unroll
        for (int ks = 0; ks < 2; ++ks) {
            bf16x8 bfv[4], afv[4];
#pragma unroll
            for (int nf = 0; nf < 4; ++nf)
                bfv[nf] = *(const bf16x8*)&LB[(((wn * 4 + nf) * 2 + ks) * 64 + ln) * 8];
#pragma unroll
            for (int mf = 0; mf < 4; ++mf)
                afv[mf] = *(const bf16x8*)&LA[(((wm * 4 + mf) * 2 + ks) * 64 + ln) * 8];
#pragma unroll
            for (int mf = 0; mf < 4; ++mf)
#pragma unroll
                for (int nf = 0; nf < 4; ++nf)
                    acc[mf][nf] = __builtin_amdgcn_mfma_f32_16x16x32_bf16(
                        afv[mf], bfv[nf], acc[mf][nf], 0, 0, 0);
        }
        __builtin_amdgcn_s_setprio(0);
        __builtin_amdgcn_s_barrier();
    }
#undef G128_STAGE

#pragma unroll
    for (int mf = 0; mf < 4; ++mf) {
        const int row0 = bm + wm * 64 + mf * 16 + lkg * 4;
#pragma unroll
        for (int nf = 0; nf < 4; ++nf) {
            float* cp = C + (size_t)row0 * N + bn + wn * 64 + nf * 16 + lrow;
#pragma unroll
            for (int j = 0; j < 4; ++j) cp[(size_t)j * N] = acc[mf][nf][j];
        }
    }
}

// ================= causal depthwise conv1d (K=4) + SiLU =====================
__global__ __launch_bounds__(256) void conv_silu_kernel(
    const float* __restrict__ pre, const float* __restrict__ cw, float* __restrict__ out)
{
    int idx = blockIdx.x * 256 + threadIdx.x;
    const int NC4 = CONV_DIM / 4;
    int s = idx / NC4;
    int c = (idx % NC4) * 4;
    float w[4][4];
#pragma unroll
    for (int j = 0; j < 4; ++j) {
        float4 wj = *(const float4*)(cw + (size_t)(c + j) * 4);
        w[j][0] = wj.x; w[j][1] = wj.y; w[j][2] = wj.z; w[j][3] = wj.w;
    }
    float acc[4] = {0.f, 0.f, 0.f, 0.f};
#pragma unroll
    for (int t = 0; t < 4; ++t) {
        int ss = s - 3 + t;
        if (ss >= 0) {
            float4 x = *(const float4*)(pre + (size_t)ss * CONV_DIM + c);
            acc[0] = fmaf(x.x, w[0][t], acc[0]);
            acc[1] = fmaf(x.y, w[1][t], acc[1]);
            acc[2] = fmaf(x.z, w[2][t], acc[2]);
            acc[3] = fmaf(x.w, w[3][t], acc[3]);
        }
    }
    float4 o = make_float4(silu_f(acc[0]), silu_f(acc[1]), silu_f(acc[2]), silu_f(acc[3]));
    *(float4*)(out + (size_t)s * CONV_DIM + c) = o;
}

// ====== g = -exp(A_log)*softplus(a+dt_bias), beta = sigmoid(b) ==============
__global__ __launch_bounds__(256) void gb_kernel(
    const float* __restrict__ ab, const float* __restrict__ dt_bias,
    const float* __restrict__ A_log, float* __restrict__ g, float* __restrict__ beta)
{
    int idx = blockIdx.x * 256 + threadIdx.x;
    int s = idx >> 5, h = idx & 31;
    float av = ab[(size_t)s * 128 + h] + dt_bias[h];
    float sp = (av > 20.f) ? av : log1pf(__expf(av));
    g[idx] = -__expf(A_log[h]) * sp;
    beta[idx] = sigmoid_f(ab[(size_t)s * 128 + 32 + h]);
}

// ===== l2norm q,k: q -> bf16 (qnb), k -> f32 (kn) ===========================
__global__ __launch_bounds__(256) void l2norm_kernel(
    const float* __restrict__ mixed, ushort* __restrict__ qnb, float* __restrict__ kn)
{
    int gw = (blockIdx.x * 256 + threadIdx.x) >> 6;
    int lane = threadIdx.x & 63;
    int isk = gw >= S_LEN * NKH;
    int r = gw - isk * S_LEN * NKH;
    int s = r / NKH, kh = r % NKH;
    const float* src = mixed + (size_t)s * CONV_DIM + isk * KEY_DIM + kh * DKD;
    float2 x = *(const float2*)(src + lane * 2);
    float ss = x.x * x.x + x.y * x.y;
#pragma unroll
    for (int m = 1; m < 64; m <<= 1) ss += __shfl_xor(ss, m, 64);
    float scale = rsqrtf(ss + 1e-6f);
    if (!isk) {
        scale *= 0.08838834764831843f;   // DK^-0.5
        union { ushort u[2]; uint v; } p;
        p.u[0] = f2bf(x.x * scale); p.u[1] = f2bf(x.y * scale);
        *(uint*)(qnb + ((size_t)(s * NKH + kh)) * DKD + lane * 2) = p.v;
    } else {
        float* dst = kn + ((size_t)(s * NKH + kh)) * DKD + lane * 2;
        *(float2*)dst = make_float2(x.x * scale, x.y * scale);
    }
}

// ================= Phase A: per (head, chunk) intra-chunk work ==============
// blocked WY solve: off-diagonal via MFMA, 16x16 diagonal solves scalar fp32.
__global__ __launch_bounds__(256) void phaseA_kernel(
    const ushort* __restrict__ qnb, const float* __restrict__ kn,
    const float* __restrict__ mixed, const float* __restrict__ gbuf,
    const float* __restrict__ betabuf,
    float* __restrict__ u, ushort* __restrict__ kcd,
    ushort* __restrict__ scores, float* __restrict__ gcs_out,
    ushort* __restrict__ knT)
{
    extern __shared__ char pasm[];
    ushort* kb    = (ushort*)(pasm);            // 16KB frag [m4][ks4][64][8]
    ushort* qb    = (ushort*)(pasm + 16384);    // 16KB frag; later P f32[16][256]
    ushort* Xb    = (ushort*)(pasm + 32768);    // 32KB [t2(2)][ct(16)][64][8]
    float*  Adiag = (float*)(pasm + 65536);     // 4KB [4][16][16] fp32 diag blocks
    ushort* Ab    = (ushort*)(pasm + 69632);    // 4KB: 4 frags 16x32 bf16 (K=32 padded)
    float*  gcs_s = (float*)(pasm + 73728);     // 64 f
    float*  bet_s = (float*)(pasm + 73984);     // 64 f
    float*  scK_s = (float*)(pasm + 74240);     // 64 f : beta*exp(gcs)
    float*  Pf    = (float*)qb;                 // alias (qb dead after QK^T MFMA)

    const int n = blockIdx.x, h = blockIdx.y, kh = h >> 1;
    const int tid = threadIdx.x;
    const int s0 = n * CCH;
    const int wv = tid >> 6, ln = tid & 63;
    const int lrow = ln & 15, lkg = ln >> 4;

    float xr[64];
    if (tid < 128) {
        const float* vp = mixed + (size_t)s0 * CONV_DIM + 2 * KEY_DIM + h * DVD + tid;
#pragma unroll
        for (int i = 0; i < 64; ++i) xr[i] = vp[(size_t)i * CONV_DIM];
    } else {
        const float* kp = kn + ((size_t)s0 * NKH + kh) * DKD + (tid - 128);
#pragma unroll
        for (int i = 0; i < 64; ++i) xr[i] = kp[(size_t)i * (NKH * DKD)];
    }

    {
        uint4 z = {0, 0, 0, 0};
#pragma unroll
        for (int i = 0; i < 8; ++i)
            *(uint4*)&Xb[(i * 256 + tid) * 8] = z;
        *(uint4*)&Ab[tid * 8] = z;
    }

    if (tid < 64) {
        float gv = gbuf[(size_t)(s0 + tid) * NVH + h];
#pragma unroll
        for (int off = 1; off < 64; off <<= 1) {
            float pv = __shfl_up(gv, off, 64);
            if (tid >= off) gv += pv;
        }
        float bv = betabuf[(size_t)(s0 + tid) * NVH + h];
        gcs_s[tid] = gv;
        bet_s[tid] = bv;
        scK_s[tid] = bv * __expf(gv);
        gcs_out[(size_t)h * S_LEN + s0 + tid] = gv;
    }

    {
        const int r = tid >> 2, c0 = (tid & 3) * 32;
        const int mbase = (((r >> 4) * 4 + (tid & 3)) * 64 + (r & 15)) * 8;
        const float* ksrc = kn + ((size_t)(s0 + r) * NKH + kh) * DKD + c0;
#pragma unroll
        for (int j0 = 0; j0 < 4; ++j0) {
            float4 v0 = *(const float4*)(ksrc + j0 * 8);
            float4 v1 = *(const float4*)(ksrc + j0 * 8 + 4);
            union { ushort us[8]; uint4 v; } p;
            p.us[0] = f2bf(v0.x); p.us[1] = f2bf(v0.y); p.us[2] = f2bf(v0.z); p.us[3] = f2bf(v0.w);
            p.us[4] = f2bf(v1.x); p.us[5] = f2bf(v1.y); p.us[6] = f2bf(v1.z); p.us[7] = f2bf(v1.w);
            *(uint4*)&kb[mbase + (j0 << 7)] = p.v;
        }
        const ushort* qsrc = qnb + ((size_t)(s0 + r) * NKH + kh) * DKD + c0;
#pragma unroll
        for (int j0 = 0; j0 < 4; ++j0) {
            uint4 v = *(const uint4*)(qsrc + j0 * 8);
            *(uint4*)&qb[mbase + (j0 << 7)] = v;
        }
    }
    __syncthreads();    // B1

    f32x4 accA[4], accQ[4];
#pragma unroll
    for (int j = 0; j < 4; ++j) {
        f32x4 z = {0.f, 0.f, 0.f, 0.f};
        accA[j] = z; accQ[j] = z;
    }
#pragma unroll
    for (int ks = 0; ks < 4; ++ks) {
        bf16x8 a_k = *(const bf16x8*)&kb[((wv * 4 + ks) * 64 + ln) * 8];
        bf16x8 a_q = *(const bf16x8*)&qb[((wv * 4 + ks) * 64 + ln) * 8];
#pragma unroll
        for (int j = 0; j < 4; ++j) {
            bf16x8 b_k = *(const bf16x8*)&kb[((j * 4 + ks) * 64 + ln) * 8];
            accA[j] = __builtin_amdgcn_mfma_f32_16x16x32_bf16(a_k, b_k, accA[j], 0, 0, 0);
            accQ[j] = __builtin_amdgcn_mfma_f32_16x16x32_bf16(a_q, b_k, accQ[j], 0, 0, 0);
        }
    }
    {
        ushort* scp = scores + (size_t)(h * NCHK + n) * (CCH * CCH);
#pragma unroll
        for (int j = 0; j < 4; ++j) {
            const int c = j * 16 + lrow;
            const float gc = gcs_s[c];
#pragma unroll
            for (int jj = 0; jj < 4; ++jj) {
                const int i = wv * 16 + lkg * 4 + jj;
                const float e = __expf(gcs_s[i] - gc);
                float sv = (i >= c) ? (accQ[j][jj] * e) : 0.f;
                scp[i * CCH + c] = f2bf(sv);
                float aval = (i > c) ? (-bet_s[i] * accA[j][jj] * e) : 0.f;
                if (j == wv) {
                    Adiag[wv * 256 + (i & 15) * 16 + lrow] = aval;
                } else if (j < wv) {
                    const int f = (wv == 1) ? 0 : ((wv == 2) ? 1 : (2 + (j >> 1)));
                    const int lk = ((j & 1) << 4) | lrow;
                    const int lane2 = (i & 15) | ((lk >> 3) << 4);
                    Ab[(f * 64 + lane2) * 8 + (lk & 7)] = f2bf(aval);
                }
            }
        }
    }
    if (tid < 128) {
#pragma unroll
        for (int i4 = 0; i4 < 16; ++i4) {
            float4 b4 = *(const float4*)&bet_s[i4 * 4];
            xr[i4 * 4 + 0] *= b4.x; xr[i4 * 4 + 1] *= b4.y;
            xr[i4 * 4 + 2] *= b4.z; xr[i4 * 4 + 3] *= b4.w;
        }
    } else {
#pragma unroll
        for (int i4 = 0; i4 < 16; ++i4) {
            float4 b4 = *(const float4*)&scK_s[i4 * 4];
            xr[i4 * 4 + 0] *= b4.x; xr[i4 * 4 + 1] *= b4.y;
            xr[i4 * 4 + 2] *= b4.z; xr[i4 * 4 + 3] *= b4.w;
        }
    }
    __syncthreads();    // B2

    const int ct = tid >> 4, lct = tid & 15;
#pragma unroll
    for (int s = 0; s < 4; ++s) {
        float y[16];
        float pr[16];
        if (s > 0) {
#pragma unroll
            for (int r = 0; r < 16; ++r) pr[r] = Pf[r * 256 + tid];
        } else {
#pragma unroll
            for (int r = 0; r < 16; ++r) pr[r] = 0.f;
        }
#pragma unroll
        for (int r = 0; r < 16; ++r) {
            float acc = xr[s * 16 + r] + pr[r];
#pragma unroll
            for (int k4 = 0; k4 < 16; k4 += 4) {
                if (k4 < r) {
                    float4 a4 = *(const float4*)&Adiag[s * 256 + r * 16 + k4];
                    if (k4 + 0 < r) acc = fmaf(a4.x, y[k4 + 0], acc);
                    if (k4 + 1 < r) acc = fmaf(a4.y, y[k4 + 1], acc);
                    if (k4 + 2 < r) acc = fmaf(a4.z, y[k4 + 2], acc);
                    if (k4 + 3 < r) acc = fmaf(a4.w, y[k4 + 3], acc);
                }
            }
            y[r] = acc;
        }
        if (tid < 128) {
            float* up = u + (size_t)(h * NCHK + n) * (CCH * DVD) + (s * 16) * DVD + tid;
#pragma unroll
            for (int r = 0; r < 16; ++r) up[r * DVD] = y[r];
        } else {
            ushort* kp = kcd + (size_t)(h * NCHK + n) * (CCH * DKD) + (s * 16) * DKD + (tid - 128);
#pragma unroll
            for (int r = 0; r < 16; ++r) kp[r * DKD] = f2bf(y[r]);
        }
        if (s < 3) {
#pragma unroll
            for (int half = 0; half < 2; ++half) {
                union { ushort us[8]; uint4 v; } p;
#pragma unroll
                for (int e = 0; e < 8; ++e) p.us[e] = f2bf(y[half * 8 + e]);
                const int kg = (s & 1) * 2 + half;
                *(uint4*)&Xb[(((s >> 1) * 16 + ct) * 64 + (kg * 16 + lct)) * 8] = p.v;
            }
            __syncthreads();
            const int snx = s + 1;
            const int nT2 = (snx + 1) >> 1;
            f32x4 accP[4];
#pragma unroll
            for (int ctl = 0; ctl < 4; ++ctl) {
                f32x4 z = {0.f, 0.f, 0.f, 0.f};
                accP[ctl] = z;
            }
#pragma unroll
            for (int t2 = 0; t2 < 2; ++t2) {
                if (t2 < nT2) {
                    const int f = (snx == 1) ? 0 : ((snx == 2) ? 1 : (2 + t2));
                    bf16x8 a = *(const bf16x8*)&Ab[(f * 64 + ln) * 8];
#pragma unroll
                    for (int ctl = 0; ctl < 4; ++ctl) {
                        bf16x8 b = *(const bf16x8*)&Xb[((t2 * 16 + wv * 4 + ctl) * 64 + ln) * 8];
                        accP[ctl] = __builtin_amdgcn_mfma_f32_16x16x32_bf16(a, b, accP[ctl], 0, 0, 0);
                    }
                }
            }
#pragma unroll
            for (int ctl = 0; ctl < 4; ++ctl)
#pragma unroll
                for (int jj = 0; jj < 4; ++jj)
                    Pf[(lkg * 4 + jj) * 256 + wv * 64 + ctl * 16 + lrow] = accP[ctl][jj];
            __syncthreads();
        }
    }

    if (!(h & 1)) {
        const int dk = tid >> 1, ch = (tid & 1) * 32;
        ushort* dst = knT + ((size_t)(kh * NCHK + n) * DKD + dk) * CCH + ch;
        const int kpart = ((dk >> 5) * 64) * 8 + (((dk >> 3) & 3) << 4) * 8 + (dk & 7);
#pragma unroll
        for (int j0 = 0; j0 < 32; j0 += 8) {
            union { ushort us[8]; uint4 v; } p;
#pragma unroll
            for (int j = 0; j < 8; ++j) {
                const int row = ch + j0 + j;
                p.us[j] = kb[((row >> 4) * 4 * 64 + (row & 15)) * 8 + kpart];
            }
            *(uint4*)(dst + j0) = p.v;
        }
    }
}

// ================= Phase B: inter-chunk state scan (MFMA) ===================
__global__ __launch_bounds__(256) void phaseB_kernel(
    const ushort* __restrict__ qnb, const ushort* __restrict__ knT,
    const float* __restrict__ u, const ushort* __restrict__ kcd,
    const ushort* __restrict__ sc, const float* __restrict__ gcs,
    float* __restrict__ obuf)
{
    extern __shared__ ushort smu[];
    ushort* qorg  = smu;             // 8192  [m4][ks4][64][8]
    ushort* kcorg = smu + 8192;      // 8192
    ushort* scorg = smu + 16384;     // 4096
    ushort* kTorg = smu + 20480;     // 8192
    ushort* storg = smu + 28672;     // 2048  S^T bf16
    ushort* vnorg = smu + 30720;     // 1024
    ushort* vnsorg= smu + 31744;     // 1024
    float* gcs_s  = (float*)(smu + 32768);   // 64

    const int h = blockIdx.x;
    const int dvb = blockIdx.y;
    const int d0 = dvb * 16;
    const int kh = h >> 1;
    const int tid = threadIdx.x;
    const int wv = tid >> 6, ln = tid & 63;
    const int lrow = ln & 15, lkg = ln >> 4;

    for (int i = tid; i < 2048 / 8; i += 256) {
        uint4 z = {0, 0, 0, 0};
        *(uint4*)&storg[i * 8] = z;
    }

    const int q_lane  = lrow * (NKH * DKD) + kh * DKD + wv * 32 + lkg * 8;
    const int kc_lane = lrow * DKD + wv * 32 + lkg * 8;
    const int st_lane = ((tid >> 7) * 16 + lrow) * 64 + ((tid >> 6) & 1) * 32 + lkg * 8;
    const int dst_e   = wv * 512;

    f32x4 accS0 = {0.f, 0.f, 0.f, 0.f}, accS1 = {0.f, 0.f, 0.f, 0.f};

    for (int n = 0; n < NCHK; ++n) {
        const int s0 = n * CCH;
        const ushort* qsrc  = qnb + (size_t)s0 * (NKH * DKD);
        const ushort* kcsrc = kcd + (size_t)(h * NCHK + n) * (CCH * DKD);
        const ushort* scsrc = sc  + (size_t)(h * NCHK + n) * (CCH * CCH);
        const ushort* kTsrc = knT + (size_t)(kh * NCHK + n) * (DKD * CCH);
#pragma unroll
        for (int r = 0; r < 4; ++r) {
            GLL(qsrc + q_lane + r * 32768, &qorg[r * 2048 + dst_e]);
            GLL(kcsrc + kc_lane + r * 2048, &kcorg[r * 2048 + dst_e]);
            GLL(kTsrc + st_lane + r * 2048, &kTorg[r * 2048 + dst_e]);
        }
#pragma unroll
        for (int r = 0; r < 2; ++r)
            GLL(scsrc + st_lane + r * 2048, &scorg[r * 2048 + dst_e]);
        if (tid < 64) gcs_s[tid] = gcs[(size_t)h * S_LEN + s0 + tid];
        __syncthreads();                 // B1

        f32x4 accv = {0.f, 0.f, 0.f, 0.f};
        f32x4 acco = {0.f, 0.f, 0.f, 0.f};
#pragma unroll
        for (int ks = 0; ks < 4; ++ks) {
            bf16x8 b_st = *(const bf16x8*)&storg[(ks * 64 + ln) * 8];
            bf16x8 a_kc = *(const bf16x8*)&kcorg[((wv * 4 + ks) * 64 + ln) * 8];
            bf16x8 a_q  = *(const bf16x8*)&qorg[((wv * 4 + ks) * 64 + ln) * 8];
            accv = __builtin_amdgcn_mfma_f32_16x16x32_bf16(a_kc, b_st, accv, 0, 0, 0);
            acco = __builtin_amdgcn_mfma_f32_16x16x32_bf16(a_q, b_st, acco, 0, 0, 0);
        }
        const float* up = u + (size_t)(h * NCHK + n) * (CCH * DVD)
                            + (wv * 16 + lkg * 4) * DVD + d0 + lrow;
        float u0 = up[0], u1 = up[DVD], u2 = up[2 * DVD], u3 = up[3 * DVD];
        const float gl = gcs_s[63];
        float vn0 = u0 - accv[0], vn1 = u1 - accv[1];
        float vn2 = u2 - accv[2], vn3 = u3 - accv[3];
        {
            const int row = wv * 16 + lkg * 4;
            float g0 = gcs_s[row], g1 = gcs_s[row + 1], g2 = gcs_s[row + 2], g3 = gcs_s[row + 3];
            acco[0] *= __expf(g0); acco[1] *= __expf(g1);
            acco[2] *= __expf(g2); acco[3] *= __expf(g3);
            const int eb = ((wv >> 1) * 64 + ((wv & 1) * 2 + (lkg >> 1)) * 16 + lrow) * 8
                         + (lkg & 1) * 4;
            union { ushort u2a[4]; uint2 v; } pa, pb;
            pa.u2a[0] = f2bf(vn0); pa.u2a[1] = f2bf(vn1);
            pa.u2a[2] = f2bf(vn2); pa.u2a[3] = f2bf(vn3);
            pb.u2a[0] = f2bf(vn0 * __expf(gl - g0)); pb.u2a[1] = f2bf(vn1 * __expf(gl - g1));
            pb.u2a[2] = f2bf(vn2 * __expf(gl - g2)); pb.u2a[3] = f2bf(vn3 * __expf(gl - g3));
            *(uint2*)&vnorg[eb] = pa.v;
            *(uint2*)&vnsorg[eb] = pb.v;
        }
        __syncthreads();                 // B2

#pragma unroll
        for (int ks = 0; ks < 2; ++ks) {
            bf16x8 a_sc = *(const bf16x8*)&scorg[((wv * 2 + ks) * 64 + ln) * 8];
            bf16x8 b_vn = *(const bf16x8*)&vnorg[(ks * 64 + ln) * 8];
            acco = __builtin_amdgcn_mfma_f32_16x16x32_bf16(a_sc, b_vn, acco, 0, 0, 0);
        }
        float* op = obuf + (size_t)(s0 + wv * 16 + lkg * 4) * VAL_DIM + h * DVD + d0 + lrow;
        op[0] = acco[0]; op[VAL_DIM] = acco[1];
        op[2 * VAL_DIM] = acco[2]; op[3 * VAL_DIM] = acco[3];

        const float egl = __expf(gl);
        accS0 *= egl; accS1 *= egl;
#pragma unroll
        for (int ks = 0; ks < 2; ++ks) {
            bf16x8 a_vs = *(const bf16x8*)&vnsorg[(ks * 64 + ln) * 8];
            bf16x8 b_k0 = *(const bf16x8*)&kTorg[(((wv * 2 + 0) * 2 + ks) * 64 + ln) * 8];
            bf16x8 b_k1 = *(const bf16x8*)&kTorg[(((wv * 2 + 1) * 2 + ks) * 64 + ln) * 8];
            accS0 = __builtin_amdgcn_mfma_f32_16x16x32_bf16(a_vs, b_k0, accS0, 0, 0, 0);
            accS1 = __builtin_amdgcn_mfma_f32_16x16x32_bf16(a_vs, b_k1, accS1, 0, 0, 0);
        }
#pragma unroll
        for (int j = 0; j < 4; ++j) {
            storg[(wv * 64 + ((lrow >> 3)) * 16 + lkg * 4 + j) * 8 + (lrow & 7)] = f2bf(accS0[j]);
            storg[(wv * 64 + (2 + (lrow >> 3)) * 16 + lkg * 4 + j) * 8 + (lrow & 7)] = f2bf(accS1[j]);
        }
        __syncthreads();                 // B3
    }
}

// ================= RMSNorm * norm_w * silu(z) -> bf16 =======================
__global__ __launch_bounds__(256) void norm_kernel(
    const float* __restrict__ obuf, const float* __restrict__ z,
    const float* __restrict__ nw, ushort* __restrict__ hbuf)
{
    int row = (blockIdx.x * 256 + threadIdx.x) >> 6;
    int lane = threadIdx.x & 63;
    float2 x = *(const float2*)(obuf + (size_t)row * DVD + lane * 2);
    float ss = x.x * x.x + x.y * x.y;
#pragma unroll
    for (int m = 1; m < 64; m <<= 1) ss += __shfl_xor(ss, m, 64);
    float scale = rsqrtf(ss * (1.f / DVD) + 1e-6f);
    float2 zz = *(const float2*)(z + (size_t)row * DVD + lane * 2);
    float2 w2 = *(const float2*)(nw + lane * 2);
    float h0 = x.x * scale * w2.x * silu_f(zz.x);
    float h1 = x.y * scale * w2.y * silu_f(zz.y);
    union { ushort u[2]; uint v; } r;
    r.u[0] = f2bf(h0); r.u[1] = f2bf(h1);
    *(uint*)(hbuf + (size_t)row * DVD + lane * 2) = r.v;
}

// ============================================================================
extern "C" void kernel_launch(void* const* d_in, const int* in_sizes, int n_in,
                              void* d_out, int out_size, void* d_ws, size_t ws_size,
                              hipStream_t stream)
{
    (void)in_sizes; (void)n_in; (void)out_size; (void)ws_size;
    const float* x      = (const float*)d_in[0];
    const float* W_qkv  = (const float*)d_in[1];
    const float* W_z    = (const float*)d_in[2];
    const float* W_a    = (const float*)d_in[3];
    const float* W_b    = (const float*)d_in[4];
    const float* conv_w = (const float*)d_in[5];
    const float* dt_b   = (const float*)d_in[6];
    const float* A_log  = (const float*)d_in[7];
    const float* norm_w = (const float*)d_in[8];
    const float* W_out  = (const float*)d_in[9];
    float* out = (float*)d_out;

    // ---- workspace layout (bytes), overlaid by liveness; total ~202.1 MB ---
    char* ws = (char*)d_ws;
    // region A @0 (67,108,864): mixed_pre -> {u f32, kcd bf16, knT bf16}
    float*  mixed_pre = (float*)(ws);
    float*  u_buf     = (float*)(ws);                   // 33,554,432
    ushort* kcd_buf   = (ushort*)(ws + 33554432);       // 16,777,216
    ushort* knT_buf   = (ushort*)(ws + 50331648);       //  8,388,608
    // region B @67,108,864 (67,108,864): {wqz 50.3MB, xb 8.4MB} -> mixed ->
    //   {obuf 33.6, hbuf 16.8, wob 16.8}
    ushort* wqz       = (ushort*)(ws + 67108864);       // 50,331,648 (12288x2048)
    ushort* xb        = (ushort*)(ws + 117440512);      //  8,388,608
    float*  mixed     = (float*)(ws + 67108864);
    float*  obuf      = (float*)(ws + 67108864);
    ushort* hbuf      = (ushort*)(ws + 100663296);
    ushort* wob       = (ushort*)(ws + 117440512);
    // fixed regions
    float*  z_buf     = (float*)(ws + 134217728);       // 33,554,432
    ushort* sc_buf    = (ushort*)(ws + 167772160);      //  8,388,608 (step>=6)
    ushort* wabb      = (ushort*)(ws + 167772160);      //    524,288 (steps 1-3)
    float*  ab_buf    = (float*)(ws + 168296448);       //  1,048,576 (steps 3-4)
    ushort* qnb       = (ushort*)(ws + 176160768);      //  8,388,608
    float*  kn        = (float*)(ws + 184549376);       // 16,777,216
    float*  g_buf     = (float*)(ws + 201326592);       //    262,144
    float*  bet_buf   = (float*)(ws + 201588736);       //    262,144
    float*  gcs_buf   = (float*)(ws + 201850880);       //    262,144

    hipFuncSetAttribute((const void*)phaseA_kernel,
                        hipFuncAttributeMaxDynamicSharedMemorySize, PA_LDS_BYTES);
    hipFuncSetAttribute((const void*)phaseB_kernel,
                        hipFuncAttributeMaxDynamicSharedMemorySize, PB_LDS_BYTES);
    hipFuncSetAttribute((const void*)gemm256_kernel,
                        hipFuncAttributeMaxDynamicSharedMemorySize, G256_LDS_BYTES);
    hipFuncSetAttribute((const void*)gemm128_kernel,
                        hipFuncAttributeMaxDynamicSharedMemorySize, G128_LDS_BYTES);

    dim3 blk(256);
    // 1) casts to bf16 (W_qkv and W_z fused contiguously into wqz)
    cast_kernel<<<(S_LEN * HIDDIM / 8) / 256, blk, 0, stream>>>(x, xb, S_LEN * HIDDIM / 8);
    cast_kernel<<<(CONV_DIM * HIDDIM / 8) / 256, blk, 0, stream>>>(W_qkv, wqz, CONV_DIM * HIDDIM / 8);
    cast_kernel<<<(VAL_DIM * HIDDIM / 8) / 256, blk, 0, stream>>>(W_z, wqz + (size_t)CONV_DIM * HIDDIM, VAL_DIM * HIDDIM / 8);
    cast_ab_kernel<<<(128 * HIDDIM / 8) / 256, blk, 0, stream>>>(W_a, W_b, wabb);
    // 2) fused qkv+z projection (256^2 pipelined, dual output)
    gemm256_kernel<<<dim3((CONV_DIM + VAL_DIM) / 256, S_LEN / 256), dim3(512), G256_LDS_BYTES, stream>>>(
        xb, wqz, mixed_pre, z_buf, HIDDIM, CONV_DIM, CONV_DIM, VAL_DIM);
    // 3) a/b projection (128^2 pipelined)
    gemm128_kernel<<<dim3(1, S_LEN / 128), blk, G128_LDS_BYTES, stream>>>(
        xb, wabb, ab_buf, 128, HIDDIM);
    // 4) conv + silu (fp32)
    conv_silu_kernel<<<(S_LEN * CONV_DIM / 4) / 256, blk, 0, stream>>>(mixed_pre, conv_w, mixed);
    // 5) gates
    gb_kernel<<<(S_LEN * NVH) / 256, blk, 0, stream>>>(ab_buf, dt_b, A_log, g_buf, bet_buf);
    // 6) l2norm q,k
    l2norm_kernel<<<(2 * S_LEN * NKH * 64) / 256, blk, 0, stream>>>(mixed, qnb, kn);
    // 7) phase A (intra-chunk, blocked-MFMA solve)
    phaseA_kernel<<<dim3(NCHK, NVH), blk, PA_LDS_BYTES, stream>>>(
        qnb, kn, mixed, g_buf, bet_buf, u_buf, kcd_buf, sc_buf, gcs_buf, knT_buf);
    // 8) phase B (inter-chunk scan, MFMA)
    phaseB_kernel<<<dim3(NVH, 8), blk, PB_LDS_BYTES, stream>>>(
        qnb, knT_buf, u_buf, kcd_buf, sc_buf, gcs_buf, obuf);
    // 9) W_out cast (mixed region now dead) + gated RMSNorm -> bf16
    cast_kernel<<<(HIDDIM * VAL_DIM / 8) / 256, blk, 0, stream>>>(W_out, wob, HIDDIM * VAL_DIM / 8);
    norm_kernel<<<(S_LEN * NVH * 64) / 256, blk, 0, stream>>>(obuf, z_buf, norm_w, hbuf);
    // 10) output projection (128^2 pipelined)
    gemm128_kernel<<<dim3(HIDDIM / 128, S_LEN / 128), blk, G128_LDS_BYTES, stream>>>(
        hbuf, wob, out, HIDDIM, VAL_DIM);
}

// Round 8
// 491.674 us; speedup vs baseline: 7.1157x; 1.0815x over previous
//
#include <hip/hip_runtime.h>
#include <hip/hip_bf16.h>
#include <math.h>

// ---- problem constants ----
#define S_LEN   2048
#define HIDDIM  2048
#define NKH     16
#define NVH     32
#define DKD     128
#define DVD     128
#define CCH     64          // chunk
#define NCHK    32          // S/chunk
#define KEY_DIM 2048
#define VAL_DIM 4096
#define CONV_DIM 8192

#define PA_LDS_BYTES (16384 + 16384 + 32768 + 4096 + 4096 + 256 + 256 + 256)
#define PB_LDS_BYTES ((8192+8192+4096+8192+2048+1024+1024)*2 + 64*4)
// gemm256: 3 bufs x (A 128x64 + B 256x64) bf16 = 3 x 24576 ushorts
#define G256_LDS_BYTES (3 * 24576 * 2)   // 147456
// gemm128: 3 bufs x (A 128x64 + B 128x64) = 3 x 16384 ushorts
#define G128_LDS_BYTES (3 * 16384 * 2)   // 98304

typedef __bf16 bf16x8 __attribute__((ext_vector_type(8)));
typedef float f32x4 __attribute__((ext_vector_type(4)));

__device__ __forceinline__ float sigmoid_f(float x) { return 1.f / (1.f + __expf(-x)); }
__device__ __forceinline__ float silu_f(float x) { return x * sigmoid_f(x); }
__device__ __forceinline__ ushort f2bf(float f) {
    unsigned u = __float_as_uint(f);
    u += 0x7fffu + ((u >> 16) & 1u);          // RNE (inputs finite)
    return (ushort)(u >> 16);
}
__device__ __forceinline__ float bf2f(ushort u) {
    return __uint_as_float((unsigned)u << 16);
}

#define GLL(srcp, dstp) __builtin_amdgcn_global_load_lds( \
    (const __attribute__((address_space(1))) void*)(srcp), \
    (__attribute__((address_space(3))) void*)(dstp), 16, 0, 0)

// ================= fp32 -> bf16 cast (8 elems/thread) =======================
__global__ __launch_bounds__(256) void cast_kernel(
    const float* __restrict__ in, ushort* __restrict__ out, int n8)
{
    int t = blockIdx.x * 256 + threadIdx.x;
    if (t >= n8) return;
    float4 v0 = *(const float4*)(in + (size_t)t * 8);
    float4 v1 = *(const float4*)(in + (size_t)t * 8 + 4);
    union { ushort u[8]; uint4 v; } r;
    r.u[0] = f2bf(v0.x); r.u[1] = f2bf(v0.y); r.u[2] = f2bf(v0.z); r.u[3] = f2bf(v0.w);
    r.u[4] = f2bf(v1.x); r.u[5] = f2bf(v1.y); r.u[6] = f2bf(v1.z); r.u[7] = f2bf(v1.w);
    *(uint4*)(out + (size_t)t * 8) = r.v;
}

// ====== W_a,W_b -> one padded bf16 weight [128,2048] (rows 64..127 zero) ====
__global__ __launch_bounds__(256) void cast_ab_kernel(
    const float* __restrict__ Wa, const float* __restrict__ Wb, ushort* __restrict__ out)
{
    int t = blockIdx.x * 256 + threadIdx.x;          // 128*2048/8 = 32768 threads
    int row = t >> 8;
    int c8 = (t & 255) * 8;
    union { ushort u[8]; uint4 v; } r;
    if (row < 64) {
        const float* src = (row < 32) ? (Wa + (size_t)row * HIDDIM + c8)
                                      : (Wb + (size_t)(row - 32) * HIDDIM + c8);
        float4 v0 = *(const float4*)(src);
        float4 v1 = *(const float4*)(src + 4);
        r.u[0] = f2bf(v0.x); r.u[1] = f2bf(v0.y); r.u[2] = f2bf(v0.z); r.u[3] = f2bf(v0.w);
        r.u[4] = f2bf(v1.x); r.u[5] = f2bf(v1.y); r.u[6] = f2bf(v1.z); r.u[7] = f2bf(v1.w);
    } else {
        r.u[0] = r.u[1] = r.u[2] = r.u[3] = r.u[4] = r.u[5] = r.u[6] = r.u[7] = 0;
    }
    *(uint4*)(out + (size_t)t * 8) = r.v;
}

// ======== 128x256 triple-buffered counted-vmcnt bf16 GEMM, dual output ======
// C[M,Ntot] = A[M,K] @ B[Ntot,K]^T ; block cols < NSPLIT -> C0 else C1.
// 512 thr = 8 waves (2M x 4N), wave tile 64x64. BK=64, 3 LDS buffers:
// tile t computes buf t%3; tile t+2 staged into buf (t+2)%3 during tile t.
// Top-of-tile wait = vmcnt(6) (t+1's loads stay in flight). 1 barrier/tile.
__global__ __launch_bounds__(512, 2) void gemm256_kernel(
    const ushort* __restrict__ A, const ushort* __restrict__ B,
    float* __restrict__ C0, float* __restrict__ C1,
    int K, int NSPLIT, int ldc0, int ldc1)
{
    extern __shared__ ushort g2s[];          // [3][A 8192 | B 16384] ushorts
    const int tid = threadIdx.x;
    const int wv = tid >> 6, ln = tid & 63;
    const int wm = wv >> 2, wn = wv & 3;
    const int lrow = ln & 15, lkg = ln >> 4;
    const int bm = blockIdx.y * 128, bn = blockIdx.x * 256;

    // staging source offsets: granule g -> frag=g>>7, ks=(g>>6)&1, l=g&63
    // elem (frag*16+(l&15), ks*32+(l>>4)*8); A: g=tid+j*512 (j<2), B: j<4
    int soffA[2], soffB[4];
#pragma unroll
    for (int j = 0; j < 4; ++j) {
        int g = tid + j * 512;
        int frag = g >> 7, ks = (g >> 6) & 1, l = g & 63;
        int off = (frag * 16 + (l & 15)) * K + ks * 32 + (l >> 4) * 8;
        if (j < 2) soffA[j] = off;
        soffB[j] = off;
    }
    const ushort* Abase = A + (size_t)bm * K;
    const ushort* Bbase = B + (size_t)bn * K;

    f32x4 acc[4][4];
#pragma unroll
    for (int m = 0; m < 4; ++m)
#pragma unroll
        for (int n = 0; n < 4; ++n) {
            f32x4 z = {0.f, 0.f, 0.f, 0.f};
            acc[m][n] = z;
        }

#define G256_STAGE(bb, k0) do {                                            \
        ushort* bufA_ = g2s + (bb) * 24576;                                \
        ushort* bufB_ = bufA_ + 8192;                                      \
        _Pragma("unroll")                                                  \
        for (int j_ = 0; j_ < 2; ++j_)                                     \
            GLL(Abase + soffA[j_] + (k0), bufA_ + (j_ * 512 + wv * 64) * 8);\
        _Pragma("unroll")                                                  \
        for (int j_ = 0; j_ < 4; ++j_)                                     \
            GLL(Bbase + soffB[j_] + (k0), bufB_ + (j_ * 512 + wv * 64) * 8);\
    } while (0)

    const int T = K >> 6;
    G256_STAGE(0, 0);
    G256_STAGE(1, 64);
    int bb = 0;
    for (int t = 0; t < T; ++t) {
        if (t + 1 < T) {
            asm volatile("s_waitcnt vmcnt(6)" ::: "memory");
        } else {
            asm volatile("s_waitcnt vmcnt(0)" ::: "memory");
        }
        __builtin_amdgcn_s_barrier();          // all threads' tile-t loads landed
        // stage target = (bb+2)%3 : 0->2, 1->0, 2->1   [bugfix vs round 7]
        if (t + 2 < T) G256_STAGE((bb >= 1) ? (bb - 1) : (bb + 2), (t + 2) * 64);
        const ushort* LA = g2s + bb * 24576;
        const ushort* LB = LA + 8192;
        __builtin_amdgcn_s_setprio(1);
#pragma unroll
        for (int ks = 0; ks < 2; ++ks) {
            bf16x8 afv[4], bfv[4];
#pragma unroll
            for (int mf = 0; mf < 4; ++mf)
                afv[mf] = *(const bf16x8*)&LA[(((wm * 4 + mf) * 2 + ks) * 64 + ln) * 8];
#pragma unroll
            for (int nf = 0; nf < 4; ++nf)
                bfv[nf] = *(const bf16x8*)&LB[(((wn * 4 + nf) * 2 + ks) * 64 + ln) * 8];
#pragma unroll
            for (int mf = 0; mf < 4; ++mf)
#pragma unroll
                for (int nf = 0; nf < 4; ++nf)
                    acc[mf][nf] = __builtin_amdgcn_mfma_f32_16x16x32_bf16(
                        afv[mf], bfv[nf], acc[mf][nf], 0, 0, 0);
        }
        __builtin_amdgcn_s_setprio(0);
        bb = (bb == 2) ? 0 : bb + 1;
    }
#undef G256_STAGE

    // epilogue: dual-output split (NSPLIT % 256 == 0 -> block on one side)
    const bool inC1 = (bn >= NSPLIT);
    float* Cp = inC1 ? C1 : C0;
    const int ldc = inC1 ? ldc1 : ldc0;
    const int cb = bn + wn * 64 - (inC1 ? NSPLIT : 0);
#pragma unroll
    for (int mf = 0; mf < 4; ++mf) {
        const int row0 = bm + wm * 64 + mf * 16 + lkg * 4;
#pragma unroll
        for (int nf = 0; nf < 4; ++nf) {
            float* cp = Cp + (size_t)row0 * ldc + cb + nf * 16 + lrow;
#pragma unroll
            for (int j = 0; j < 4; ++j) cp[(size_t)j * ldc] = acc[mf][nf][j];
        }
    }
}

// ======== 128x128 triple-buffered counted-vmcnt bf16 GEMM ===================
__global__ __launch_bounds__(256, 2) void gemm128_kernel(
    const ushort* __restrict__ A, const ushort* __restrict__ B,
    float* __restrict__ C, int N, int K)
{
    extern __shared__ ushort g1s[];          // [3][A 8192 | B 8192] ushorts
    const int tid = threadIdx.x;
    const int wv = tid >> 6, ln = tid & 63;
    const int wm = wv >> 1, wn = wv & 1;
    const int lrow = ln & 15, lkg = ln >> 4;
    const int bm = blockIdx.y * 128, bn = blockIdx.x * 128;

    int soff[4];
#pragma unroll
    for (int j = 0; j < 4; ++j) {
        int g = tid + j * 256;
        int frag = g >> 7, ks = (g >> 6) & 1, l = g & 63;
        soff[j] = (frag * 16 + (l & 15)) * K + ks * 32 + (l >> 4) * 8;
    }
    const ushort* Abase = A + (size_t)bm * K;
    const ushort* Bbase = B + (size_t)bn * K;

    f32x4 acc[4][4];
#pragma unroll
    for (int m = 0; m < 4; ++m)
#pragma unroll
        for (int n = 0; n < 4; ++n) {
            f32x4 z = {0.f, 0.f, 0.f, 0.f};
            acc[m][n] = z;
        }

#define G128_STAGE(bb, k0) do {                                            \
        ushort* bufA_ = g1s + (bb) * 16384;                                \
        ushort* bufB_ = bufA_ + 8192;                                      \
        _Pragma("unroll")                                                  \
        for (int j_ = 0; j_ < 4; ++j_) {                                   \
            GLL(Abase + soff[j_] + (k0), bufA_ + (j_ * 256 + wv * 64) * 8);\
            GLL(Bbase + soff[j_] + (k0), bufB_ + (j_ * 256 + wv * 64) * 8);\
        }                                                                  \
    } while (0)

    const int T = K >> 6;
    G128_STAGE(0, 0);
    G128_STAGE(1, 64);
    int bb = 0;
    for (int t = 0; t < T; ++t) {
        if (t + 1 < T) {
            asm volatile("s_waitcnt vmcnt(8)" ::: "memory");
        } else {
            asm volatile("s_waitcnt vmcnt(0)" ::: "memory");
        }
        __builtin_amdgcn_s_barrier();
        if (t + 2 < T) G128_STAGE((bb >= 1) ? (bb - 1) : (bb + 2), (t + 2) * 64);
        const ushort* LA = g1s + bb * 16384;
        const ushort* LB = LA + 8192;
        __builtin_amdgcn_s_setprio(1);
#pragma unroll
        for (int ks = 0; ks < 2; ++ks) {
            bf16x8 afv[4], bfv[4];
#pragma unroll
            for (int mf = 0; mf < 4; ++mf)
                afv[mf] = *(const bf16x8*)&LA[(((wm * 4 + mf) * 2 + ks) * 64 + ln) * 8];
#pragma unroll
            for (int nf = 0; nf < 4; ++nf)
                bfv[nf] = *(const bf16x8*)&LB[(((wn * 4 + nf) * 2 + ks) * 64 + ln) * 8];
#pragma unroll
            for (int mf = 0; mf < 4; ++mf)
#pragma unroll
                for (int nf = 0; nf < 4; ++nf)
                    acc[mf][nf] = __builtin_amdgcn_mfma_f32_16x16x32_bf16(
                        afv[mf], bfv[nf], acc[mf][nf], 0, 0, 0);
        }
        __builtin_amdgcn_s_setprio(0);
        bb = (bb == 2) ? 0 : bb + 1;
    }
#undef G128_STAGE

#pragma unroll
    for (int mf = 0; mf < 4; ++mf) {
        const int row0 = bm + wm * 64 + mf * 16 + lkg * 4;
#pragma unroll
        for (int nf = 0; nf < 4; ++nf) {
            float* cp = C + (size_t)row0 * N + bn + wn * 64 + nf * 16 + lrow;
#pragma unroll
            for (int j = 0; j < 4; ++j) cp[(size_t)j * N] = acc[mf][nf][j];
        }
    }
}

// ================= causal depthwise conv1d (K=4) + SiLU =====================
__global__ __launch_bounds__(256) void conv_silu_kernel(
    const float* __restrict__ pre, const float* __restrict__ cw, float* __restrict__ out)
{
    int idx = blockIdx.x * 256 + threadIdx.x;
    const int NC4 = CONV_DIM / 4;
    int s = idx / NC4;
    int c = (idx % NC4) * 4;
    float w[4][4];
#pragma unroll
    for (int j = 0; j < 4; ++j) {
        float4 wj = *(const float4*)(cw + (size_t)(c + j) * 4);
        w[j][0] = wj.x; w[j][1] = wj.y; w[j][2] = wj.z; w[j][3] = wj.w;
    }
    float acc[4] = {0.f, 0.f, 0.f, 0.f};
#pragma unroll
    for (int t = 0; t < 4; ++t) {
        int ss = s - 3 + t;
        if (ss >= 0) {
            float4 x = *(const float4*)(pre + (size_t)ss * CONV_DIM + c);
            acc[0] = fmaf(x.x, w[0][t], acc[0]);
            acc[1] = fmaf(x.y, w[1][t], acc[1]);
            acc[2] = fmaf(x.z, w[2][t], acc[2]);
            acc[3] = fmaf(x.w, w[3][t], acc[3]);
        }
    }
    float4 o = make_float4(silu_f(acc[0]), silu_f(acc[1]), silu_f(acc[2]), silu_f(acc[3]));
    *(float4*)(out + (size_t)s * CONV_DIM + c) = o;
}

// ====== g = -exp(A_log)*softplus(a+dt_bias), beta = sigmoid(b) ==============
__global__ __launch_bounds__(256) void gb_kernel(
    const float* __restrict__ ab, const float* __restrict__ dt_bias,
    const float* __restrict__ A_log, float* __restrict__ g, float* __restrict__ beta)
{
    int idx = blockIdx.x * 256 + threadIdx.x;
    int s = idx >> 5, h = idx & 31;
    float av = ab[(size_t)s * 128 + h] + dt_bias[h];
    float sp = (av > 20.f) ? av : log1pf(__expf(av));
    g[idx] = -__expf(A_log[h]) * sp;
    beta[idx] = sigmoid_f(ab[(size_t)s * 128 + 32 + h]);
}

// ===== l2norm q,k: q -> bf16 (qnb), k -> f32 (kn) ===========================
__global__ __launch_bounds__(256) void l2norm_kernel(
    const float* __restrict__ mixed, ushort* __restrict__ qnb, float* __restrict__ kn)
{
    int gw = (blockIdx.x * 256 + threadIdx.x) >> 6;
    int lane = threadIdx.x & 63;
    int isk = gw >= S_LEN * NKH;
    int r = gw - isk * S_LEN * NKH;
    int s = r / NKH, kh = r % NKH;
    const float* src = mixed + (size_t)s * CONV_DIM + isk * KEY_DIM + kh * DKD;
    float2 x = *(const float2*)(src + lane * 2);
    float ss = x.x * x.x + x.y * x.y;
#pragma unroll
    for (int m = 1; m < 64; m <<= 1) ss += __shfl_xor(ss, m, 64);
    float scale = rsqrtf(ss + 1e-6f);
    if (!isk) {
        scale *= 0.08838834764831843f;   // DK^-0.5
        union { ushort u[2]; uint v; } p;
        p.u[0] = f2bf(x.x * scale); p.u[1] = f2bf(x.y * scale);
        *(uint*)(qnb + ((size_t)(s * NKH + kh)) * DKD + lane * 2) = p.v;
    } else {
        float* dst = kn + ((size_t)(s * NKH + kh)) * DKD + lane * 2;
        *(float2*)dst = make_float2(x.x * scale, x.y * scale);
    }
}

// ================= Phase A: per (head, chunk) intra-chunk work ==============
// blocked WY solve: off-diagonal via MFMA, 16x16 diagonal solves scalar fp32.
__global__ __launch_bounds__(256) void phaseA_kernel(
    const ushort* __restrict__ qnb, const float* __restrict__ kn,
    const float* __restrict__ mixed, const float* __restrict__ gbuf,
    const float* __restrict__ betabuf,
    float* __restrict__ u, ushort* __restrict__ kcd,
    ushort* __restrict__ scores, float* __restrict__ gcs_out,
    ushort* __restrict__ knT)
{
    extern __shared__ char pasm[];
    ushort* kb    = (ushort*)(pasm);            // 16KB frag [m4][ks4][64][8]
    ushort* qb    = (ushort*)(pasm + 16384);    // 16KB frag; later P f32[16][256]
    ushort* Xb    = (ushort*)(pasm + 32768);    // 32KB [t2(2)][ct(16)][64][8]
    float*  Adiag = (float*)(pasm + 65536);     // 4KB [4][16][16] fp32 diag blocks
    ushort* Ab    = (ushort*)(pasm + 69632);    // 4KB: 4 frags 16x32 bf16 (K=32 padded)
    float*  gcs_s = (float*)(pasm + 73728);     // 64 f
    float*  bet_s = (float*)(pasm + 73984);     // 64 f
    float*  scK_s = (float*)(pasm + 74240);     // 64 f : beta*exp(gcs)
    float*  Pf    = (float*)qb;                 // alias (qb dead after QK^T MFMA)

    const int n = blockIdx.x, h = blockIdx.y, kh = h >> 1;
    const int tid = threadIdx.x;
    const int s0 = n * CCH;
    const int wv = tid >> 6, ln = tid & 63;
    const int lrow = ln & 15, lkg = ln >> 4;

    float xr[64];
    if (tid < 128) {
        const float* vp = mixed + (size_t)s0 * CONV_DIM + 2 * KEY_DIM + h * DVD + tid;
#pragma unroll
        for (int i = 0; i < 64; ++i) xr[i] = vp[(size_t)i * CONV_DIM];
    } else {
        const float* kp = kn + ((size_t)s0 * NKH + kh) * DKD + (tid - 128);
#pragma unroll
        for (int i = 0; i < 64; ++i) xr[i] = kp[(size_t)i * (NKH * DKD)];
    }

    {
        uint4 z = {0, 0, 0, 0};
#pragma unroll
        for (int i = 0; i < 8; ++i)
            *(uint4*)&Xb[(i * 256 + tid) * 8] = z;
        *(uint4*)&Ab[tid * 8] = z;
    }

    if (tid < 64) {
        float gv = gbuf[(size_t)(s0 + tid) * NVH + h];
#pragma unroll
        for (int off = 1; off < 64; off <<= 1) {
            float pv = __shfl_up(gv, off, 64);
            if (tid >= off) gv += pv;
        }
        float bv = betabuf[(size_t)(s0 + tid) * NVH + h];
        gcs_s[tid] = gv;
        bet_s[tid] = bv;
        scK_s[tid] = bv * __expf(gv);
        gcs_out[(size_t)h * S_LEN + s0 + tid] = gv;
    }

    {
        const int r = tid >> 2, c0 = (tid & 3) * 32;
        const int mbase = (((r >> 4) * 4 + (tid & 3)) * 64 + (r & 15)) * 8;
        const float* ksrc = kn + ((size_t)(s0 + r) * NKH + kh) * DKD + c0;
#pragma unroll
        for (int j0 = 0; j0 < 4; ++j0) {
            float4 v0 = *(const float4*)(ksrc + j0 * 8);
            float4 v1 = *(const float4*)(ksrc + j0 * 8 + 4);
            union { ushort us[8]; uint4 v; } p;
            p.us[0] = f2bf(v0.x); p.us[1] = f2bf(v0.y); p.us[2] = f2bf(v0.z); p.us[3] = f2bf(v0.w);
            p.us[4] = f2bf(v1.x); p.us[5] = f2bf(v1.y); p.us[6] = f2bf(v1.z); p.us[7] = f2bf(v1.w);
            *(uint4*)&kb[mbase + (j0 << 7)] = p.v;
        }
        const ushort* qsrc = qnb + ((size_t)(s0 + r) * NKH + kh) * DKD + c0;
#pragma unroll
        for (int j0 = 0; j0 < 4; ++j0) {
            uint4 v = *(const uint4*)(qsrc + j0 * 8);
            *(uint4*)&qb[mbase + (j0 << 7)] = v;
        }
    }
    __syncthreads();    // B1

    f32x4 accA[4], accQ[4];
#pragma unroll
    for (int j = 0; j < 4; ++j) {
        f32x4 z = {0.f, 0.f, 0.f, 0.f};
        accA[j] = z; accQ[j] = z;
    }
#pragma unroll
    for (int ks = 0; ks < 4; ++ks) {
        bf16x8 a_k = *(const bf16x8*)&kb[((wv * 4 + ks) * 64 + ln) * 8];
        bf16x8 a_q = *(const bf16x8*)&qb[((wv * 4 + ks) * 64 + ln) * 8];
#pragma unroll
        for (int j = 0; j < 4; ++j) {
            bf16x8 b_k = *(const bf16x8*)&kb[((j * 4 + ks) * 64 + ln) * 8];
            accA[j] = __builtin_amdgcn_mfma_f32_16x16x32_bf16(a_k, b_k, accA[j], 0, 0, 0);
            accQ[j] = __builtin_amdgcn_mfma_f32_16x16x32_bf16(a_q, b_k, accQ[j], 0, 0, 0);
        }
    }
    {
        ushort* scp = scores + (size_t)(h * NCHK + n) * (CCH * CCH);
#pragma unroll
        for (int j = 0; j < 4; ++j) {
            const int c = j * 16 + lrow;
            const float gc = gcs_s[c];
#pragma unroll
            for (int jj = 0; jj < 4; ++jj) {
                const int i = wv * 16 + lkg * 4 + jj;
                const float e = __expf(gcs_s[i] - gc);
                float sv = (i >= c) ? (accQ[j][jj] * e) : 0.f;
                scp[i * CCH + c] = f2bf(sv);
                float aval = (i > c) ? (-bet_s[i] * accA[j][jj] * e) : 0.f;
                if (j == wv) {
                    Adiag[wv * 256 + (i & 15) * 16 + lrow] = aval;
                } else if (j < wv) {
                    const int f = (wv == 1) ? 0 : ((wv == 2) ? 1 : (2 + (j >> 1)));
                    const int lk = ((j & 1) << 4) | lrow;
                    const int lane2 = (i & 15) | ((lk >> 3) << 4);
                    Ab[(f * 64 + lane2) * 8 + (lk & 7)] = f2bf(aval);
                }
            }
        }
    }
    if (tid < 128) {
#pragma unroll
        for (int i4 = 0; i4 < 16; ++i4) {
            float4 b4 = *(const float4*)&bet_s[i4 * 4];
            xr[i4 * 4 + 0] *= b4.x; xr[i4 * 4 + 1] *= b4.y;
            xr[i4 * 4 + 2] *= b4.z; xr[i4 * 4 + 3] *= b4.w;
        }
    } else {
#pragma unroll
        for (int i4 = 0; i4 < 16; ++i4) {
            float4 b4 = *(const float4*)&scK_s[i4 * 4];
            xr[i4 * 4 + 0] *= b4.x; xr[i4 * 4 + 1] *= b4.y;
            xr[i4 * 4 + 2] *= b4.z; xr[i4 * 4 + 3] *= b4.w;
        }
    }
    __syncthreads();    // B2

    const int ct = tid >> 4, lct = tid & 15;
#pragma unroll
    for (int s = 0; s < 4; ++s) {
        float y[16];
        float pr[16];
        if (s > 0) {
#pragma unroll
            for (int r = 0; r < 16; ++r) pr[r] = Pf[r * 256 + tid];
        } else {
#pragma unroll
            for (int r = 0; r < 16; ++r) pr[r] = 0.f;
        }
#pragma unroll
        for (int r = 0; r < 16; ++r) {
            float acc = xr[s * 16 + r] + pr[r];
#pragma unroll
            for (int k4 = 0; k4 < 16; k4 += 4) {
                if (k4 < r) {
                    float4 a4 = *(const float4*)&Adiag[s * 256 + r * 16 + k4];
                    if (k4 + 0 < r) acc = fmaf(a4.x, y[k4 + 0], acc);
                    if (k4 + 1 < r) acc = fmaf(a4.y, y[k4 + 1], acc);
                    if (k4 + 2 < r) acc = fmaf(a4.z, y[k4 + 2], acc);
                    if (k4 + 3 < r) acc = fmaf(a4.w, y[k4 + 3], acc);
                }
            }
            y[r] = acc;
        }
        if (tid < 128) {
            float* up = u + (size_t)(h * NCHK + n) * (CCH * DVD) + (s * 16) * DVD + tid;
#pragma unroll
            for (int r = 0; r < 16; ++r) up[r * DVD] = y[r];
        } else {
            ushort* kp = kcd + (size_t)(h * NCHK + n) * (CCH * DKD) + (s * 16) * DKD + (tid - 128);
#pragma unroll
            for (int r = 0; r < 16; ++r) kp[r * DKD] = f2bf(y[r]);
        }
        if (s < 3) {
#pragma unroll
            for (int half = 0; half < 2; ++half) {
                union { ushort us[8]; uint4 v; } p;
#pragma unroll
                for (int e = 0; e < 8; ++e) p.us[e] = f2bf(y[half * 8 + e]);
                const int kg = (s & 1) * 2 + half;
                *(uint4*)&Xb[(((s >> 1) * 16 + ct) * 64 + (kg * 16 + lct)) * 8] = p.v;
            }
            __syncthreads();
            const int snx = s + 1;
            const int nT2 = (snx + 1) >> 1;
            f32x4 accP[4];
#pragma unroll
            for (int ctl = 0; ctl < 4; ++ctl) {
                f32x4 z = {0.f, 0.f, 0.f, 0.f};
                accP[ctl] = z;
            }
#pragma unroll
            for (int t2 = 0; t2 < 2; ++t2) {
                if (t2 < nT2) {
                    const int f = (snx == 1) ? 0 : ((snx == 2) ? 1 : (2 + t2));
                    bf16x8 a = *(const bf16x8*)&Ab[(f * 64 + ln) * 8];
#pragma unroll
                    for (int ctl = 0; ctl < 4; ++ctl) {
                        bf16x8 b = *(const bf16x8*)&Xb[((t2 * 16 + wv * 4 + ctl) * 64 + ln) * 8];
                        accP[ctl] = __builtin_amdgcn_mfma_f32_16x16x32_bf16(a, b, accP[ctl], 0, 0, 0);
                    }
                }
            }
#pragma unroll
            for (int ctl = 0; ctl < 4; ++ctl)
#pragma unroll
                for (int jj = 0; jj < 4; ++jj)
                    Pf[(lkg * 4 + jj) * 256 + wv * 64 + ctl * 16 + lrow] = accP[ctl][jj];
            __syncthreads();
        }
    }

    if (!(h & 1)) {
        const int dk = tid >> 1, ch = (tid & 1) * 32;
        ushort* dst = knT + ((size_t)(kh * NCHK + n) * DKD + dk) * CCH + ch;
        const int kpart = ((dk >> 5) * 64) * 8 + (((dk >> 3) & 3) << 4) * 8 + (dk & 7);
#pragma unroll
        for (int j0 = 0; j0 < 32; j0 += 8) {
            union { ushort us[8]; uint4 v; } p;
#pragma unroll
            for (int j = 0; j < 8; ++j) {
                const int row = ch + j0 + j;
                p.us[j] = kb[((row >> 4) * 4 * 64 + (row & 15)) * 8 + kpart];
            }
            *(uint4*)(dst + j0) = p.v;
        }
    }
}

// ================= Phase B: inter-chunk state scan (MFMA) ===================
__global__ __launch_bounds__(256) void phaseB_kernel(
    const ushort* __restrict__ qnb, const ushort* __restrict__ knT,
    const float* __restrict__ u, const ushort* __restrict__ kcd,
    const ushort* __restrict__ sc, const float* __restrict__ gcs,
    float* __restrict__ obuf)
{
    extern __shared__ ushort smu[];
    ushort* qorg  = smu;             // 8192  [m4][ks4][64][8]
    ushort* kcorg = smu + 8192;      // 8192
    ushort* scorg = smu + 16384;     // 4096
    ushort* kTorg = smu + 20480;     // 8192
    ushort* storg = smu + 28672;     // 2048  S^T bf16
    ushort* vnorg = smu + 30720;     // 1024
    ushort* vnsorg= smu + 31744;     // 1024
    float* gcs_s  = (float*)(smu + 32768);   // 64

    const int h = blockIdx.x;
    const int dvb = blockIdx.y;
    const int d0 = dvb * 16;
    const int kh = h >> 1;
    const int tid = threadIdx.x;
    const int wv = tid >> 6, ln = tid & 63;
    const int lrow = ln & 15, lkg = ln >> 4;

    for (int i = tid; i < 2048 / 8; i += 256) {
        uint4 z = {0, 0, 0, 0};
        *(uint4*)&storg[i * 8] = z;
    }

    const int q_lane  = lrow * (NKH * DKD) + kh * DKD + wv * 32 + lkg * 8;
    const int kc_lane = lrow * DKD + wv * 32 + lkg * 8;
    const int st_lane = ((tid >> 7) * 16 + lrow) * 64 + ((tid >> 6) & 1) * 32 + lkg * 8;
    const int dst_e   = wv * 512;

    f32x4 accS0 = {0.f, 0.f, 0.f, 0.f}, accS1 = {0.f, 0.f, 0.f, 0.f};

    for (int n = 0; n < NCHK; ++n) {
        const int s0 = n * CCH;
        const ushort* qsrc  = qnb + (size_t)s0 * (NKH * DKD);
        const ushort* kcsrc = kcd + (size_t)(h * NCHK + n) * (CCH * DKD);
        const ushort* scsrc = sc  + (size_t)(h * NCHK + n) * (CCH * CCH);
        const ushort* kTsrc = knT + (size_t)(kh * NCHK + n) * (DKD * CCH);
#pragma unroll
        for (int r = 0; r < 4; ++r) {
            GLL(qsrc + q_lane + r * 32768, &qorg[r * 2048 + dst_e]);
            GLL(kcsrc + kc_lane + r * 2048, &kcorg[r * 2048 + dst_e]);
            GLL(kTsrc + st_lane + r * 2048, &kTorg[r * 2048 + dst_e]);
        }
#pragma unroll
        for (int r = 0; r < 2; ++r)
            GLL(scsrc + st_lane + r * 2048, &scorg[r * 2048 + dst_e]);
        if (tid < 64) gcs_s[tid] = gcs[(size_t)h * S_LEN + s0 + tid];
        __syncthreads();                 // B1

        f32x4 accv = {0.f, 0.f, 0.f, 0.f};
        f32x4 acco = {0.f, 0.f, 0.f, 0.f};
#pragma unroll
        for (int ks = 0; ks < 4; ++ks) {
            bf16x8 b_st = *(const bf16x8*)&storg[(ks * 64 + ln) * 8];
            bf16x8 a_kc = *(const bf16x8*)&kcorg[((wv * 4 + ks) * 64 + ln) * 8];
            bf16x8 a_q  = *(const bf16x8*)&qorg[((wv * 4 + ks) * 64 + ln) * 8];
            accv = __builtin_amdgcn_mfma_f32_16x16x32_bf16(a_kc, b_st, accv, 0, 0, 0);
            acco = __builtin_amdgcn_mfma_f32_16x16x32_bf16(a_q, b_st, acco, 0, 0, 0);
        }
        const float* up = u + (size_t)(h * NCHK + n) * (CCH * DVD)
                            + (wv * 16 + lkg * 4) * DVD + d0 + lrow;
        float u0 = up[0], u1 = up[DVD], u2 = up[2 * DVD], u3 = up[3 * DVD];
        const float gl = gcs_s[63];
        float vn0 = u0 - accv[0], vn1 = u1 - accv[1];
        float vn2 = u2 - accv[2], vn3 = u3 - accv[3];
        {
            const int row = wv * 16 + lkg * 4;
            float g0 = gcs_s[row], g1 = gcs_s[row + 1], g2 = gcs_s[row + 2], g3 = gcs_s[row + 3];
            acco[0] *= __expf(g0); acco[1] *= __expf(g1);
            acco[2] *= __expf(g2); acco[3] *= __expf(g3);
            const int eb = ((wv >> 1) * 64 + ((wv & 1) * 2 + (lkg >> 1)) * 16 + lrow) * 8
                         + (lkg & 1) * 4;
            union { ushort u2a[4]; uint2 v; } pa, pb;
            pa.u2a[0] = f2bf(vn0); pa.u2a[1] = f2bf(vn1);
            pa.u2a[2] = f2bf(vn2); pa.u2a[3] = f2bf(vn3);
            pb.u2a[0] = f2bf(vn0 * __expf(gl - g0)); pb.u2a[1] = f2bf(vn1 * __expf(gl - g1));
            pb.u2a[2] = f2bf(vn2 * __expf(gl - g2)); pb.u2a[3] = f2bf(vn3 * __expf(gl - g3));
            *(uint2*)&vnorg[eb] = pa.v;
            *(uint2*)&vnsorg[eb] = pb.v;
        }
        __syncthreads();                 // B2

#pragma unroll
        for (int ks = 0; ks < 2; ++ks) {
            bf16x8 a_sc = *(const bf16x8*)&scorg[((wv * 2 + ks) * 64 + ln) * 8];
            bf16x8 b_vn = *(const bf16x8*)&vnorg[(ks * 64 + ln) * 8];
            acco = __builtin_amdgcn_mfma_f32_16x16x32_bf16(a_sc, b_vn, acco, 0, 0, 0);
        }
        float* op = obuf + (size_t)(s0 + wv * 16 + lkg * 4) * VAL_DIM + h * DVD + d0 + lrow;
        op[0] = acco[0]; op[VAL_DIM] = acco[1];
        op[2 * VAL_DIM] = acco[2]; op[3 * VAL_DIM] = acco[3];

        const float egl = __expf(gl);
        accS0 *= egl; accS1 *= egl;
#pragma unroll
        for (int ks = 0; ks < 2; ++ks) {
            bf16x8 a_vs = *(const bf16x8*)&vnsorg[(ks * 64 + ln) * 8];
            bf16x8 b_k0 = *(const bf16x8*)&kTorg[(((wv * 2 + 0) * 2 + ks) * 64 + ln) * 8];
            bf16x8 b_k1 = *(const bf16x8*)&kTorg[(((wv * 2 + 1) * 2 + ks) * 64 + ln) * 8];
            accS0 = __builtin_amdgcn_mfma_f32_16x16x32_bf16(a_vs, b_k0, accS0, 0, 0, 0);
            accS1 = __builtin_amdgcn_mfma_f32_16x16x32_bf16(a_vs, b_k1, accS1, 0, 0, 0);
        }
#pragma unroll
        for (int j = 0; j < 4; ++j) {
            storg[(wv * 64 + ((lrow >> 3)) * 16 + lkg * 4 + j) * 8 + (lrow & 7)] = f2bf(accS0[j]);
            storg[(wv * 64 + (2 + (lrow >> 3)) * 16 + lkg * 4 + j) * 8 + (lrow & 7)] = f2bf(accS1[j]);
        }
        __syncthreads();                 // B3
    }
}

// ================= RMSNorm * norm_w * silu(z) -> bf16 =======================
__global__ __launch_bounds__(256) void norm_kernel(
    const float* __restrict__ obuf, const float* __restrict__ z,
    const float* __restrict__ nw, ushort* __restrict__ hbuf)
{
    int row = (blockIdx.x * 256 + threadIdx.x) >> 6;
    int lane = threadIdx.x & 63;
    float2 x = *(const float2*)(obuf + (size_t)row * DVD + lane * 2);
    float ss = x.x * x.x + x.y * x.y;
#pragma unroll
    for (int m = 1; m < 64; m <<= 1) ss += __shfl_xor(ss, m, 64);
    float scale = rsqrtf(ss * (1.f / DVD) + 1e-6f);
    float2 zz = *(const float2*)(z + (size_t)row * DVD + lane * 2);
    float2 w2 = *(const float2*)(nw + lane * 2);
    float h0 = x.x * scale * w2.x * silu_f(zz.x);
    float h1 = x.y * scale * w2.y * silu_f(zz.y);
    union { ushort u[2]; uint v; } r;
    r.u[0] = f2bf(h0); r.u[1] = f2bf(h1);
    *(uint*)(hbuf + (size_t)row * DVD + lane * 2) = r.v;
}

// ============================================================================
extern "C" void kernel_launch(void* const* d_in, const int* in_sizes, int n_in,
                              void* d_out, int out_size, void* d_ws, size_t ws_size,
                              hipStream_t stream)
{
    (void)in_sizes; (void)n_in; (void)out_size; (void)ws_size;
    const float* x      = (const float*)d_in[0];
    const float* W_qkv  = (const float*)d_in[1];
    const float* W_z    = (const float*)d_in[2];
    const float* W_a    = (const float*)d_in[3];
    const float* W_b    = (const float*)d_in[4];
    const float* conv_w = (const float*)d_in[5];
    const float* dt_b   = (const float*)d_in[6];
    const float* A_log  = (const float*)d_in[7];
    const float* norm_w = (const float*)d_in[8];
    const float* W_out  = (const float*)d_in[9];
    float* out = (float*)d_out;

    // ---- workspace layout (bytes), overlaid by liveness; total ~202.1 MB ---
    char* ws = (char*)d_ws;
    // region A @0 (67,108,864): mixed_pre -> {u f32, kcd bf16, knT bf16}
    float*  mixed_pre = (float*)(ws);
    float*  u_buf     = (float*)(ws);                   // 33,554,432
    ushort* kcd_buf   = (ushort*)(ws + 33554432);       // 16,777,216
    ushort* knT_buf   = (ushort*)(ws + 50331648);       //  8,388,608
    // region B @67,108,864 (67,108,864): {wqz 50.3MB, xb 8.4MB} -> mixed ->
    //   {obuf 33.6, hbuf 16.8, wob 16.8}
    ushort* wqz       = (ushort*)(ws + 67108864);       // 50,331,648 (12288x2048)
    ushort* xb        = (ushort*)(ws + 117440512);      //  8,388,608
    float*  mixed     = (float*)(ws + 67108864);
    float*  obuf      = (float*)(ws + 67108864);
    ushort* hbuf      = (ushort*)(ws + 100663296);
    ushort* wob       = (ushort*)(ws + 117440512);
    // fixed regions
    float*  z_buf     = (float*)(ws + 134217728);       // 33,554,432
    ushort* sc_buf    = (ushort*)(ws + 167772160);      //  8,388,608 (step>=6)
    ushort* wabb      = (ushort*)(ws + 167772160);      //    524,288 (steps 1-3)
    float*  ab_buf    = (float*)(ws + 168296448);       //  1,048,576 (steps 3-4)
    ushort* qnb       = (ushort*)(ws + 176160768);      //  8,388,608
    float*  kn        = (float*)(ws + 184549376);       // 16,777,216
    float*  g_buf     = (float*)(ws + 201326592);       //    262,144
    float*  bet_buf   = (float*)(ws + 201588736);       //    262,144
    float*  gcs_buf   = (float*)(ws + 201850880);       //    262,144

    hipFuncSetAttribute((const void*)phaseA_kernel,
                        hipFuncAttributeMaxDynamicSharedMemorySize, PA_LDS_BYTES);
    hipFuncSetAttribute((const void*)phaseB_kernel,
                        hipFuncAttributeMaxDynamicSharedMemorySize, PB_LDS_BYTES);
    hipFuncSetAttribute((const void*)gemm256_kernel,
                        hipFuncAttributeMaxDynamicSharedMemorySize, G256_LDS_BYTES);
    hipFuncSetAttribute((const void*)gemm128_kernel,
                        hipFuncAttributeMaxDynamicSharedMemorySize, G128_LDS_BYTES);

    dim3 blk(256);
    // 1) casts to bf16 (W_qkv and W_z fused contiguously into wqz)
    cast_kernel<<<(S_LEN * HIDDIM / 8) / 256, blk, 0, stream>>>(x, xb, S_LEN * HIDDIM / 8);
    cast_kernel<<<(CONV_DIM * HIDDIM / 8) / 256, blk, 0, stream>>>(W_qkv, wqz, CONV_DIM * HIDDIM / 8);
    cast_kernel<<<(VAL_DIM * HIDDIM / 8) / 256, blk, 0, stream>>>(W_z, wqz + (size_t)CONV_DIM * HIDDIM, VAL_DIM * HIDDIM / 8);
    cast_ab_kernel<<<(128 * HIDDIM / 8) / 256, blk, 0, stream>>>(W_a, W_b, wabb);
    // 2) fused qkv+z projection (128x256 triple-buffered, 768 blocks = 3x256)
    gemm256_kernel<<<dim3((CONV_DIM + VAL_DIM) / 256, S_LEN / 128), dim3(512), G256_LDS_BYTES, stream>>>(
        xb, wqz, mixed_pre, z_buf, HIDDIM, CONV_DIM, CONV_DIM, VAL_DIM);
    // 3) a/b projection
    gemm128_kernel<<<dim3(1, S_LEN / 128), blk, G128_LDS_BYTES, stream>>>(
        xb, wabb, ab_buf, 128, HIDDIM);
    // 4) conv + silu (fp32)
    conv_silu_kernel<<<(S_LEN * CONV_DIM / 4) / 256, blk, 0, stream>>>(mixed_pre, conv_w, mixed);
    // 5) gates
    gb_kernel<<<(S_LEN * NVH) / 256, blk, 0, stream>>>(ab_buf, dt_b, A_log, g_buf, bet_buf);
    // 6) l2norm q,k
    l2norm_kernel<<<(2 * S_LEN * NKH * 64) / 256, blk, 0, stream>>>(mixed, qnb, kn);
    // 7) phase A (intra-chunk, blocked-MFMA solve)
    phaseA_kernel<<<dim3(NCHK, NVH), blk, PA_LDS_BYTES, stream>>>(
        qnb, kn, mixed, g_buf, bet_buf, u_buf, kcd_buf, sc_buf, gcs_buf, knT_buf);
    // 8) phase B (inter-chunk scan, MFMA)
    phaseB_kernel<<<dim3(NVH, 8), blk, PB_LDS_BYTES, stream>>>(
        qnb, knT_buf, u_buf, kcd_buf, sc_buf, gcs_buf, obuf);
    // 9) W_out cast (mixed region now dead) + gated RMSNorm -> bf16
    cast_kernel<<<(HIDDIM * VAL_DIM / 8) / 256, blk, 0, stream>>>(W_out, wob, HIDDIM * VAL_DIM / 8);
    norm_kernel<<<(S_LEN * NVH * 64) / 256, blk, 0, stream>>>(obuf, z_buf, norm_w, hbuf);
    // 10) output projection (128^2 triple-buffered, 256 blocks = 1x256)
    gemm128_kernel<<<dim3(HIDDIM / 128, S_LEN / 128), blk, G128_LDS_BYTES, stream>>>(
        hbuf, wob, out, HIDDIM, VAL_DIM);
}